// Round 8
// baseline (1007.944 us; speedup 1.0000x reference)
//
#include <hip/hip_runtime.h>
#include <math.h>

#define T 4
#define LL 3
#define C 256
#define DIN 20
#define NN 4096
#define EE 65536
#define AHD 4
#define MCH 4     // attention m-chunks (blockIdx.z)

// ---- workspace layout (4-byte word offsets) ----
#define W_OFF    0                    // int[N*T+1]
#define W_CURSOR 16640                // int[N*T]  (also hist counts)
#define W_SORTED 33024                // int[E]
#define F_XL     98560                // float[T][N][C]
#define F_H      (F_XL + T*NN*C)      // float[T][N][C]
#define F_OPART  F_XL                 // alias: float[MCH][N][C] = 4M words fits dead F_XL region
#define F_SSRC   (F_H + T*NN*C)       // float[T][N]
#define F_SDST   (F_SSRC + T*NN)      // float[T][N]
#define F_SE     (F_SDST + T*NN)      // float[LL][E]
#define F_SLOOP  (F_SE + LL*EE)       // float[LL][N*T] indexed l*NT + n*T+t
#define F_WE     (F_SLOOP + LL*T*NN)  // float[T*LL][10] (padded 128)
#define F_HACC   (F_WE + 128)         // float[N][C]
#define F_WT     (F_HACC + NN*C)      // float[256][768] in_proj_w transposed
#define F_QKV    (F_WT + 768*256)     // float[N][768]
#define F_DPART  (F_QKV + NN*768)     // float[MCH][N][AH]
#define F_MEANP  (F_DPART + MCH*NN*AHD) // float[C]
#define F_MAXP   (F_MEANP + C)        // float[C]
#define F_OMEAN  (F_MAXP + C)         // float[C]
#define F_ATTNP  (F_OMEAN + C)        // float[C]
#define F_G1     (F_ATTNP + C)        // float[512]
#define WS_WORDS (F_G1 + 512)
#define NZERO (MCH*NN*AHD + 3*C)      // dpart (atomic target) + meanp, maxp, omean

static __device__ __forceinline__ float lrelu(float x){ return x > 0.f ? x : 0.2f*x; }
static __device__ __forceinline__ float eluf(float x){ return x > 0.f ? x : __expf(x) - 1.f; }
static __device__ __forceinline__ void fma4(float4& o, float p, float4 v){
  o.x += p*v.x; o.y += p*v.y; o.z += p*v.z; o.w += p*v.w;
}
static __device__ __forceinline__ void exp4(float4& s){
  s.x = __expf(s.x); s.y = __expf(s.y); s.z = __expf(s.z); s.w = __expf(s.w);
}

typedef _Float16 half2_t __attribute__((ext_vector_type(2)));
static __device__ __forceinline__ unsigned pk2(float x, float y){
  half2_t h; h.x = (_Float16)x; h.y = (_Float16)y;
  return __builtin_bit_cast(unsigned, h);
}
#if __has_builtin(__builtin_amdgcn_fdot2)
static __device__ __forceinline__ float fdot2u(unsigned a, unsigned b, float c){
  return __builtin_amdgcn_fdot2(__builtin_bit_cast(half2_t, a), __builtin_bit_cast(half2_t, b), c, false);
}
#else
static __device__ __forceinline__ float fdot2u(unsigned a, unsigned b, float c){
  half2_t ha = __builtin_bit_cast(half2_t, a), hb = __builtin_bit_cast(half2_t, b);
  return c + (float)ha.x*(float)hb.x + (float)ha.y*(float)hb.y;
}
#endif
static __device__ __forceinline__ float dotu4(uint4 a, uint4 b, float c){
  c = fdot2u(a.x, b.x, c); c = fdot2u(a.y, b.y, c);
  c = fdot2u(a.z, b.z, c); c = fdot2u(a.w, b.w, c);
  return c;
}
// swizzled LDS index: row-major [row][32 u32], chunks of 4 u32 rotated by (row>>2)
// -> score/PV reads are 2-way-conflict-free (free per m136)
static __device__ __forceinline__ int rotIdx(int row, int p){
  return row*32 + ((((p >> 2) + (row >> 2)) & 7) << 2) + (p & 3);
}

static __device__ inline void atomicMaxF(float* addr, float val){
  int* ai = (int*)addr;
  int old = __float_as_int(*addr);
  while (__int_as_float(old) < val){
    int assumed = old;
    old = atomicCAS(ai, assumed, __float_as_int(val));
    if (old == assumed) break;
  }
}

__global__ __launch_bounds__(256) void zero_k(float* fz, int nf, int* iz, int ni){
  int i = blockIdx.x*256 + threadIdx.x;
  if (i < nf) fz[i] = 0.f;
  if (i < ni) iz[i] = 0;
}
__global__ __launch_bounds__(256) void initmax_k(float* maxp){ maxp[threadIdx.x] = -1e30f; }

__global__ __launch_bounds__(256) void hist_k(const int* __restrict__ dst, const int* __restrict__ ety, int* cnt){
  int e = blockIdx.x*256 + threadIdx.x;
  if (e < EE) atomicAdd(&cnt[dst[e]*T + ety[e]], 1);
}

__global__ __launch_bounds__(1024) void scan_k(int* cnt, int* off, int* cursor){
  __shared__ int part[1024];
  int tid = threadIdx.x;
  int base = tid*16;
  int loc[16]; int s = 0;
  for (int i = 0; i < 16; i++){ loc[i] = cnt[base+i]; s += loc[i]; }
  part[tid] = s; __syncthreads();
  int v = s;
  for (int offn = 1; offn < 1024; offn <<= 1){
    int add = (tid >= offn) ? part[tid-offn] : 0;
    __syncthreads();
    v += add; part[tid] = v;
    __syncthreads();
  }
  int excl = v - s;
  for (int i = 0; i < 16; i++){ off[base+i] = excl; cursor[base+i] = excl; excl += loc[i]; }
  if (tid == 1023) off[NN*T] = excl;
}

__global__ __launch_bounds__(256) void scatter_k(const int* __restrict__ dst, const int* __restrict__ ety,
                                                 int* cursor, int* sorted){
  int e = blockIdx.x*256 + threadIdx.x;
  if (e < EE){
    int p = atomicAdd(&cursor[dst[e]*T + ety[e]], 1);
    sorted[p] = e;
  }
}

// we[t][l][k] = sum_c lin_edge_w[t,l,k,c] * att_edge[t,l,0,c]  -- all (t,l) in one launch
__global__ __launch_bounds__(256) void we2_k(const float* __restrict__ linE, const float* __restrict__ attE,
                                             float* we){
  int t = blockIdx.x, l = blockIdx.y, c = threadIdx.x;
  __shared__ float part[10*C];
  float ae = attE[(t*LL + l)*C + c];
  const float* lw = linE + (size_t)((t*LL + l)*10)*C;
  for (int k = 0; k < 10; k++) part[k*C + c] = lw[k*C + c]*ae;
  __syncthreads();
  if (c < 10){
    float s = 0.f;
    for (int i = 0; i < C; i++) s += part[c*C + i];
    we[(t*LL + l)*10 + c] = s;
  }
}

// xl[t][n][:] = h_t[n][:] @ W_t ; 8 nodes per block; fused ssd reduction
__global__ __launch_bounds__(256) void gemm_k(const float* __restrict__ hin, long htstr, int K,
                                              const float* __restrict__ Wb, long wtstr,
                                              const float* __restrict__ attS, const float* __restrict__ attD,
                                              int l, float* __restrict__ xlo,
                                              float* __restrict__ ssrc, float* __restrict__ sdst){
  int t = blockIdx.y;
  const float* h = hin + (size_t)t*htstr;
  const float* W = Wb + (size_t)t*wtstr;
  int n0 = blockIdx.x*8;
  __shared__ float sh[8*256];
  __shared__ float red[64];
  for (int j = 0; j < 8; j++)
    for (int k = threadIdx.x; k < K; k += 256)
      sh[j*K + k] = h[(n0+j)*K + k];
  __syncthreads();
  float acc[8] = {0,0,0,0,0,0,0,0};
  int c = threadIdx.x;
  for (int k = 0; k < K; k += 4){
    float w0 = W[(k+0)*C + c], w1 = W[(k+1)*C + c], w2 = W[(k+2)*C + c], w3 = W[(k+3)*C + c];
    #pragma unroll
    for (int j = 0; j < 8; j++){
      float4 h4 = *(const float4*)&sh[j*K + k];
      acc[j] += w0*h4.x + w1*h4.y + w2*h4.z + w3*h4.w;
    }
  }
  #pragma unroll
  for (int j = 0; j < 8; j++) xlo[(t*NN + n0 + j)*C + c] = acc[j];
  float aS = attS[(t*LL + l)*C + c], aD = attD[(t*LL + l)*C + c];
  int lane = c & 63, w = c >> 6;
  #pragma unroll
  for (int j = 0; j < 8; j++){
    float v1 = acc[j]*aS, v2 = acc[j]*aD;
    #pragma unroll
    for (int off = 32; off > 0; off >>= 1){ v1 += __shfl_down(v1, off); v2 += __shfl_down(v2, off); }
    if (lane == 0){ red[j*8 + w] = v1; red[j*8 + 4 + w] = v2; }
  }
  __syncthreads();
  if (c < 16){
    int j = c >> 1, which = c & 1;
    const float* r = red + j*8 + which*4;
    float s = r[0] + r[1] + r[2] + r[3];
    (which ? sdst : ssrc)[t*NN + n0 + j] = s;
  }
}

// all layers at once: se[l][e]
__global__ __launch_bounds__(256) void se_k(const float* __restrict__ eattr, const int* __restrict__ ety,
                                            const float* __restrict__ we, float* se){
  int e = blockIdx.x*256 + threadIdx.x;
  int l = blockIdx.y;
  if (e < EE){
    const float* w = we + (ety[e]*LL + l)*10;
    const float* ea = eattr + e*10;
    float s = 0.f;
    #pragma unroll
    for (int k = 0; k < 10; k++) s += ea[k]*w[k];
    se[(size_t)l*EE + e] = s;
  }
}

// all layers at once: sloop[l][i]
__global__ __launch_bounds__(256) void sloop_k(const int* __restrict__ off, const int* __restrict__ sorted,
                                               const float* __restrict__ se, float* sloop){
  int i = blockIdx.x*256 + threadIdx.x;
  int l = blockIdx.y;
  if (i < NN*T){
    int o0 = off[i], o1 = off[i+1];
    const float* sel = se + (size_t)l*EE;
    float s = 0.f;
    for (int j = o0; j < o1; j++) s += sel[sorted[j]];
    int dg = o1 - o0;
    sloop[(size_t)l*(NN*T) + i] = s / (float)(dg > 0 ? dg : 1);
  }
}

__global__ __launch_bounds__(256) void agg_k(const float* __restrict__ xl, const float* __restrict__ ssrc,
                                             const float* __restrict__ sdst, const float* __restrict__ se,
                                             const float* __restrict__ sloop, const int* __restrict__ off,
                                             const int* __restrict__ sorted, const int* __restrict__ srcv,
                                             const float* __restrict__ bias, float* __restrict__ hout, int l){
  int n = blockIdx.x, t = blockIdx.y;
  int i = n*T + t;
  int o0 = off[i];
  int deg = off[i+1] - o0;
  if (deg > 512) deg = 512;
  __shared__ float sc[512];
  __shared__ int sj[512];
  __shared__ float sInv, sAL;
  for (int j = threadIdx.x; j < deg; j += 256){
    int e = sorted[o0 + j];
    int sn = srcv[e];
    sc[j] = lrelu(ssrc[t*NN + sn] + sdst[t*NN + n] + se[e]);
    sj[j] = sn;
  }
  __syncthreads();
  if (threadIdx.x == 0){
    float al = lrelu(ssrc[t*NN + n] + sdst[t*NN + n] + sloop[i]);
    float mx = al;
    for (int j = 0; j < deg; j++) mx = fmaxf(mx, sc[j]);
    float al_e = __expf(al - mx);
    float ssum = al_e;
    for (int j = 0; j < deg; j++){ float ex = __expf(sc[j] - mx); sc[j] = ex; ssum += ex; }
    sInv = 1.f/(ssum + 1e-16f);
    sAL = al_e;
  }
  __syncthreads();
  int c = threadIdx.x;
  float acc = sAL * xl[(t*NN + n)*C + c];
  for (int j = 0; j < deg; j++) acc += sc[j] * xl[(t*NN + sj[j])*C + c];
  acc = acc*sInv + bias[(t*LL + l)*C + c];
  hout[(t*NN + n)*C + c] = eluf(acc);
}

__global__ __launch_bounds__(256) void hacc_k(const float* __restrict__ h, const float* __restrict__ etw,
                                              float* __restrict__ hacc){
  int n = blockIdx.x, c = threadIdx.x;
  float e0 = etw[0], e1 = etw[1], e2 = etw[2], e3 = etw[3];
  float m = fmaxf(fmaxf(e0,e1), fmaxf(e2,e3));
  float w0 = __expf(e0-m), w1 = __expf(e1-m), w2 = __expf(e2-m), w3 = __expf(e3-m);
  float inv = 1.f/(w0+w1+w2+w3);
  float s = w0*h[(0*NN+n)*C+c] + w1*h[(1*NN+n)*C+c] + w2*h[(2*NN+n)*C+c] + w3*h[(3*NN+n)*C+c];
  hacc[n*C + c] = s*inv;
}

__global__ __launch_bounds__(256) void colstats_k(const float* __restrict__ hacc, float* meanp, float* maxp){
  int r0 = blockIdx.x*128, c = threadIdx.x;
  float sm = 0.f, mx = -1e30f;
  for (int r = 0; r < 128; r++){
    float v = hacc[(r0+r)*C + c];
    sm += v; mx = fmaxf(mx, v);
  }
  atomicAdd(&meanp[c], sm*(1.f/4096.f));
  atomicMaxF(&maxp[c], mx);
}

__global__ __launch_bounds__(256) void transpose_k(const float* __restrict__ ipw, float* __restrict__ WT){
  int i = blockIdx.x*256 + threadIdx.x;
  if (i < 768*256){
    int j = i >> 8, k = i & 255;
    WT[k*768 + j] = ipw[i];
  }
}

__global__ __launch_bounds__(256) void qkv_k(const float* __restrict__ hacc, const float* __restrict__ WT,
                                             const float* __restrict__ ipb, float* __restrict__ qkv){
  int p = blockIdx.y;
  int n0 = blockIdx.x*8;
  int jj = threadIdx.x;
  __shared__ float sh[8*256];
  for (int j = 0; j < 8; j++) sh[j*256 + threadIdx.x] = hacc[(n0+j)*C + threadIdx.x];
  __syncthreads();
  float acc[8] = {0,0,0,0,0,0,0,0};
  int col = p*256 + jj;
  for (int k = 0; k < 256; k += 4){
    float w0 = WT[(k+0)*768 + col], w1 = WT[(k+1)*768 + col],
          w2 = WT[(k+2)*768 + col], w3 = WT[(k+3)*768 + col];
    #pragma unroll
    for (int j = 0; j < 8; j++){
      float4 h4 = *(const float4*)&sh[j*256 + k];
      acc[j] += w0*h4.x + w1*h4.y + w2*h4.z + w3*h4.w;
    }
  }
  float b = ipb[col];
  #pragma unroll
  for (int j = 0; j < 8; j++) qkv[(n0+j)*768 + col] = acc[j] + b;
}

// R8: flash attn with f16 LDS tiles + v_dot2_f32_f16 (R7 post-mortem: kernel is
// LDS-issue-bound, ~256 b128 reads/wave-tile ~= 330us aggregate vs 110us VALU).
// f16 pairs: each b128 read carries 8 operands, each dot2 = 2 MACs -> LDS instr
// and VALU both halve. Chunk-rotation swizzle keeps reads 2-way-free.
// fp32 accumulation throughout; f16 staging error ~4e-4 << 4.5e-3 threshold.
__global__ __launch_bounds__(256, 4) void attn_k(const float* __restrict__ qkv,
                                                 float* __restrict__ opart,
                                                 float* __restrict__ dpart){
  __shared__ unsigned QTh[64*32];  // [n][kk-pairs] f16, rotated chunks
  __shared__ unsigned KTh[64*32];  // [m][kk-pairs]
  __shared__ unsigned VTh[64*32];  // [d][m-pairs]
  __shared__ unsigned Ph [64*32];  // [n][m-pairs]
  int tid = threadIdx.x;
  int nb = blockIdx.x * 64, h = blockIdx.y, mc = blockIdx.z;
  int tn = tid & 15, td = tid >> 4;     // td 0..15
  int n0 = tn*4, m0 = td*4, d0 = td*4;
  int sr = tid >> 2, sc = (tid & 3)*16; // staging row / first f16 col

  // stage Q (prescaled by 1/8), f16
  {
    const float* qrow = qkv + (size_t)(nb + sr)*768 + h*64 + sc;
    float4 A = *(const float4*)(qrow+0), B = *(const float4*)(qrow+4),
           Cc = *(const float4*)(qrow+8), D = *(const float4*)(qrow+12);
    uint4 w0 = make_uint4(pk2(A.x*0.125f,A.y*0.125f), pk2(A.z*0.125f,A.w*0.125f),
                          pk2(B.x*0.125f,B.y*0.125f), pk2(B.z*0.125f,B.w*0.125f));
    uint4 w1 = make_uint4(pk2(Cc.x*0.125f,Cc.y*0.125f), pk2(Cc.z*0.125f,Cc.w*0.125f),
                          pk2(D.x*0.125f,D.y*0.125f), pk2(D.z*0.125f,D.w*0.125f));
    *(uint4*)&QTh[rotIdx(sr, sc>>1)] = w0;
    *(uint4*)&QTh[rotIdx(sr, (sc>>1)+4)] = w1;
  }

  float4 o0 = make_float4(0,0,0,0), o1 = o0, o2 = o0, o3 = o0;
  float4 dn = make_float4(0,0,0,0);

  for (int mt = 0; mt < NN/MCH/64; mt++){
    int mb = mc*(NN/MCH) + mt*64;
    __syncthreads();                    // prev PV done; Q staged on iter 0
    {
      const float* krow = qkv + (size_t)(mb + sr)*768 + 256 + h*64 + sc;
      const float* vrow = krow + 256;
      float4 A = *(const float4*)(krow+0), B = *(const float4*)(krow+4),
             Cc = *(const float4*)(krow+8), D = *(const float4*)(krow+12);
      uint4 w0 = make_uint4(pk2(A.x,A.y), pk2(A.z,A.w), pk2(B.x,B.y), pk2(B.z,B.w));
      uint4 w1 = make_uint4(pk2(Cc.x,Cc.y), pk2(Cc.z,Cc.w), pk2(D.x,D.y), pk2(D.z,D.w));
      *(uint4*)&KTh[rotIdx(sr, sc>>1)] = w0;
      *(uint4*)&KTh[rotIdx(sr, (sc>>1)+4)] = w1;
      _Float16* VH = (_Float16*)VTh;
      int p = sr >> 1, hf = sr & 1;
      #pragma unroll
      for (int i = 0; i < 4; i++){
        float4 v = *(const float4*)(vrow + 4*i);
        int dd = sc + 4*i;
        VH[2*rotIdx(dd+0, p) + hf] = (_Float16)v.x;
        VH[2*rotIdx(dd+1, p) + hf] = (_Float16)v.y;
        VH[2*rotIdx(dd+2, p) + hf] = (_Float16)v.z;
        VH[2*rotIdx(dd+3, p) + hf] = (_Float16)v.w;
      }
    }
    __syncthreads();
    // scores: s_i = n-row n0+i, components = m-cols m0..m0+3
    float4 s0 = make_float4(0,0,0,0), s1 = s0, s2 = s0, s3 = s0;
    #pragma unroll
    for (int c = 0; c < 8; c++){
      uint4 qa = *(uint4*)&QTh[rotIdx(n0+0, c<<2)];
      uint4 qb = *(uint4*)&QTh[rotIdx(n0+1, c<<2)];
      uint4 qc = *(uint4*)&QTh[rotIdx(n0+2, c<<2)];
      uint4 qd = *(uint4*)&QTh[rotIdx(n0+3, c<<2)];
      uint4 ka = *(uint4*)&KTh[rotIdx(m0+0, c<<2)];
      uint4 kb = *(uint4*)&KTh[rotIdx(m0+1, c<<2)];
      uint4 kc = *(uint4*)&KTh[rotIdx(m0+2, c<<2)];
      uint4 kd = *(uint4*)&KTh[rotIdx(m0+3, c<<2)];
      s0.x = dotu4(qa,ka,s0.x); s0.y = dotu4(qa,kb,s0.y); s0.z = dotu4(qa,kc,s0.z); s0.w = dotu4(qa,kd,s0.w);
      s1.x = dotu4(qb,ka,s1.x); s1.y = dotu4(qb,kb,s1.y); s1.z = dotu4(qb,kc,s1.z); s1.w = dotu4(qb,kd,s1.w);
      s2.x = dotu4(qc,ka,s2.x); s2.y = dotu4(qc,kb,s2.y); s2.z = dotu4(qc,kc,s2.z); s2.w = dotu4(qc,kd,s2.w);
      s3.x = dotu4(qd,ka,s3.x); s3.y = dotu4(qd,kb,s3.y); s3.z = dotu4(qd,kc,s3.z); s3.w = dotu4(qd,kd,s3.w);
    }
    exp4(s0); exp4(s1); exp4(s2); exp4(s3);
    dn.x += s0.x+s0.y+s0.z+s0.w;
    dn.y += s1.x+s1.y+s1.z+s1.w;
    dn.z += s2.x+s2.y+s2.z+s2.w;
    dn.w += s3.x+s3.y+s3.z+s3.w;
    // P[n][m-pairs] f16 (separate buffer -> no barrier needed before write)
    *(uint2*)&Ph[rotIdx(n0+0, td<<1)] = make_uint2(pk2(s0.x,s0.y), pk2(s0.z,s0.w));
    *(uint2*)&Ph[rotIdx(n0+1, td<<1)] = make_uint2(pk2(s1.x,s1.y), pk2(s1.z,s1.w));
    *(uint2*)&Ph[rotIdx(n0+2, td<<1)] = make_uint2(pk2(s2.x,s2.y), pk2(s2.z,s2.w));
    *(uint2*)&Ph[rotIdx(n0+3, td<<1)] = make_uint2(pk2(s3.x,s3.y), pk2(s3.z,s3.w));
    __syncthreads();                    // P fully written
    // PV: o_i = n-row n0+i, components = d-cols d0..d0+3
    #pragma unroll
    for (int c = 0; c < 8; c++){
      uint4 pa = *(uint4*)&Ph[rotIdx(n0+0, c<<2)];
      uint4 pb = *(uint4*)&Ph[rotIdx(n0+1, c<<2)];
      uint4 pc = *(uint4*)&Ph[rotIdx(n0+2, c<<2)];
      uint4 pd = *(uint4*)&Ph[rotIdx(n0+3, c<<2)];
      uint4 va = *(uint4*)&VTh[rotIdx(d0+0, c<<2)];
      uint4 vb = *(uint4*)&VTh[rotIdx(d0+1, c<<2)];
      uint4 vc = *(uint4*)&VTh[rotIdx(d0+2, c<<2)];
      uint4 vd = *(uint4*)&VTh[rotIdx(d0+3, c<<2)];
      o0.x = dotu4(pa,va,o0.x); o0.y = dotu4(pa,vb,o0.y); o0.z = dotu4(pa,vc,o0.z); o0.w = dotu4(pa,vd,o0.w);
      o1.x = dotu4(pb,va,o1.x); o1.y = dotu4(pb,vb,o1.y); o1.z = dotu4(pb,vc,o1.z); o1.w = dotu4(pb,vd,o1.w);
      o2.x = dotu4(pc,va,o2.x); o2.y = dotu4(pc,vb,o2.y); o2.z = dotu4(pc,vc,o2.z); o2.w = dotu4(pc,vd,o2.w);
      o3.x = dotu4(pd,va,o3.x); o3.y = dotu4(pd,vb,o3.y); o3.z = dotu4(pd,vc,o3.z); o3.w = dotu4(pd,vd,o3.w);
    }
  }

  float* ob = opart + ((size_t)mc*NN + nb)*C + h*64;
  *(float4*)(ob + (n0+0)*C + d0) = o0;
  *(float4*)(ob + (n0+1)*C + d0) = o1;
  *(float4*)(ob + (n0+2)*C + d0) = o2;
  *(float4*)(ob + (n0+3)*C + d0) = o3;
  // dn components = n-rows; sum over td groups (bits 4,5 of tid) then 4 waves via atomics
  dn.x += __shfl_xor(dn.x, 16); dn.y += __shfl_xor(dn.y, 16);
  dn.z += __shfl_xor(dn.z, 16); dn.w += __shfl_xor(dn.w, 16);
  dn.x += __shfl_xor(dn.x, 32); dn.y += __shfl_xor(dn.y, 32);
  dn.z += __shfl_xor(dn.z, 32); dn.w += __shfl_xor(dn.w, 32);
  if ((tid & 63) < 16){
    float* db = dpart + ((size_t)mc*NN + nb + n0)*AHD + h;
    atomicAdd(&db[0*AHD], dn.x); atomicAdd(&db[1*AHD], dn.y);
    atomicAdd(&db[2*AHD], dn.z); atomicAdd(&db[3*AHD], dn.w);
  }
}

__global__ __launch_bounds__(256) void attnred_k(const float* __restrict__ opart, const float* __restrict__ dpart,
                                                 float* omean){
  int r0 = blockIdx.x*128, c = threadIdx.x;
  int head = c >> 6;
  float s = 0.f;
  for (int r = 0; r < 128; r++){
    int n = r0 + r;
    float dsum = 0.f, osum = 0.f;
    #pragma unroll
    for (int mc = 0; mc < MCH; mc++){
      dsum += dpart[((size_t)mc*NN + n)*AHD + head];
      osum += opart[((size_t)mc*NN + n)*C + c];
    }
    s += osum / (dsum + 1e-16f);
  }
  atomicAdd(&omean[c], s*(1.f/4096.f));
}

__global__ __launch_bounds__(256) void attnproj_k(const float* __restrict__ omean, const float* __restrict__ opw,
                                                  const float* __restrict__ opb, float* attnp){
  __shared__ float sh[256];
  int j = threadIdx.x;
  sh[j] = omean[j];
  __syncthreads();
  float acc = opb[j];
  for (int k = 0; k < 256; k++) acc += sh[k]*opw[j*256 + k];
  attnp[j] = acc;
}

__global__ __launch_bounds__(512) void fus1_k(const float* __restrict__ meanp, const float* __restrict__ maxp,
                                              const float* __restrict__ attnp, const float* __restrict__ fw1,
                                              const float* __restrict__ fb1, float* g1){
  __shared__ float comb[768];
  for (int i = threadIdx.x; i < 768; i += 512)
    comb[i] = (i < 256) ? meanp[i] : (i < 512 ? maxp[i-256] : attnp[i-512]);
  __syncthreads();
  int j = threadIdx.x;
  float acc = fb1[j];
  for (int k = 0; k < 768; k++) acc += comb[k]*fw1[k*512 + j];
  g1[j] = fmaxf(acc, 0.f);
}

__global__ __launch_bounds__(256) void fus2_k(const float* __restrict__ g1, const float* __restrict__ fw2,
                                              const float* __restrict__ fb2, float* __restrict__ out){
  __shared__ float g[512];
  g[threadIdx.x] = g1[threadIdx.x];
  g[threadIdx.x + 256] = g1[threadIdx.x + 256];
  __syncthreads();
  int j = threadIdx.x;
  float acc = fb2[j];
  for (int k = 0; k < 512; k++) acc += g[k]*fw2[k*256 + j];
  out[j] = fmaxf(acc, 0.f);
}

extern "C" void kernel_launch(void* const* d_in, const int* in_sizes, int n_in,
                              void* d_out, int out_size, void* d_ws, size_t ws_size,
                              hipStream_t stream){
  const float* x     = (const float*)d_in[0];
  const int*   srcv  = (const int*)d_in[1];
  const int*   dstv  = (const int*)d_in[2];
  const float* eattr = (const float*)d_in[3];
  const int*   etyp  = (const int*)d_in[4];
  const float* W0    = (const float*)d_in[5];
  const float* W12   = (const float*)d_in[6];
  const float* attS  = (const float*)d_in[7];
  const float* attD  = (const float*)d_in[8];
  const float* attE  = (const float*)d_in[9];
  const float* linE  = (const float*)d_in[10];
  const float* bias  = (const float*)d_in[11];
  const float* etw   = (const float*)d_in[12];
  const float* ipw   = (const float*)d_in[13];
  const float* ipb   = (const float*)d_in[14];
  const float* opw   = (const float*)d_in[15];
  const float* opb   = (const float*)d_in[16];
  const float* fw1   = (const float*)d_in[17];
  const float* fb1   = (const float*)d_in[18];
  const float* fw2   = (const float*)d_in[19];
  const float* fb2   = (const float*)d_in[20];
  float* out = (float*)d_out;

  if (ws_size < (size_t)WS_WORDS*4) return;

  int*   ip = (int*)d_ws;
  float* fp = (float*)d_ws;

  zero_k<<<(NZERO + 255)/256, 256, 0, stream>>>(fp + F_DPART, NZERO, ip + W_CURSOR, NN*T);
  initmax_k<<<1, 256, 0, stream>>>(fp + F_MAXP);

  hist_k<<<EE/256, 256, 0, stream>>>(dstv, etyp, ip + W_CURSOR);
  scan_k<<<1, 1024, 0, stream>>>(ip + W_CURSOR, ip + W_OFF, ip + W_CURSOR);
  scatter_k<<<EE/256, 256, 0, stream>>>(dstv, etyp, ip + W_CURSOR, ip + W_SORTED);

  transpose_k<<<768, 256, 0, stream>>>(ipw, fp + F_WT);

  // all-layer prepass: we, se, sloop
  we2_k<<<dim3(T, LL), 256, 0, stream>>>(linE, attE, fp + F_WE);
  se_k<<<dim3(EE/256, LL), 256, 0, stream>>>(eattr, etyp, fp + F_WE, fp + F_SE);
  sloop_k<<<dim3((NN*T)/256, LL), 256, 0, stream>>>(ip + W_OFF, ip + W_SORTED, fp + F_SE, fp + F_SLOOP);

  for (int l = 0; l < 3; l++){
    const float* hin = (l == 0) ? x : (fp + F_H);
    long htstr = (l == 0) ? 0 : (long)NN*C;
    int K = (l == 0) ? DIN : C;
    const float* Wb = (l == 0) ? W0 : (W12 + (size_t)(l-1)*C*C);
    long wtstr = (l == 0) ? (long)DIN*C : (long)2*C*C;

    gemm_k<<<dim3(NN/8, T), 256, 0, stream>>>(hin, htstr, K, Wb, wtstr, attS, attD, l,
                                              fp + F_XL, fp + F_SSRC, fp + F_SDST);
    agg_k<<<dim3(NN, T), 256, 0, stream>>>(fp + F_XL, fp + F_SSRC, fp + F_SDST,
                                           fp + F_SE + (size_t)l*EE,
                                           fp + F_SLOOP + (size_t)l*(NN*T),
                                           ip + W_OFF, ip + W_SORTED, srcv,
                                           bias, fp + F_H, l);
  }

  hacc_k<<<NN, 256, 0, stream>>>(fp + F_H, etw, fp + F_HACC);
  colstats_k<<<32, 256, 0, stream>>>(fp + F_HACC, fp + F_MEANP, fp + F_MAXP);

  qkv_k<<<dim3(NN/8, 3), 256, 0, stream>>>(fp + F_HACC, fp + F_WT, ipb, fp + F_QKV);
  attn_k<<<dim3(NN/64, AHD, MCH), 256, 0, stream>>>(fp + F_QKV, fp + F_OPART, fp + F_DPART);
  attnred_k<<<32, 256, 0, stream>>>(fp + F_OPART, fp + F_DPART, fp + F_OMEAN);
  attnproj_k<<<1, 256, 0, stream>>>(fp + F_OMEAN, opw, opb, fp + F_ATTNP);

  fus1_k<<<1, 512, 0, stream>>>(fp + F_MEANP, fp + F_MAXP, fp + F_ATTNP, fw1, fb1, fp + F_G1);
  fus2_k<<<1, 256, 0, stream>>>(fp + F_G1, fw2, fb2, out);
}

// Round 9
// 760.867 us; speedup vs baseline: 1.3247x; 1.3247x over previous
//
#include <hip/hip_runtime.h>
#include <math.h>

#define T 4
#define LL 3
#define C 256
#define DIN 20
#define NN 4096
#define EE 65536
#define AHD 4
#define MCH 2     // attention m-chunks (blockIdx.z); 2 keeps co-resident stream drift < 4MB L2/XCD (R8 post-mortem)

// ---- workspace layout (4-byte word offsets) ----
#define W_OFF    0                    // int[N*T+1]
#define W_CURSOR 16640                // int[N*T]  (also hist counts)
#define W_SORTED 33024                // int[E]
#define F_XL     98560                // float[T][N][C]
#define F_H      (F_XL + T*NN*C)      // float[T][N][C]
#define F_OPART  F_XL                 // alias: float[MCH][N][C] fits dead F_XL region
#define F_SSRC   (F_H + T*NN*C)       // float[T][N]
#define F_SDST   (F_SSRC + T*NN)      // float[T][N]
#define F_SE     (F_SDST + T*NN)      // float[LL][E]
#define F_SLOOP  (F_SE + LL*EE)       // float[LL][N*T] indexed l*NT + n*T+t
#define F_WE     (F_SLOOP + LL*T*NN)  // float[T*LL][10] (padded 128)
#define F_HACC   (F_WE + 128)         // float[N][C]
#define F_WT     (F_HACC + NN*C)      // float[256][768] in_proj_w transposed
#define F_QKV    (F_WT + 768*256)     // float[N][768]
#define F_DPART  (F_QKV + NN*768)     // float[MCH][N][AH]
#define F_MEANP  (F_DPART + MCH*NN*AHD) // float[C]
#define F_MAXP   (F_MEANP + C)        // float[C]
#define F_OMEAN  (F_MAXP + C)         // float[C]
#define F_ATTNP  (F_OMEAN + C)        // float[C]
#define F_G1     (F_ATTNP + C)        // float[512]
#define WS_WORDS (F_G1 + 512)
#define NZERO (MCH*NN*AHD + 3*C)      // dpart (atomic target) + meanp, maxp, omean

static __device__ __forceinline__ float lrelu(float x){ return x > 0.f ? x : 0.2f*x; }
static __device__ __forceinline__ float eluf(float x){ return x > 0.f ? x : __expf(x) - 1.f; }
static __device__ __forceinline__ void exp4(float4& s){
  s.x = __expf(s.x); s.y = __expf(s.y); s.z = __expf(s.z); s.w = __expf(s.w);
}

typedef _Float16 half2_t __attribute__((ext_vector_type(2)));
static __device__ __forceinline__ unsigned pk2(float x, float y){
  half2_t h; h.x = (_Float16)x; h.y = (_Float16)y;
  return __builtin_bit_cast(unsigned, h);
}
#if __has_builtin(__builtin_amdgcn_fdot2)
static __device__ __forceinline__ float fdot2u(unsigned a, unsigned b, float c){
  return __builtin_amdgcn_fdot2(__builtin_bit_cast(half2_t, a), __builtin_bit_cast(half2_t, b), c, false);
}
#else
static __device__ __forceinline__ float fdot2u(unsigned a, unsigned b, float c){
  half2_t ha = __builtin_bit_cast(half2_t, a), hb = __builtin_bit_cast(half2_t, b);
  return c + (float)ha.x*(float)hb.x + (float)ha.y*(float)hb.y;
}
#endif
static __device__ __forceinline__ float dotu4(uint4 a, uint4 b, float c){
  c = fdot2u(a.x, b.x, c); c = fdot2u(a.y, b.y, c);
  c = fdot2u(a.z, b.z, c); c = fdot2u(a.w, b.w, c);
  return c;
}
// swizzled LDS index: row-major [row][32 u32], chunks of 4 u32 rotated by (row>>2)
static __device__ __forceinline__ int rotIdx(int row, int p){
  return row*32 + ((((p >> 2) + (row >> 2)) & 7) << 2) + (p & 3);
}

static __device__ inline void atomicMaxF(float* addr, float val){
  int* ai = (int*)addr;
  int old = __float_as_int(*addr);
  while (__int_as_float(old) < val){
    int assumed = old;
    old = atomicCAS(ai, assumed, __float_as_int(val));
    if (old == assumed) break;
  }
}

__global__ __launch_bounds__(256) void zero_k(float* fz, int nf, int* iz, int ni){
  int i = blockIdx.x*256 + threadIdx.x;
  if (i < nf) fz[i] = 0.f;
  if (i < ni) iz[i] = 0;
}
__global__ __launch_bounds__(256) void initmax_k(float* maxp){ maxp[threadIdx.x] = -1e30f; }

__global__ __launch_bounds__(256) void hist_k(const int* __restrict__ dst, const int* __restrict__ ety, int* cnt){
  int e = blockIdx.x*256 + threadIdx.x;
  if (e < EE) atomicAdd(&cnt[dst[e]*T + ety[e]], 1);
}

__global__ __launch_bounds__(1024) void scan_k(int* cnt, int* off, int* cursor){
  __shared__ int part[1024];
  int tid = threadIdx.x;
  int base = tid*16;
  int loc[16]; int s = 0;
  for (int i = 0; i < 16; i++){ loc[i] = cnt[base+i]; s += loc[i]; }
  part[tid] = s; __syncthreads();
  int v = s;
  for (int offn = 1; offn < 1024; offn <<= 1){
    int add = (tid >= offn) ? part[tid-offn] : 0;
    __syncthreads();
    v += add; part[tid] = v;
    __syncthreads();
  }
  int excl = v - s;
  for (int i = 0; i < 16; i++){ off[base+i] = excl; cursor[base+i] = excl; excl += loc[i]; }
  if (tid == 1023) off[NN*T] = excl;
}

__global__ __launch_bounds__(256) void scatter_k(const int* __restrict__ dst, const int* __restrict__ ety,
                                                 int* cursor, int* sorted){
  int e = blockIdx.x*256 + threadIdx.x;
  if (e < EE){
    int p = atomicAdd(&cursor[dst[e]*T + ety[e]], 1);
    sorted[p] = e;
  }
}

// we[t][l][k] = sum_c lin_edge_w[t,l,k,c] * att_edge[t,l,0,c]  -- all (t,l) in one launch
__global__ __launch_bounds__(256) void we2_k(const float* __restrict__ linE, const float* __restrict__ attE,
                                             float* we){
  int t = blockIdx.x, l = blockIdx.y, c = threadIdx.x;
  __shared__ float part[10*C];
  float ae = attE[(t*LL + l)*C + c];
  const float* lw = linE + (size_t)((t*LL + l)*10)*C;
  for (int k = 0; k < 10; k++) part[k*C + c] = lw[k*C + c]*ae;
  __syncthreads();
  if (c < 10){
    float s = 0.f;
    for (int i = 0; i < C; i++) s += part[c*C + i];
    we[(t*LL + l)*10 + c] = s;
  }
}

// xl[t][n][:] = h_t[n][:] @ W_t ; 8 nodes per block; fused ssd reduction
__global__ __launch_bounds__(256) void gemm_k(const float* __restrict__ hin, long htstr, int K,
                                              const float* __restrict__ Wb, long wtstr,
                                              const float* __restrict__ attS, const float* __restrict__ attD,
                                              int l, float* __restrict__ xlo,
                                              float* __restrict__ ssrc, float* __restrict__ sdst){
  int t = blockIdx.y;
  const float* h = hin + (size_t)t*htstr;
  const float* W = Wb + (size_t)t*wtstr;
  int n0 = blockIdx.x*8;
  __shared__ float sh[8*256];
  __shared__ float red[64];
  for (int j = 0; j < 8; j++)
    for (int k = threadIdx.x; k < K; k += 256)
      sh[j*K + k] = h[(n0+j)*K + k];
  __syncthreads();
  float acc[8] = {0,0,0,0,0,0,0,0};
  int c = threadIdx.x;
  for (int k = 0; k < K; k += 4){
    float w0 = W[(k+0)*C + c], w1 = W[(k+1)*C + c], w2 = W[(k+2)*C + c], w3 = W[(k+3)*C + c];
    #pragma unroll
    for (int j = 0; j < 8; j++){
      float4 h4 = *(const float4*)&sh[j*K + k];
      acc[j] += w0*h4.x + w1*h4.y + w2*h4.z + w3*h4.w;
    }
  }
  #pragma unroll
  for (int j = 0; j < 8; j++) xlo[(t*NN + n0 + j)*C + c] = acc[j];
  float aS = attS[(t*LL + l)*C + c], aD = attD[(t*LL + l)*C + c];
  int lane = c & 63, w = c >> 6;
  #pragma unroll
  for (int j = 0; j < 8; j++){
    float v1 = acc[j]*aS, v2 = acc[j]*aD;
    #pragma unroll
    for (int off = 32; off > 0; off >>= 1){ v1 += __shfl_down(v1, off); v2 += __shfl_down(v2, off); }
    if (lane == 0){ red[j*8 + w] = v1; red[j*8 + 4 + w] = v2; }
  }
  __syncthreads();
  if (c < 16){
    int j = c >> 1, which = c & 1;
    const float* r = red + j*8 + which*4;
    float s = r[0] + r[1] + r[2] + r[3];
    (which ? sdst : ssrc)[t*NN + n0 + j] = s;
  }
}

// all layers at once: se[l][e]
__global__ __launch_bounds__(256) void se_k(const float* __restrict__ eattr, const int* __restrict__ ety,
                                            const float* __restrict__ we, float* se){
  int e = blockIdx.x*256 + threadIdx.x;
  int l = blockIdx.y;
  if (e < EE){
    const float* w = we + (ety[e]*LL + l)*10;
    const float* ea = eattr + e*10;
    float s = 0.f;
    #pragma unroll
    for (int k = 0; k < 10; k++) s += ea[k]*w[k];
    se[(size_t)l*EE + e] = s;
  }
}

// all layers at once: sloop[l][i]
__global__ __launch_bounds__(256) void sloop_k(const int* __restrict__ off, const int* __restrict__ sorted,
                                               const float* __restrict__ se, float* sloop){
  int i = blockIdx.x*256 + threadIdx.x;
  int l = blockIdx.y;
  if (i < NN*T){
    int o0 = off[i], o1 = off[i+1];
    const float* sel = se + (size_t)l*EE;
    float s = 0.f;
    for (int j = o0; j < o1; j++) s += sel[sorted[j]];
    int dg = o1 - o0;
    sloop[(size_t)l*(NN*T) + i] = s / (float)(dg > 0 ? dg : 1);
  }
}

__global__ __launch_bounds__(256) void agg_k(const float* __restrict__ xl, const float* __restrict__ ssrc,
                                             const float* __restrict__ sdst, const float* __restrict__ se,
                                             const float* __restrict__ sloop, const int* __restrict__ off,
                                             const int* __restrict__ sorted, const int* __restrict__ srcv,
                                             const float* __restrict__ bias, float* __restrict__ hout, int l){
  int n = blockIdx.x, t = blockIdx.y;
  int i = n*T + t;
  int o0 = off[i];
  int deg = off[i+1] - o0;
  if (deg > 512) deg = 512;
  __shared__ float sc[512];
  __shared__ int sj[512];
  __shared__ float sInv, sAL;
  for (int j = threadIdx.x; j < deg; j += 256){
    int e = sorted[o0 + j];
    int sn = srcv[e];
    sc[j] = lrelu(ssrc[t*NN + sn] + sdst[t*NN + n] + se[e]);
    sj[j] = sn;
  }
  __syncthreads();
  if (threadIdx.x == 0){
    float al = lrelu(ssrc[t*NN + n] + sdst[t*NN + n] + sloop[i]);
    float mx = al;
    for (int j = 0; j < deg; j++) mx = fmaxf(mx, sc[j]);
    float al_e = __expf(al - mx);
    float ssum = al_e;
    for (int j = 0; j < deg; j++){ float ex = __expf(sc[j] - mx); sc[j] = ex; ssum += ex; }
    sInv = 1.f/(ssum + 1e-16f);
    sAL = al_e;
  }
  __syncthreads();
  int c = threadIdx.x;
  float acc = sAL * xl[(t*NN + n)*C + c];
  for (int j = 0; j < deg; j++) acc += sc[j] * xl[(t*NN + sj[j])*C + c];
  acc = acc*sInv + bias[(t*LL + l)*C + c];
  hout[(t*NN + n)*C + c] = eluf(acc);
}

__global__ __launch_bounds__(256) void hacc_k(const float* __restrict__ h, const float* __restrict__ etw,
                                              float* __restrict__ hacc){
  int n = blockIdx.x, c = threadIdx.x;
  float e0 = etw[0], e1 = etw[1], e2 = etw[2], e3 = etw[3];
  float m = fmaxf(fmaxf(e0,e1), fmaxf(e2,e3));
  float w0 = __expf(e0-m), w1 = __expf(e1-m), w2 = __expf(e2-m), w3 = __expf(e3-m);
  float inv = 1.f/(w0+w1+w2+w3);
  float s = w0*h[(0*NN+n)*C+c] + w1*h[(1*NN+n)*C+c] + w2*h[(2*NN+n)*C+c] + w3*h[(3*NN+n)*C+c];
  hacc[n*C + c] = s*inv;
}

__global__ __launch_bounds__(256) void colstats_k(const float* __restrict__ hacc, float* meanp, float* maxp){
  int r0 = blockIdx.x*128, c = threadIdx.x;
  float sm = 0.f, mx = -1e30f;
  for (int r = 0; r < 128; r++){
    float v = hacc[(r0+r)*C + c];
    sm += v; mx = fmaxf(mx, v);
  }
  atomicAdd(&meanp[c], sm*(1.f/4096.f));
  atomicMaxF(&maxp[c], mx);
}

__global__ __launch_bounds__(256) void transpose_k(const float* __restrict__ ipw, float* __restrict__ WT){
  int i = blockIdx.x*256 + threadIdx.x;
  if (i < 768*256){
    int j = i >> 8, k = i & 255;
    WT[k*768 + j] = ipw[i];
  }
}

__global__ __launch_bounds__(256) void qkv_k(const float* __restrict__ hacc, const float* __restrict__ WT,
                                             const float* __restrict__ ipb, float* __restrict__ qkv){
  int p = blockIdx.y;
  int n0 = blockIdx.x*8;
  int jj = threadIdx.x;
  __shared__ float sh[8*256];
  for (int j = 0; j < 8; j++) sh[j*256 + threadIdx.x] = hacc[(n0+j)*C + threadIdx.x];
  __syncthreads();
  float acc[8] = {0,0,0,0,0,0,0,0};
  int col = p*256 + jj;
  for (int k = 0; k < 256; k += 4){
    float w0 = WT[(k+0)*768 + col], w1 = WT[(k+1)*768 + col],
          w2 = WT[(k+2)*768 + col], w3 = WT[(k+3)*768 + col];
    #pragma unroll
    for (int j = 0; j < 8; j++){
      float4 h4 = *(const float4*)&sh[j*256 + k];
      acc[j] += w0*h4.x + w1*h4.y + w2*h4.z + w3*h4.w;
    }
  }
  float b = ipb[col];
  #pragma unroll
  for (int j = 0; j < 8; j++) qkv[(n0+j)*768 + col] = acc[j] + b;
}

// R9: f16/dot2 flash attn (R8 kernel) at R7's residency regime: MCH=2 +
// launch_bounds(256,2) => 512 blocks, 2/CU; co-resident stream drift
// ~2MB/XCD < 4MB L2 (R8 post-mortem: MCH=4 @ 4/CU thrashed L2 -> 675MB
// L2-miss traffic, 426us; R7 same regime held FETCH at 35MB).
__global__ __launch_bounds__(256, 2) void attn_k(const float* __restrict__ qkv,
                                                 float* __restrict__ opart,
                                                 float* __restrict__ dpart){
  __shared__ unsigned QTh[64*32];  // [n][kk-pairs] f16, rotated chunks
  __shared__ unsigned KTh[64*32];  // [m][kk-pairs]
  __shared__ unsigned VTh[64*32];  // [d][m-pairs]
  __shared__ unsigned Ph [64*32];  // [n][m-pairs]
  int tid = threadIdx.x;
  int nb = blockIdx.x * 64, h = blockIdx.y, mc = blockIdx.z;
  int tn = tid & 15, td = tid >> 4;     // td 0..15
  int n0 = tn*4, m0 = td*4, d0 = td*4;
  int sr = tid >> 2, sc = (tid & 3)*16; // staging row / first f16 col

  // stage Q (prescaled by 1/8), f16
  {
    const float* qrow = qkv + (size_t)(nb + sr)*768 + h*64 + sc;
    float4 A = *(const float4*)(qrow+0), B = *(const float4*)(qrow+4),
           Cc = *(const float4*)(qrow+8), D = *(const float4*)(qrow+12);
    uint4 w0 = make_uint4(pk2(A.x*0.125f,A.y*0.125f), pk2(A.z*0.125f,A.w*0.125f),
                          pk2(B.x*0.125f,B.y*0.125f), pk2(B.z*0.125f,B.w*0.125f));
    uint4 w1 = make_uint4(pk2(Cc.x*0.125f,Cc.y*0.125f), pk2(Cc.z*0.125f,Cc.w*0.125f),
                          pk2(D.x*0.125f,D.y*0.125f), pk2(D.z*0.125f,D.w*0.125f));
    *(uint4*)&QTh[rotIdx(sr, sc>>1)] = w0;
    *(uint4*)&QTh[rotIdx(sr, (sc>>1)+4)] = w1;
  }

  float4 o0 = make_float4(0,0,0,0), o1 = o0, o2 = o0, o3 = o0;
  float4 dn = make_float4(0,0,0,0);

  for (int mt = 0; mt < NN/MCH/64; mt++){
    int mb = mc*(NN/MCH) + mt*64;
    __syncthreads();                    // prev PV done; Q staged on iter 0
    {
      const float* krow = qkv + (size_t)(mb + sr)*768 + 256 + h*64 + sc;
      const float* vrow = krow + 256;
      float4 A = *(const float4*)(krow+0), B = *(const float4*)(krow+4),
             Cc = *(const float4*)(krow+8), D = *(const float4*)(krow+12);
      uint4 w0 = make_uint4(pk2(A.x,A.y), pk2(A.z,A.w), pk2(B.x,B.y), pk2(B.z,B.w));
      uint4 w1 = make_uint4(pk2(Cc.x,Cc.y), pk2(Cc.z,Cc.w), pk2(D.x,D.y), pk2(D.z,D.w));
      *(uint4*)&KTh[rotIdx(sr, sc>>1)] = w0;
      *(uint4*)&KTh[rotIdx(sr, (sc>>1)+4)] = w1;
      _Float16* VH = (_Float16*)VTh;
      int p = sr >> 1, hf = sr & 1;
      #pragma unroll
      for (int i = 0; i < 4; i++){
        float4 v = *(const float4*)(vrow + 4*i);
        int dd = sc + 4*i;
        VH[2*rotIdx(dd+0, p) + hf] = (_Float16)v.x;
        VH[2*rotIdx(dd+1, p) + hf] = (_Float16)v.y;
        VH[2*rotIdx(dd+2, p) + hf] = (_Float16)v.z;
        VH[2*rotIdx(dd+3, p) + hf] = (_Float16)v.w;
      }
    }
    __syncthreads();
    // scores: s_i = n-row n0+i, components = m-cols m0..m0+3
    float4 s0 = make_float4(0,0,0,0), s1 = s0, s2 = s0, s3 = s0;
    #pragma unroll
    for (int c = 0; c < 8; c++){
      uint4 qa = *(uint4*)&QTh[rotIdx(n0+0, c<<2)];
      uint4 qb = *(uint4*)&QTh[rotIdx(n0+1, c<<2)];
      uint4 qc = *(uint4*)&QTh[rotIdx(n0+2, c<<2)];
      uint4 qd = *(uint4*)&QTh[rotIdx(n0+3, c<<2)];
      uint4 ka = *(uint4*)&KTh[rotIdx(m0+0, c<<2)];
      uint4 kb = *(uint4*)&KTh[rotIdx(m0+1, c<<2)];
      uint4 kc = *(uint4*)&KTh[rotIdx(m0+2, c<<2)];
      uint4 kd = *(uint4*)&KTh[rotIdx(m0+3, c<<2)];
      s0.x = dotu4(qa,ka,s0.x); s0.y = dotu4(qa,kb,s0.y); s0.z = dotu4(qa,kc,s0.z); s0.w = dotu4(qa,kd,s0.w);
      s1.x = dotu4(qb,ka,s1.x); s1.y = dotu4(qb,kb,s1.y); s1.z = dotu4(qb,kc,s1.z); s1.w = dotu4(qb,kd,s1.w);
      s2.x = dotu4(qc,ka,s2.x); s2.y = dotu4(qc,kb,s2.y); s2.z = dotu4(qc,kc,s2.z); s2.w = dotu4(qc,kd,s2.w);
      s3.x = dotu4(qd,ka,s3.x); s3.y = dotu4(qd,kb,s3.y); s3.z = dotu4(qd,kc,s3.z); s3.w = dotu4(qd,kd,s3.w);
    }
    exp4(s0); exp4(s1); exp4(s2); exp4(s3);
    dn.x += s0.x+s0.y+s0.z+s0.w;
    dn.y += s1.x+s1.y+s1.z+s1.w;
    dn.z += s2.x+s2.y+s2.z+s2.w;
    dn.w += s3.x+s3.y+s3.z+s3.w;
    // P[n][m-pairs] f16 (separate buffer -> no barrier needed before write)
    *(uint2*)&Ph[rotIdx(n0+0, td<<1)] = make_uint2(pk2(s0.x,s0.y), pk2(s0.z,s0.w));
    *(uint2*)&Ph[rotIdx(n0+1, td<<1)] = make_uint2(pk2(s1.x,s1.y), pk2(s1.z,s1.w));
    *(uint2*)&Ph[rotIdx(n0+2, td<<1)] = make_uint2(pk2(s2.x,s2.y), pk2(s2.z,s2.w));
    *(uint2*)&Ph[rotIdx(n0+3, td<<1)] = make_uint2(pk2(s3.x,s3.y), pk2(s3.z,s3.w));
    __syncthreads();                    // P fully written
    // PV: o_i = n-row n0+i, components = d-cols d0..d0+3
    #pragma unroll
    for (int c = 0; c < 8; c++){
      uint4 pa = *(uint4*)&Ph[rotIdx(n0+0, c<<2)];
      uint4 pb = *(uint4*)&Ph[rotIdx(n0+1, c<<2)];
      uint4 pc = *(uint4*)&Ph[rotIdx(n0+2, c<<2)];
      uint4 pd = *(uint4*)&Ph[rotIdx(n0+3, c<<2)];
      uint4 va = *(uint4*)&VTh[rotIdx(d0+0, c<<2)];
      uint4 vb = *(uint4*)&VTh[rotIdx(d0+1, c<<2)];
      uint4 vc = *(uint4*)&VTh[rotIdx(d0+2, c<<2)];
      uint4 vd = *(uint4*)&VTh[rotIdx(d0+3, c<<2)];
      o0.x = dotu4(pa,va,o0.x); o0.y = dotu4(pa,vb,o0.y); o0.z = dotu4(pa,vc,o0.z); o0.w = dotu4(pa,vd,o0.w);
      o1.x = dotu4(pb,va,o1.x); o1.y = dotu4(pb,vb,o1.y); o1.z = dotu4(pb,vc,o1.z); o1.w = dotu4(pb,vd,o1.w);
      o2.x = dotu4(pc,va,o2.x); o2.y = dotu4(pc,vb,o2.y); o2.z = dotu4(pc,vc,o2.z); o2.w = dotu4(pc,vd,o2.w);
      o3.x = dotu4(pd,va,o3.x); o3.y = dotu4(pd,vb,o3.y); o3.z = dotu4(pd,vc,o3.z); o3.w = dotu4(pd,vd,o3.w);
    }
  }

  float* ob = opart + ((size_t)mc*NN + nb)*C + h*64;
  *(float4*)(ob + (n0+0)*C + d0) = o0;
  *(float4*)(ob + (n0+1)*C + d0) = o1;
  *(float4*)(ob + (n0+2)*C + d0) = o2;
  *(float4*)(ob + (n0+3)*C + d0) = o3;
  // dn components = n-rows; sum over td groups (bits 4,5 of tid) then 4 waves via atomics
  dn.x += __shfl_xor(dn.x, 16); dn.y += __shfl_xor(dn.y, 16);
  dn.z += __shfl_xor(dn.z, 16); dn.w += __shfl_xor(dn.w, 16);
  dn.x += __shfl_xor(dn.x, 32); dn.y += __shfl_xor(dn.y, 32);
  dn.z += __shfl_xor(dn.z, 32); dn.w += __shfl_xor(dn.w, 32);
  if ((tid & 63) < 16){
    float* db = dpart + ((size_t)mc*NN + nb + n0)*AHD + h;
    atomicAdd(&db[0*AHD], dn.x); atomicAdd(&db[1*AHD], dn.y);
    atomicAdd(&db[2*AHD], dn.z); atomicAdd(&db[3*AHD], dn.w);
  }
}

__global__ __launch_bounds__(256) void attnred_k(const float* __restrict__ opart, const float* __restrict__ dpart,
                                                 float* omean){
  int r0 = blockIdx.x*128, c = threadIdx.x;
  int head = c >> 6;
  float s = 0.f;
  for (int r = 0; r < 128; r++){
    int n = r0 + r;
    float dsum = 0.f, osum = 0.f;
    #pragma unroll
    for (int mc = 0; mc < MCH; mc++){
      dsum += dpart[((size_t)mc*NN + n)*AHD + head];
      osum += opart[((size_t)mc*NN + n)*C + c];
    }
    s += osum / (dsum + 1e-16f);
  }
  atomicAdd(&omean[c], s*(1.f/4096.f));
}

__global__ __launch_bounds__(256) void attnproj_k(const float* __restrict__ omean, const float* __restrict__ opw,
                                                  const float* __restrict__ opb, float* attnp){
  __shared__ float sh[256];
  int j = threadIdx.x;
  sh[j] = omean[j];
  __syncthreads();
  float acc = opb[j];
  for (int k = 0; k < 256; k++) acc += sh[k]*opw[j*256 + k];
  attnp[j] = acc;
}

__global__ __launch_bounds__(512) void fus1_k(const float* __restrict__ meanp, const float* __restrict__ maxp,
                                              const float* __restrict__ attnp, const float* __restrict__ fw1,
                                              const float* __restrict__ fb1, float* g1){
  __shared__ float comb[768];
  for (int i = threadIdx.x; i < 768; i += 512)
    comb[i] = (i < 256) ? meanp[i] : (i < 512 ? maxp[i-256] : attnp[i-512]);
  __syncthreads();
  int j = threadIdx.x;
  float acc = fb1[j];
  for (int k = 0; k < 768; k++) acc += comb[k]*fw1[k*512 + j];
  g1[j] = fmaxf(acc, 0.f);
}

__global__ __launch_bounds__(256) void fus2_k(const float* __restrict__ g1, const float* __restrict__ fw2,
                                              const float* __restrict__ fb2, float* __restrict__ out){
  __shared__ float g[512];
  g[threadIdx.x] = g1[threadIdx.x];
  g[threadIdx.x + 256] = g1[threadIdx.x + 256];
  __syncthreads();
  int j = threadIdx.x;
  float acc = fb2[j];
  for (int k = 0; k < 512; k++) acc += g[k]*fw2[k*256 + j];
  out[j] = fmaxf(acc, 0.f);
}

extern "C" void kernel_launch(void* const* d_in, const int* in_sizes, int n_in,
                              void* d_out, int out_size, void* d_ws, size_t ws_size,
                              hipStream_t stream){
  const float* x     = (const float*)d_in[0];
  const int*   srcv  = (const int*)d_in[1];
  const int*   dstv  = (const int*)d_in[2];
  const float* eattr = (const float*)d_in[3];
  const int*   etyp  = (const int*)d_in[4];
  const float* W0    = (const float*)d_in[5];
  const float* W12   = (const float*)d_in[6];
  const float* attS  = (const float*)d_in[7];
  const float* attD  = (const float*)d_in[8];
  const float* attE  = (const float*)d_in[9];
  const float* linE  = (const float*)d_in[10];
  const float* bias  = (const float*)d_in[11];
  const float* etw   = (const float*)d_in[12];
  const float* ipw   = (const float*)d_in[13];
  const float* ipb   = (const float*)d_in[14];
  const float* opw   = (const float*)d_in[15];
  const float* opb   = (const float*)d_in[16];
  const float* fw1   = (const float*)d_in[17];
  const float* fb1   = (const float*)d_in[18];
  const float* fw2   = (const float*)d_in[19];
  const float* fb2   = (const float*)d_in[20];
  float* out = (float*)d_out;

  if (ws_size < (size_t)WS_WORDS*4) return;

  int*   ip = (int*)d_ws;
  float* fp = (float*)d_ws;

  zero_k<<<(NZERO + 255)/256, 256, 0, stream>>>(fp + F_DPART, NZERO, ip + W_CURSOR, NN*T);
  initmax_k<<<1, 256, 0, stream>>>(fp + F_MAXP);

  hist_k<<<EE/256, 256, 0, stream>>>(dstv, etyp, ip + W_CURSOR);
  scan_k<<<1, 1024, 0, stream>>>(ip + W_CURSOR, ip + W_OFF, ip + W_CURSOR);
  scatter_k<<<EE/256, 256, 0, stream>>>(dstv, etyp, ip + W_CURSOR, ip + W_SORTED);

  transpose_k<<<768, 256, 0, stream>>>(ipw, fp + F_WT);

  // all-layer prepass: we, se, sloop
  we2_k<<<dim3(T, LL), 256, 0, stream>>>(linE, attE, fp + F_WE);
  se_k<<<dim3(EE/256, LL), 256, 0, stream>>>(eattr, etyp, fp + F_WE, fp + F_SE);
  sloop_k<<<dim3((NN*T)/256, LL), 256, 0, stream>>>(ip + W_OFF, ip + W_SORTED, fp + F_SE, fp + F_SLOOP);

  for (int l = 0; l < 3; l++){
    const float* hin = (l == 0) ? x : (fp + F_H);
    long htstr = (l == 0) ? 0 : (long)NN*C;
    int K = (l == 0) ? DIN : C;
    const float* Wb = (l == 0) ? W0 : (W12 + (size_t)(l-1)*C*C);
    long wtstr = (l == 0) ? (long)DIN*C : (long)2*C*C;

    gemm_k<<<dim3(NN/8, T), 256, 0, stream>>>(hin, htstr, K, Wb, wtstr, attS, attD, l,
                                              fp + F_XL, fp + F_SSRC, fp + F_SDST);
    agg_k<<<dim3(NN, T), 256, 0, stream>>>(fp + F_XL, fp + F_SSRC, fp + F_SDST,
                                           fp + F_SE + (size_t)l*EE,
                                           fp + F_SLOOP + (size_t)l*(NN*T),
                                           ip + W_OFF, ip + W_SORTED, srcv,
                                           bias, fp + F_H, l);
  }

  hacc_k<<<NN, 256, 0, stream>>>(fp + F_H, etw, fp + F_HACC);
  colstats_k<<<32, 256, 0, stream>>>(fp + F_HACC, fp + F_MEANP, fp + F_MAXP);

  qkv_k<<<dim3(NN/8, 3), 256, 0, stream>>>(fp + F_HACC, fp + F_WT, ipb, fp + F_QKV);
  attn_k<<<dim3(NN/64, AHD, MCH), 256, 0, stream>>>(fp + F_QKV, fp + F_OPART, fp + F_DPART);
  attnred_k<<<32, 256, 0, stream>>>(fp + F_OPART, fp + F_DPART, fp + F_OMEAN);
  attnproj_k<<<1, 256, 0, stream>>>(fp + F_OMEAN, opw, opb, fp + F_ATTNP);

  fus1_k<<<1, 512, 0, stream>>>(fp + F_MEANP, fp + F_MAXP, fp + F_ATTNP, fw1, fb1, fp + F_G1);
  fus2_k<<<1, 256, 0, stream>>>(fp + F_G1, fw2, fb2, out);
}

// Round 10
// 672.154 us; speedup vs baseline: 1.4996x; 1.1320x over previous
//
#include <hip/hip_runtime.h>
#include <math.h>

#define T 4
#define LL 3
#define C 256
#define DIN 20
#define NN 4096
#define EE 65536
#define AHD 4
#define MCH 2     // attention m-chunks; 2 keeps co-resident stream drift < 4MB L2/XCD (R8 post-mortem)

// ---- workspace layout (4-byte word offsets) ----
#define W_OFF    0                    // int[N*T+1]
#define W_CURSOR 16640                // int[N*T]  (also hist counts)
#define W_SORTED 33024                // int[E]
#define F_XL     98560                // float[T][N][C]
#define F_H      (F_XL + T*NN*C)      // float[T][N][C]
#define F_OPART  F_XL                 // alias: float[MCH][N][C] fits dead F_XL region
#define F_SSRC   (F_H + T*NN*C)       // float[T][N]
#define F_SDST   (F_SSRC + T*NN)      // float[T][N]
#define F_SE     (F_SDST + T*NN)      // float[LL][E]
#define F_SLOOP  (F_SE + LL*EE)       // float[LL][N*T] indexed l*NT + n*T+t
#define F_WE     (F_SLOOP + LL*T*NN)  // float[T*LL][10] (padded 128)
#define F_HACC   (F_WE + 128)         // float[N][C]
#define F_WT     (F_HACC + NN*C)      // u32[128][768] packed f16-pair in_proj_w^T (region reserved 768*256)
#define F_QKV    (F_WT + 768*256)     // float[N][768]
#define F_DPART  (F_QKV + NN*768)     // float[MCH][N][AH]
#define F_MEANP  (F_DPART + MCH*NN*AHD) // float[C]
#define F_MAXP   (F_MEANP + C)        // float[C]
#define F_OMEAN  (F_MAXP + C)         // float[C]
#define F_ATTNP  (F_OMEAN + C)        // float[C]
#define F_G1     (F_ATTNP + C)        // float[512]
#define U_W12P   (F_G1 + 512)         // u32[T*2][128][256] packed f16-pair W12
#define WS_WORDS (U_W12P + 262144)
#define NZERO (MCH*NN*AHD + 3*C)      // dpart (atomic target) + meanp, maxp, omean

static __device__ __forceinline__ float lrelu(float x){ return x > 0.f ? x : 0.2f*x; }
static __device__ __forceinline__ float eluf(float x){ return x > 0.f ? x : __expf(x) - 1.f; }
static __device__ __forceinline__ void exp4(float4& s){
  s.x = __expf(s.x); s.y = __expf(s.y); s.z = __expf(s.z); s.w = __expf(s.w);
}

typedef _Float16 half2_t __attribute__((ext_vector_type(2)));
static __device__ __forceinline__ unsigned pk2(float x, float y){
  half2_t h; h.x = (_Float16)x; h.y = (_Float16)y;
  return __builtin_bit_cast(unsigned, h);
}
#if __has_builtin(__builtin_amdgcn_fdot2)
static __device__ __forceinline__ float fdot2u(unsigned a, unsigned b, float c){
  return __builtin_amdgcn_fdot2(__builtin_bit_cast(half2_t, a), __builtin_bit_cast(half2_t, b), c, false);
}
#else
static __device__ __forceinline__ float fdot2u(unsigned a, unsigned b, float c){
  half2_t ha = __builtin_bit_cast(half2_t, a), hb = __builtin_bit_cast(half2_t, b);
  return c + (float)ha.x*(float)hb.x + (float)ha.y*(float)hb.y;
}
#endif
static __device__ __forceinline__ float dotu4(uint4 a, uint4 b, float c){
  c = fdot2u(a.x, b.x, c); c = fdot2u(a.y, b.y, c);
  c = fdot2u(a.z, b.z, c); c = fdot2u(a.w, b.w, c);
  return c;
}
// swizzled LDS index: row-major [row][32 u32], chunks of 4 u32 rotated by (row>>2)
static __device__ __forceinline__ int rotIdx(int row, int p){
  return row*32 + ((((p >> 2) + (row >> 2)) & 7) << 2) + (p & 3);
}

static __device__ inline void atomicMaxF(float* addr, float val){
  int* ai = (int*)addr;
  int old = __float_as_int(*addr);
  while (__int_as_float(old) < val){
    int assumed = old;
    old = atomicCAS(ai, assumed, __float_as_int(val));
    if (old == assumed) break;
  }
}

__global__ __launch_bounds__(256) void zero_k(float* fz, int nf, int* iz, int ni){
  int i = blockIdx.x*256 + threadIdx.x;
  if (i < nf) fz[i] = 0.f;
  if (i < ni) iz[i] = 0;
}
__global__ __launch_bounds__(256) void initmax_k(float* maxp){ maxp[threadIdx.x] = -1e30f; }

__global__ __launch_bounds__(256) void hist_k(const int* __restrict__ dst, const int* __restrict__ ety, int* cnt){
  int e = blockIdx.x*256 + threadIdx.x;
  if (e < EE) atomicAdd(&cnt[dst[e]*T + ety[e]], 1);
}

__global__ __launch_bounds__(1024) void scan_k(int* cnt, int* off, int* cursor){
  __shared__ int part[1024];
  int tid = threadIdx.x;
  int base = tid*16;
  int loc[16]; int s = 0;
  for (int i = 0; i < 16; i++){ loc[i] = cnt[base+i]; s += loc[i]; }
  part[tid] = s; __syncthreads();
  int v = s;
  for (int offn = 1; offn < 1024; offn <<= 1){
    int add = (tid >= offn) ? part[tid-offn] : 0;
    __syncthreads();
    v += add; part[tid] = v;
    __syncthreads();
  }
  int excl = v - s;
  for (int i = 0; i < 16; i++){ off[base+i] = excl; cursor[base+i] = excl; excl += loc[i]; }
  if (tid == 1023) off[NN*T] = excl;
}

__global__ __launch_bounds__(256) void scatter_k(const int* __restrict__ dst, const int* __restrict__ ety,
                                                 int* cursor, int* sorted){
  int e = blockIdx.x*256 + threadIdx.x;
  if (e < EE){
    int p = atomicAdd(&cursor[dst[e]*T + ety[e]], 1);
    sorted[p] = e;
  }
}

// pack W12 [t][i][256][256] -> f16-pair u32 [t*2+i][128][256]
__global__ __launch_bounds__(256) void pack12_k(const float* __restrict__ w, unsigned* __restrict__ wp){
  int b = blockIdx.y, k2 = blockIdx.x, c = threadIdx.x;
  const float* s = w + (size_t)b*C*C;
  wp[((size_t)b*128 + k2)*C + c] = pk2(s[(2*k2)*C + c], s[(2*k2+1)*C + c]);
}

// pack in_proj_w [768][256] -> transposed f16-pair u32 [128][768]
__global__ __launch_bounds__(256) void packT_k(const float* __restrict__ ipw, unsigned* __restrict__ wtp){
  int k2 = blockIdx.x, j = blockIdx.y*256 + threadIdx.x;
  wtp[k2*768 + j] = pk2(ipw[(size_t)j*C + 2*k2], ipw[(size_t)j*C + 2*k2 + 1]);
}

// we[t][l][k] = sum_c lin_edge_w[t,l,k,c] * att_edge[t,l,0,c]  -- all (t,l) in one launch
__global__ __launch_bounds__(256) void we2_k(const float* __restrict__ linE, const float* __restrict__ attE,
                                             float* we){
  int t = blockIdx.x, l = blockIdx.y, c = threadIdx.x;
  __shared__ float part[10*C];
  float ae = attE[(t*LL + l)*C + c];
  const float* lw = linE + (size_t)((t*LL + l)*10)*C;
  for (int k = 0; k < 10; k++) part[k*C + c] = lw[k*C + c]*ae;
  __syncthreads();
  if (c < 10){
    float s = 0.f;
    for (int i = 0; i < C; i++) s += part[c*C + i];
    we[(t*LL + l)*10 + c] = s;
  }
}

// layer 0 only (K=20, cheap): fp32 path, fused ssd reduction
__global__ __launch_bounds__(256) void gemm_k(const float* __restrict__ hin, int K,
                                              const float* __restrict__ Wb, long wtstr,
                                              const float* __restrict__ attS, const float* __restrict__ attD,
                                              int l, float* __restrict__ xlo,
                                              float* __restrict__ ssrc, float* __restrict__ sdst){
  int t = blockIdx.y;
  const float* h = hin;                       // l==0: shared x across types
  const float* W = Wb + (size_t)t*wtstr;
  int n0 = blockIdx.x*8;
  __shared__ float sh[8*256];
  __shared__ float red[64];
  for (int j = 0; j < 8; j++)
    for (int k = threadIdx.x; k < K; k += 256)
      sh[j*K + k] = h[(n0+j)*K + k];
  __syncthreads();
  float acc[8] = {0,0,0,0,0,0,0,0};
  int c = threadIdx.x;
  for (int k = 0; k < K; k += 4){
    float w0 = W[(k+0)*C + c], w1 = W[(k+1)*C + c], w2 = W[(k+2)*C + c], w3 = W[(k+3)*C + c];
    #pragma unroll
    for (int j = 0; j < 8; j++){
      float4 h4 = *(const float4*)&sh[j*K + k];
      acc[j] += w0*h4.x + w1*h4.y + w2*h4.z + w3*h4.w;
    }
  }
  #pragma unroll
  for (int j = 0; j < 8; j++) xlo[(t*NN + n0 + j)*C + c] = acc[j];
  float aS = attS[(t*LL + l)*C + c], aD = attD[(t*LL + l)*C + c];
  int lane = c & 63, w = c >> 6;
  #pragma unroll
  for (int j = 0; j < 8; j++){
    float v1 = acc[j]*aS, v2 = acc[j]*aD;
    #pragma unroll
    for (int off = 32; off > 0; off >>= 1){ v1 += __shfl_down(v1, off); v2 += __shfl_down(v2, off); }
    if (lane == 0){ red[j*8 + w] = v1; red[j*8 + 4 + w] = v2; }
  }
  __syncthreads();
  if (c < 16){
    int j = c >> 1, which = c & 1;
    const float* r = red + j*8 + which*4;
    float s = r[0] + r[1] + r[2] + r[3];
    (which ? sdst : ssrc)[t*NN + n0 + j] = s;
  }
}

// R10: layers 1,2 (K=256) as f16-pair dot2 GEMM. 128 thr, 8 rows x 2 cols/thread.
// Per 8-k chunk: 8 ds_read_b128 (96cyc) vs 64 dot2 (128cyc) -> VALU-bound at
// half the fp32 VALU cost (R9 post-mortem: fp32 gemm_k was LDS-issue-bound,
// 96cyc LDS vs 64cyc VALU per 4-k chunk).
__global__ __launch_bounds__(128) void gemm16_k(const float* __restrict__ hin,
                                                const unsigned* __restrict__ w12p,
                                                const float* __restrict__ attS, const float* __restrict__ attD,
                                                int l, float* __restrict__ xlo,
                                                float* __restrict__ ssrc, float* __restrict__ sdst){
  int t = blockIdx.y;
  const float* h = hin + (size_t)t*NN*C;
  const unsigned* W = w12p + ((size_t)(t*2 + (l-1)))*128*C;
  int n0 = blockIdx.x*8;
  int tid = threadIdx.x;
  __shared__ unsigned sh[8*128];
  __shared__ float red[32];
  #pragma unroll
  for (int j = 0; j < 8; j++){
    float2 hv = *(const float2*)&h[(size_t)(n0+j)*C + 2*tid];
    sh[j*128 + tid] = pk2(hv.x, hv.y);
  }
  __syncthreads();
  float a0[8] = {0,0,0,0,0,0,0,0};
  float a1[8] = {0,0,0,0,0,0,0,0};
  int c0 = tid, c1 = tid + 128;
  for (int k2 = 0; k2 < 128; k2 += 4){
    unsigned w00 = W[(k2+0)*C + c0], w01 = W[(k2+1)*C + c0],
             w02 = W[(k2+2)*C + c0], w03 = W[(k2+3)*C + c0];
    unsigned w10 = W[(k2+0)*C + c1], w11 = W[(k2+1)*C + c1],
             w12 = W[(k2+2)*C + c1], w13 = W[(k2+3)*C + c1];
    #pragma unroll
    for (int j = 0; j < 8; j++){
      uint4 hp = *(uint4*)&sh[j*128 + k2];
      a0[j] = fdot2u(hp.x, w00, a0[j]); a0[j] = fdot2u(hp.y, w01, a0[j]);
      a0[j] = fdot2u(hp.z, w02, a0[j]); a0[j] = fdot2u(hp.w, w03, a0[j]);
      a1[j] = fdot2u(hp.x, w10, a1[j]); a1[j] = fdot2u(hp.y, w11, a1[j]);
      a1[j] = fdot2u(hp.z, w12, a1[j]); a1[j] = fdot2u(hp.w, w13, a1[j]);
    }
  }
  #pragma unroll
  for (int j = 0; j < 8; j++){
    xlo[(t*NN + n0 + j)*C + c0] = a0[j];
    xlo[(t*NN + n0 + j)*C + c1] = a1[j];
  }
  float aS0 = attS[(t*LL + l)*C + c0], aS1 = attS[(t*LL + l)*C + c1];
  float aD0 = attD[(t*LL + l)*C + c0], aD1 = attD[(t*LL + l)*C + c1];
  int lane = tid & 63, w = tid >> 6;   // 2 waves
  #pragma unroll
  for (int j = 0; j < 8; j++){
    float v1 = a0[j]*aS0 + a1[j]*aS1;
    float v2 = a0[j]*aD0 + a1[j]*aD1;
    #pragma unroll
    for (int off = 32; off > 0; off >>= 1){ v1 += __shfl_down(v1, off); v2 += __shfl_down(v2, off); }
    if (lane == 0){ red[j*4 + w*2 + 0] = v1; red[j*4 + w*2 + 1] = v2; }
  }
  __syncthreads();
  if (tid < 16){
    int j = tid >> 1, which = tid & 1;
    float s = red[j*4 + which] + red[j*4 + 2 + which];
    (which ? sdst : ssrc)[t*NN + n0 + j] = s;
  }
}

// all layers at once: se[l][e]
__global__ __launch_bounds__(256) void se_k(const float* __restrict__ eattr, const int* __restrict__ ety,
                                            const float* __restrict__ we, float* se){
  int e = blockIdx.x*256 + threadIdx.x;
  int l = blockIdx.y;
  if (e < EE){
    const float* w = we + (ety[e]*LL + l)*10;
    const float* ea = eattr + e*10;
    float s = 0.f;
    #pragma unroll
    for (int k = 0; k < 10; k++) s += ea[k]*w[k];
    se[(size_t)l*EE + e] = s;
  }
}

// all layers at once: sloop[l][i]
__global__ __launch_bounds__(256) void sloop_k(const int* __restrict__ off, const int* __restrict__ sorted,
                                               const float* __restrict__ se, float* sloop){
  int i = blockIdx.x*256 + threadIdx.x;
  int l = blockIdx.y;
  if (i < NN*T){
    int o0 = off[i], o1 = off[i+1];
    const float* sel = se + (size_t)l*EE;
    float s = 0.f;
    for (int j = o0; j < o1; j++) s += sel[sorted[j]];
    int dg = o1 - o0;
    sloop[(size_t)l*(NN*T) + i] = s / (float)(dg > 0 ? dg : 1);
  }
}

__global__ __launch_bounds__(256) void agg_k(const float* __restrict__ xl, const float* __restrict__ ssrc,
                                             const float* __restrict__ sdst, const float* __restrict__ se,
                                             const float* __restrict__ sloop, const int* __restrict__ off,
                                             const int* __restrict__ sorted, const int* __restrict__ srcv,
                                             const float* __restrict__ bias, float* __restrict__ hout, int l){
  int n = blockIdx.x, t = blockIdx.y;
  int i = n*T + t;
  int o0 = off[i];
  int deg = off[i+1] - o0;
  if (deg > 512) deg = 512;
  __shared__ float sc[512];
  __shared__ int sj[512];
  __shared__ float sInv, sAL;
  for (int j = threadIdx.x; j < deg; j += 256){
    int e = sorted[o0 + j];
    int sn = srcv[e];
    sc[j] = lrelu(ssrc[t*NN + sn] + sdst[t*NN + n] + se[e]);
    sj[j] = sn;
  }
  __syncthreads();
  if (threadIdx.x == 0){
    float al = lrelu(ssrc[t*NN + n] + sdst[t*NN + n] + sloop[i]);
    float mx = al;
    for (int j = 0; j < deg; j++) mx = fmaxf(mx, sc[j]);
    float al_e = __expf(al - mx);
    float ssum = al_e;
    for (int j = 0; j < deg; j++){ float ex = __expf(sc[j] - mx); sc[j] = ex; ssum += ex; }
    sInv = 1.f/(ssum + 1e-16f);
    sAL = al_e;
  }
  __syncthreads();
  int c = threadIdx.x;
  float acc = sAL * xl[(t*NN + n)*C + c];
  for (int j = 0; j < deg; j++) acc += sc[j] * xl[(t*NN + sj[j])*C + c];
  acc = acc*sInv + bias[(t*LL + l)*C + c];
  hout[(t*NN + n)*C + c] = eluf(acc);
}

__global__ __launch_bounds__(256) void hacc_k(const float* __restrict__ h, const float* __restrict__ etw,
                                              float* __restrict__ hacc){
  int n = blockIdx.x, c = threadIdx.x;
  float e0 = etw[0], e1 = etw[1], e2 = etw[2], e3 = etw[3];
  float m = fmaxf(fmaxf(e0,e1), fmaxf(e2,e3));
  float w0 = __expf(e0-m), w1 = __expf(e1-m), w2 = __expf(e2-m), w3 = __expf(e3-m);
  float inv = 1.f/(w0+w1+w2+w3);
  float s = w0*h[(0*NN+n)*C+c] + w1*h[(1*NN+n)*C+c] + w2*h[(2*NN+n)*C+c] + w3*h[(3*NN+n)*C+c];
  hacc[n*C + c] = s*inv;
}

__global__ __launch_bounds__(256) void colstats_k(const float* __restrict__ hacc, float* meanp, float* maxp){
  int r0 = blockIdx.x*128, c = threadIdx.x;
  float sm = 0.f, mx = -1e30f;
  for (int r = 0; r < 128; r++){
    float v = hacc[(r0+r)*C + c];
    sm += v; mx = fmaxf(mx, v);
  }
  atomicAdd(&meanp[c], sm*(1.f/4096.f));
  atomicMaxF(&maxp[c], mx);
}

// R10: qkv as f16-pair dot2 GEMM (same structure as gemm16_k), packed WT
__global__ __launch_bounds__(128) void qkv16_k(const float* __restrict__ hacc,
                                               const unsigned* __restrict__ wtp,
                                               const float* __restrict__ ipb, float* __restrict__ qkv){
  int p = blockIdx.y;
  int n0 = blockIdx.x*8;
  int tid = threadIdx.x;
  __shared__ unsigned sh[8*128];
  #pragma unroll
  for (int j = 0; j < 8; j++){
    float2 hv = *(const float2*)&hacc[(size_t)(n0+j)*C + 2*tid];
    sh[j*128 + tid] = pk2(hv.x, hv.y);
  }
  __syncthreads();
  float a0[8] = {0,0,0,0,0,0,0,0};
  float a1[8] = {0,0,0,0,0,0,0,0};
  int c0 = p*256 + tid, c1 = c0 + 128;
  for (int k2 = 0; k2 < 128; k2 += 4){
    unsigned w00 = wtp[(k2+0)*768 + c0], w01 = wtp[(k2+1)*768 + c0],
             w02 = wtp[(k2+2)*768 + c0], w03 = wtp[(k2+3)*768 + c0];
    unsigned w10 = wtp[(k2+0)*768 + c1], w11 = wtp[(k2+1)*768 + c1],
             w12 = wtp[(k2+2)*768 + c1], w13 = wtp[(k2+3)*768 + c1];
    #pragma unroll
    for (int j = 0; j < 8; j++){
      uint4 hp = *(uint4*)&sh[j*128 + k2];
      a0[j] = fdot2u(hp.x, w00, a0[j]); a0[j] = fdot2u(hp.y, w01, a0[j]);
      a0[j] = fdot2u(hp.z, w02, a0[j]); a0[j] = fdot2u(hp.w, w03, a0[j]);
      a1[j] = fdot2u(hp.x, w10, a1[j]); a1[j] = fdot2u(hp.y, w11, a1[j]);
      a1[j] = fdot2u(hp.z, w12, a1[j]); a1[j] = fdot2u(hp.w, w13, a1[j]);
    }
  }
  float b0 = ipb[c0], b1 = ipb[c1];
  #pragma unroll
  for (int j = 0; j < 8; j++){
    qkv[(size_t)(n0+j)*768 + c0] = a0[j] + b0;
    qkv[(size_t)(n0+j)*768 + c1] = a1[j] + b1;
  }
}

// R9: f16/dot2 flash attn; MCH=2 + (256,2) residency regime (L2-drift model)
__global__ __launch_bounds__(256, 2) void attn_k(const float* __restrict__ qkv,
                                                 float* __restrict__ opart,
                                                 float* __restrict__ dpart){
  __shared__ unsigned QTh[64*32];  // [n][kk-pairs] f16, rotated chunks
  __shared__ unsigned KTh[64*32];  // [m][kk-pairs]
  __shared__ unsigned VTh[64*32];  // [d][m-pairs]
  __shared__ unsigned Ph [64*32];  // [n][m-pairs]
  int tid = threadIdx.x;
  int nb = blockIdx.x * 64, h = blockIdx.y, mc = blockIdx.z;
  int tn = tid & 15, td = tid >> 4;
  int n0 = tn*4, m0 = td*4, d0 = td*4;
  int sr = tid >> 2, sc = (tid & 3)*16;

  {
    const float* qrow = qkv + (size_t)(nb + sr)*768 + h*64 + sc;
    float4 A = *(const float4*)(qrow+0), B = *(const float4*)(qrow+4),
           Cc = *(const float4*)(qrow+8), D = *(const float4*)(qrow+12);
    uint4 w0 = make_uint4(pk2(A.x*0.125f,A.y*0.125f), pk2(A.z*0.125f,A.w*0.125f),
                          pk2(B.x*0.125f,B.y*0.125f), pk2(B.z*0.125f,B.w*0.125f));
    uint4 w1 = make_uint4(pk2(Cc.x*0.125f,Cc.y*0.125f), pk2(Cc.z*0.125f,Cc.w*0.125f),
                          pk2(D.x*0.125f,D.y*0.125f), pk2(D.z*0.125f,D.w*0.125f));
    *(uint4*)&QTh[rotIdx(sr, sc>>1)] = w0;
    *(uint4*)&QTh[rotIdx(sr, (sc>>1)+4)] = w1;
  }

  float4 o0 = make_float4(0,0,0,0), o1 = o0, o2 = o0, o3 = o0;
  float4 dn = make_float4(0,0,0,0);

  for (int mt = 0; mt < NN/MCH/64; mt++){
    int mb = mc*(NN/MCH) + mt*64;
    __syncthreads();
    {
      const float* krow = qkv + (size_t)(mb + sr)*768 + 256 + h*64 + sc;
      const float* vrow = krow + 256;
      float4 A = *(const float4*)(krow+0), B = *(const float4*)(krow+4),
             Cc = *(const float4*)(krow+8), D = *(const float4*)(krow+12);
      uint4 w0 = make_uint4(pk2(A.x,A.y), pk2(A.z,A.w), pk2(B.x,B.y), pk2(B.z,B.w));
      uint4 w1 = make_uint4(pk2(Cc.x,Cc.y), pk2(Cc.z,Cc.w), pk2(D.x,D.y), pk2(D.z,D.w));
      *(uint4*)&KTh[rotIdx(sr, sc>>1)] = w0;
      *(uint4*)&KTh[rotIdx(sr, (sc>>1)+4)] = w1;
      _Float16* VH = (_Float16*)VTh;
      int p = sr >> 1, hf = sr & 1;
      #pragma unroll
      for (int i = 0; i < 4; i++){
        float4 v = *(const float4*)(vrow + 4*i);
        int dd = sc + 4*i;
        VH[2*rotIdx(dd+0, p) + hf] = (_Float16)v.x;
        VH[2*rotIdx(dd+1, p) + hf] = (_Float16)v.y;
        VH[2*rotIdx(dd+2, p) + hf] = (_Float16)v.z;
        VH[2*rotIdx(dd+3, p) + hf] = (_Float16)v.w;
      }
    }
    __syncthreads();
    float4 s0 = make_float4(0,0,0,0), s1 = s0, s2 = s0, s3 = s0;
    #pragma unroll
    for (int c = 0; c < 8; c++){
      uint4 qa = *(uint4*)&QTh[rotIdx(n0+0, c<<2)];
      uint4 qb = *(uint4*)&QTh[rotIdx(n0+1, c<<2)];
      uint4 qc = *(uint4*)&QTh[rotIdx(n0+2, c<<2)];
      uint4 qd = *(uint4*)&QTh[rotIdx(n0+3, c<<2)];
      uint4 ka = *(uint4*)&KTh[rotIdx(m0+0, c<<2)];
      uint4 kb = *(uint4*)&KTh[rotIdx(m0+1, c<<2)];
      uint4 kc = *(uint4*)&KTh[rotIdx(m0+2, c<<2)];
      uint4 kd = *(uint4*)&KTh[rotIdx(m0+3, c<<2)];
      s0.x = dotu4(qa,ka,s0.x); s0.y = dotu4(qa,kb,s0.y); s0.z = dotu4(qa,kc,s0.z); s0.w = dotu4(qa,kd,s0.w);
      s1.x = dotu4(qb,ka,s1.x); s1.y = dotu4(qb,kb,s1.y); s1.z = dotu4(qb,kc,s1.z); s1.w = dotu4(qb,kd,s1.w);
      s2.x = dotu4(qc,ka,s2.x); s2.y = dotu4(qc,kb,s2.y); s2.z = dotu4(qc,kc,s2.z); s2.w = dotu4(qc,kd,s2.w);
      s3.x = dotu4(qd,ka,s3.x); s3.y = dotu4(qd,kb,s3.y); s3.z = dotu4(qd,kc,s3.z); s3.w = dotu4(qd,kd,s3.w);
    }
    exp4(s0); exp4(s1); exp4(s2); exp4(s3);
    dn.x += s0.x+s0.y+s0.z+s0.w;
    dn.y += s1.x+s1.y+s1.z+s1.w;
    dn.z += s2.x+s2.y+s2.z+s2.w;
    dn.w += s3.x+s3.y+s3.z+s3.w;
    *(uint2*)&Ph[rotIdx(n0+0, td<<1)] = make_uint2(pk2(s0.x,s0.y), pk2(s0.z,s0.w));
    *(uint2*)&Ph[rotIdx(n0+1, td<<1)] = make_uint2(pk2(s1.x,s1.y), pk2(s1.z,s1.w));
    *(uint2*)&Ph[rotIdx(n0+2, td<<1)] = make_uint2(pk2(s2.x,s2.y), pk2(s2.z,s2.w));
    *(uint2*)&Ph[rotIdx(n0+3, td<<1)] = make_uint2(pk2(s3.x,s3.y), pk2(s3.z,s3.w));
    __syncthreads();
    #pragma unroll
    for (int c = 0; c < 8; c++){
      uint4 pa = *(uint4*)&Ph[rotIdx(n0+0, c<<2)];
      uint4 pb = *(uint4*)&Ph[rotIdx(n0+1, c<<2)];
      uint4 pc = *(uint4*)&Ph[rotIdx(n0+2, c<<2)];
      uint4 pd = *(uint4*)&Ph[rotIdx(n0+3, c<<2)];
      uint4 va = *(uint4*)&VTh[rotIdx(d0+0, c<<2)];
      uint4 vb = *(uint4*)&VTh[rotIdx(d0+1, c<<2)];
      uint4 vc = *(uint4*)&VTh[rotIdx(d0+2, c<<2)];
      uint4 vd = *(uint4*)&VTh[rotIdx(d0+3, c<<2)];
      o0.x = dotu4(pa,va,o0.x); o0.y = dotu4(pa,vb,o0.y); o0.z = dotu4(pa,vc,o0.z); o0.w = dotu4(pa,vd,o0.w);
      o1.x = dotu4(pb,va,o1.x); o1.y = dotu4(pb,vb,o1.y); o1.z = dotu4(pb,vc,o1.z); o1.w = dotu4(pb,vd,o1.w);
      o2.x = dotu4(pc,va,o2.x); o2.y = dotu4(pc,vb,o2.y); o2.z = dotu4(pc,vc,o2.z); o2.w = dotu4(pc,vd,o2.w);
      o3.x = dotu4(pd,va,o3.x); o3.y = dotu4(pd,vb,o3.y); o3.z = dotu4(pd,vc,o3.z); o3.w = dotu4(pd,vd,o3.w);
    }
  }

  float* ob = opart + ((size_t)mc*NN + nb)*C + h*64;
  *(float4*)(ob + (n0+0)*C + d0) = o0;
  *(float4*)(ob + (n0+1)*C + d0) = o1;
  *(float4*)(ob + (n0+2)*C + d0) = o2;
  *(float4*)(ob + (n0+3)*C + d0) = o3;
  dn.x += __shfl_xor(dn.x, 16); dn.y += __shfl_xor(dn.y, 16);
  dn.z += __shfl_xor(dn.z, 16); dn.w += __shfl_xor(dn.w, 16);
  dn.x += __shfl_xor(dn.x, 32); dn.y += __shfl_xor(dn.y, 32);
  dn.z += __shfl_xor(dn.z, 32); dn.w += __shfl_xor(dn.w, 32);
  if ((tid & 63) < 16){
    float* db = dpart + ((size_t)mc*NN + nb + n0)*AHD + h;
    atomicAdd(&db[0*AHD], dn.x); atomicAdd(&db[1*AHD], dn.y);
    atomicAdd(&db[2*AHD], dn.z); atomicAdd(&db[3*AHD], dn.w);
  }
}

__global__ __launch_bounds__(256) void attnred_k(const float* __restrict__ opart, const float* __restrict__ dpart,
                                                 float* omean){
  int r0 = blockIdx.x*128, c = threadIdx.x;
  int head = c >> 6;
  float s = 0.f;
  for (int r = 0; r < 128; r++){
    int n = r0 + r;
    float dsum = 0.f, osum = 0.f;
    #pragma unroll
    for (int mc = 0; mc < MCH; mc++){
      dsum += dpart[((size_t)mc*NN + n)*AHD + head];
      osum += opart[((size_t)mc*NN + n)*C + c];
    }
    s += osum / (dsum + 1e-16f);
  }
  atomicAdd(&omean[c], s*(1.f/4096.f));
}

__global__ __launch_bounds__(256) void attnproj_k(const float* __restrict__ omean, const float* __restrict__ opw,
                                                  const float* __restrict__ opb, float* attnp){
  __shared__ float sh[256];
  int j = threadIdx.x;
  sh[j] = omean[j];
  __syncthreads();
  float acc = opb[j];
  for (int k = 0; k < 256; k++) acc += sh[k]*opw[j*256 + k];
  attnp[j] = acc;
}

__global__ __launch_bounds__(512) void fus1_k(const float* __restrict__ meanp, const float* __restrict__ maxp,
                                              const float* __restrict__ attnp, const float* __restrict__ fw1,
                                              const float* __restrict__ fb1, float* g1){
  __shared__ float comb[768];
  for (int i = threadIdx.x; i < 768; i += 512)
    comb[i] = (i < 256) ? meanp[i] : (i < 512 ? maxp[i-256] : attnp[i-512]);
  __syncthreads();
  int j = threadIdx.x;
  float acc = fb1[j];
  for (int k = 0; k < 768; k++) acc += comb[k]*fw1[k*512 + j];
  g1[j] = fmaxf(acc, 0.f);
}

__global__ __launch_bounds__(256) void fus2_k(const float* __restrict__ g1, const float* __restrict__ fw2,
                                              const float* __restrict__ fb2, float* __restrict__ out){
  __shared__ float g[512];
  g[threadIdx.x] = g1[threadIdx.x];
  g[threadIdx.x + 256] = g1[threadIdx.x + 256];
  __syncthreads();
  int j = threadIdx.x;
  float acc = fb2[j];
  for (int k = 0; k < 512; k++) acc += g[k]*fw2[k*256 + j];
  out[j] = fmaxf(acc, 0.f);
}

extern "C" void kernel_launch(void* const* d_in, const int* in_sizes, int n_in,
                              void* d_out, int out_size, void* d_ws, size_t ws_size,
                              hipStream_t stream){
  const float* x     = (const float*)d_in[0];
  const int*   srcv  = (const int*)d_in[1];
  const int*   dstv  = (const int*)d_in[2];
  const float* eattr = (const float*)d_in[3];
  const int*   etyp  = (const int*)d_in[4];
  const float* W0    = (const float*)d_in[5];
  const float* W12   = (const float*)d_in[6];
  const float* attS  = (const float*)d_in[7];
  const float* attD  = (const float*)d_in[8];
  const float* attE  = (const float*)d_in[9];
  const float* linE  = (const float*)d_in[10];
  const float* bias  = (const float*)d_in[11];
  const float* etw   = (const float*)d_in[12];
  const float* ipw   = (const float*)d_in[13];
  const float* ipb   = (const float*)d_in[14];
  const float* opw   = (const float*)d_in[15];
  const float* opb   = (const float*)d_in[16];
  const float* fw1   = (const float*)d_in[17];
  const float* fb1   = (const float*)d_in[18];
  const float* fw2   = (const float*)d_in[19];
  const float* fb2   = (const float*)d_in[20];
  float* out = (float*)d_out;

  if (ws_size < (size_t)WS_WORDS*4) return;

  int*      ip  = (int*)d_ws;
  float*    fp  = (float*)d_ws;
  unsigned* wtp = (unsigned*)(fp + F_WT);
  unsigned* w12p = (unsigned*)(fp + U_W12P);

  zero_k<<<(NZERO + 255)/256, 256, 0, stream>>>(fp + F_DPART, NZERO, ip + W_CURSOR, NN*T);
  initmax_k<<<1, 256, 0, stream>>>(fp + F_MAXP);

  hist_k<<<EE/256, 256, 0, stream>>>(dstv, etyp, ip + W_CURSOR);
  scan_k<<<1, 1024, 0, stream>>>(ip + W_CURSOR, ip + W_OFF, ip + W_CURSOR);
  scatter_k<<<EE/256, 256, 0, stream>>>(dstv, etyp, ip + W_CURSOR, ip + W_SORTED);

  // weight packing prepass
  pack12_k<<<dim3(128, T*2), 256, 0, stream>>>(W12, w12p);
  packT_k<<<dim3(128, 3), 256, 0, stream>>>(ipw, wtp);

  // all-layer prepass: we, se, sloop
  we2_k<<<dim3(T, LL), 256, 0, stream>>>(linE, attE, fp + F_WE);
  se_k<<<dim3(EE/256, LL), 256, 0, stream>>>(eattr, etyp, fp + F_WE, fp + F_SE);
  sloop_k<<<dim3((NN*T)/256, LL), 256, 0, stream>>>(ip + W_OFF, ip + W_SORTED, fp + F_SE, fp + F_SLOOP);

  for (int l = 0; l < 3; l++){
    if (l == 0)
      gemm_k<<<dim3(NN/8, T), 256, 0, stream>>>(x, DIN, W0, (long)DIN*C, attS, attD, 0,
                                                fp + F_XL, fp + F_SSRC, fp + F_SDST);
    else
      gemm16_k<<<dim3(NN/8, T), 128, 0, stream>>>(fp + F_H, w12p, attS, attD, l,
                                                  fp + F_XL, fp + F_SSRC, fp + F_SDST);
    agg_k<<<dim3(NN, T), 256, 0, stream>>>(fp + F_XL, fp + F_SSRC, fp + F_SDST,
                                           fp + F_SE + (size_t)l*EE,
                                           fp + F_SLOOP + (size_t)l*(NN*T),
                                           ip + W_OFF, ip + W_SORTED, srcv,
                                           bias, fp + F_H, l);
  }

  hacc_k<<<NN, 256, 0, stream>>>(fp + F_H, etw, fp + F_HACC);
  colstats_k<<<32, 256, 0, stream>>>(fp + F_HACC, fp + F_MEANP, fp + F_MAXP);

  qkv16_k<<<dim3(NN/8, 3), 128, 0, stream>>>(fp + F_HACC, wtp, ipb, fp + F_QKV);
  attn_k<<<dim3(NN/64, AHD, MCH), 256, 0, stream>>>(fp + F_QKV, fp + F_OPART, fp + F_DPART);
  attnred_k<<<32, 256, 0, stream>>>(fp + F_OPART, fp + F_DPART, fp + F_OMEAN);
  attnproj_k<<<1, 256, 0, stream>>>(fp + F_OMEAN, opw, opb, fp + F_ATTNP);

  fus1_k<<<1, 512, 0, stream>>>(fp + F_MEANP, fp + F_MAXP, fp + F_ATTNP, fw1, fb1, fp + F_G1);
  fus2_k<<<1, 256, 0, stream>>>(fp + F_G1, fw2, fb2, out);
}

// Round 11
// 563.774 us; speedup vs baseline: 1.7879x; 1.1922x over previous
//
#include <hip/hip_runtime.h>
#include <math.h>

#define T 4
#define LL 3
#define C 256
#define DIN 20
#define NN 4096
#define EE 65536
#define AHD 4
#define MCH 4     // attention m-chunks (blockIdx.z)
#define QKS 72    // padded LDS row stride in halfs (64+8): +4 banks/row -> 2-way (free)

// ---- workspace layout (4-byte word offsets) ----
#define W_OFF    0                    // int[N*T+1]
#define W_CURSOR 16640                // int[N*T]  (also hist counts)
#define W_SORTED 33024                // int[E]
#define F_XL     98560                // float[T][N][C]
#define F_H      (F_XL + T*NN*C)      // float[T][N][C]
#define F_OPART  F_XL                 // alias: float[MCH][N][C] fits dead F_XL(+F_H) region
#define F_SSRC   (F_H + T*NN*C)       // float[T][N]
#define F_SDST   (F_SSRC + T*NN)      // float[T][N]
#define F_SE     (F_SDST + T*NN)      // float[LL][E]
#define F_SLOOP  (F_SE + LL*EE)       // float[LL][N*T] indexed l*NT + n*T+t
#define F_WE     (F_SLOOP + LL*T*NN)  // float[T*LL][10] (padded 128)
#define F_HACC   (F_WE + 128)         // float[N][C]
#define F_WT     (F_HACC + NN*C)      // u32[128][768] packed f16-pair in_proj_w^T (region reserved 768*256)
#define F_QKV    (F_WT + 768*256)     // float[N][768]
#define F_DPART  (F_QKV + NN*768)     // float[MCH][N][AH]
#define F_MEANP  (F_DPART + MCH*NN*AHD) // float[C]
#define F_MAXP   (F_MEANP + C)        // float[C]
#define F_OMEAN  (F_MAXP + C)         // float[C]
#define F_ATTNP  (F_OMEAN + C)        // float[C]
#define F_G1     (F_ATTNP + C)        // float[512]
#define U_W12P   (F_G1 + 512)         // u32[T*2][128][256] packed f16-pair W12
#define WS_WORDS (U_W12P + 262144)
#define NZERO (3*C)                   // meanp, maxp, omean (opart/dpart fully direct-stored now)

static __device__ __forceinline__ float lrelu(float x){ return x > 0.f ? x : 0.2f*x; }
static __device__ __forceinline__ float eluf(float x){ return x > 0.f ? x : __expf(x) - 1.f; }

typedef _Float16 half2_t __attribute__((ext_vector_type(2)));
typedef _Float16 v8h __attribute__((ext_vector_type(8)));
typedef float v4f __attribute__((ext_vector_type(4)));

static __device__ __forceinline__ unsigned pk2(float x, float y){
  half2_t h; h.x = (_Float16)x; h.y = (_Float16)y;
  return __builtin_bit_cast(unsigned, h);
}
#if __has_builtin(__builtin_amdgcn_fdot2)
static __device__ __forceinline__ float fdot2u(unsigned a, unsigned b, float c){
  return __builtin_amdgcn_fdot2(__builtin_bit_cast(half2_t, a), __builtin_bit_cast(half2_t, b), c, false);
}
#else
static __device__ __forceinline__ float fdot2u(unsigned a, unsigned b, float c){
  half2_t ha = __builtin_bit_cast(half2_t, a), hb = __builtin_bit_cast(half2_t, b);
  return c + (float)ha.x*(float)hb.x + (float)ha.y*(float)hb.y;
}
#endif

static __device__ inline void atomicMaxF(float* addr, float val){
  int* ai = (int*)addr;
  int old = __float_as_int(*addr);
  while (__int_as_float(old) < val){
    int assumed = old;
    old = atomicCAS(ai, assumed, __float_as_int(val));
    if (old == assumed) break;
  }
}

__global__ __launch_bounds__(256) void zero_k(float* fz, int nf, int* iz, int ni){
  int i = blockIdx.x*256 + threadIdx.x;
  if (i < nf) fz[i] = 0.f;
  if (i < ni) iz[i] = 0;
}
__global__ __launch_bounds__(256) void initmax_k(float* maxp){ maxp[threadIdx.x] = -1e30f; }

__global__ __launch_bounds__(256) void hist_k(const int* __restrict__ dst, const int* __restrict__ ety, int* cnt){
  int e = blockIdx.x*256 + threadIdx.x;
  if (e < EE) atomicAdd(&cnt[dst[e]*T + ety[e]], 1);
}

__global__ __launch_bounds__(1024) void scan_k(int* cnt, int* off, int* cursor){
  __shared__ int part[1024];
  int tid = threadIdx.x;
  int base = tid*16;
  int loc[16]; int s = 0;
  for (int i = 0; i < 16; i++){ loc[i] = cnt[base+i]; s += loc[i]; }
  part[tid] = s; __syncthreads();
  int v = s;
  for (int offn = 1; offn < 1024; offn <<= 1){
    int add = (tid >= offn) ? part[tid-offn] : 0;
    __syncthreads();
    v += add; part[tid] = v;
    __syncthreads();
  }
  int excl = v - s;
  for (int i = 0; i < 16; i++){ off[base+i] = excl; cursor[base+i] = excl; excl += loc[i]; }
  if (tid == 1023) off[NN*T] = excl;
}

__global__ __launch_bounds__(256) void scatter_k(const int* __restrict__ dst, const int* __restrict__ ety,
                                                 int* cursor, int* sorted){
  int e = blockIdx.x*256 + threadIdx.x;
  if (e < EE){
    int p = atomicAdd(&cursor[dst[e]*T + ety[e]], 1);
    sorted[p] = e;
  }
}

// pack W12 [t][i][256][256] -> f16-pair u32 [t*2+i][128][256]
__global__ __launch_bounds__(256) void pack12_k(const float* __restrict__ w, unsigned* __restrict__ wp){
  int b = blockIdx.y, k2 = blockIdx.x, c = threadIdx.x;
  const float* s = w + (size_t)b*C*C;
  wp[((size_t)b*128 + k2)*C + c] = pk2(s[(2*k2)*C + c], s[(2*k2+1)*C + c]);
}

// pack in_proj_w [768][256] -> transposed f16-pair u32 [128][768]
__global__ __launch_bounds__(256) void packT_k(const float* __restrict__ ipw, unsigned* __restrict__ wtp){
  int k2 = blockIdx.x, j = blockIdx.y*256 + threadIdx.x;
  wtp[k2*768 + j] = pk2(ipw[(size_t)j*C + 2*k2], ipw[(size_t)j*C + 2*k2 + 1]);
}

// we[t][l][k] = sum_c lin_edge_w[t,l,k,c] * att_edge[t,l,0,c]  -- all (t,l) in one launch
__global__ __launch_bounds__(256) void we2_k(const float* __restrict__ linE, const float* __restrict__ attE,
                                             float* we){
  int t = blockIdx.x, l = blockIdx.y, c = threadIdx.x;
  __shared__ float part[10*C];
  float ae = attE[(t*LL + l)*C + c];
  const float* lw = linE + (size_t)((t*LL + l)*10)*C;
  for (int k = 0; k < 10; k++) part[k*C + c] = lw[k*C + c]*ae;
  __syncthreads();
  if (c < 10){
    float s = 0.f;
    for (int i = 0; i < C; i++) s += part[c*C + i];
    we[(t*LL + l)*10 + c] = s;
  }
}

// layer 0 only (K=20, cheap): fp32 path, fused ssd reduction
__global__ __launch_bounds__(256) void gemm_k(const float* __restrict__ hin, int K,
                                              const float* __restrict__ Wb, long wtstr,
                                              const float* __restrict__ attS, const float* __restrict__ attD,
                                              int l, float* __restrict__ xlo,
                                              float* __restrict__ ssrc, float* __restrict__ sdst){
  int t = blockIdx.y;
  const float* h = hin;
  const float* W = Wb + (size_t)t*wtstr;
  int n0 = blockIdx.x*8;
  __shared__ float sh[8*256];
  __shared__ float red[64];
  for (int j = 0; j < 8; j++)
    for (int k = threadIdx.x; k < K; k += 256)
      sh[j*K + k] = h[(n0+j)*K + k];
  __syncthreads();
  float acc[8] = {0,0,0,0,0,0,0,0};
  int c = threadIdx.x;
  for (int k = 0; k < K; k += 4){
    float w0 = W[(k+0)*C + c], w1 = W[(k+1)*C + c], w2 = W[(k+2)*C + c], w3 = W[(k+3)*C + c];
    #pragma unroll
    for (int j = 0; j < 8; j++){
      float4 h4 = *(const float4*)&sh[j*K + k];
      acc[j] += w0*h4.x + w1*h4.y + w2*h4.z + w3*h4.w;
    }
  }
  #pragma unroll
  for (int j = 0; j < 8; j++) xlo[(t*NN + n0 + j)*C + c] = acc[j];
  float aS = attS[(t*LL + l)*C + c], aD = attD[(t*LL + l)*C + c];
  int lane = c & 63, w = c >> 6;
  #pragma unroll
  for (int j = 0; j < 8; j++){
    float v1 = acc[j]*aS, v2 = acc[j]*aD;
    #pragma unroll
    for (int off = 32; off > 0; off >>= 1){ v1 += __shfl_down(v1, off); v2 += __shfl_down(v2, off); }
    if (lane == 0){ red[j*8 + w] = v1; red[j*8 + 4 + w] = v2; }
  }
  __syncthreads();
  if (c < 16){
    int j = c >> 1, which = c & 1;
    const float* r = red + j*8 + which*4;
    float s = r[0] + r[1] + r[2] + r[3];
    (which ? sdst : ssrc)[t*NN + n0 + j] = s;
  }
}

// layers 1,2 (K=256) as f16-pair dot2 GEMM (R10)
__global__ __launch_bounds__(128) void gemm16_k(const float* __restrict__ hin,
                                                const unsigned* __restrict__ w12p,
                                                const float* __restrict__ attS, const float* __restrict__ attD,
                                                int l, float* __restrict__ xlo,
                                                float* __restrict__ ssrc, float* __restrict__ sdst){
  int t = blockIdx.y;
  const float* h = hin + (size_t)t*NN*C;
  const unsigned* W = w12p + ((size_t)(t*2 + (l-1)))*128*C;
  int n0 = blockIdx.x*8;
  int tid = threadIdx.x;
  __shared__ unsigned sh[8*128];
  __shared__ float red[32];
  #pragma unroll
  for (int j = 0; j < 8; j++){
    float2 hv = *(const float2*)&h[(size_t)(n0+j)*C + 2*tid];
    sh[j*128 + tid] = pk2(hv.x, hv.y);
  }
  __syncthreads();
  float a0[8] = {0,0,0,0,0,0,0,0};
  float a1[8] = {0,0,0,0,0,0,0,0};
  int c0 = tid, c1 = tid + 128;
  for (int k2 = 0; k2 < 128; k2 += 4){
    unsigned w00 = W[(k2+0)*C + c0], w01 = W[(k2+1)*C + c0],
             w02 = W[(k2+2)*C + c0], w03 = W[(k2+3)*C + c0];
    unsigned w10 = W[(k2+0)*C + c1], w11 = W[(k2+1)*C + c1],
             w12 = W[(k2+2)*C + c1], w13 = W[(k2+3)*C + c1];
    #pragma unroll
    for (int j = 0; j < 8; j++){
      uint4 hp = *(uint4*)&sh[j*128 + k2];
      a0[j] = fdot2u(hp.x, w00, a0[j]); a0[j] = fdot2u(hp.y, w01, a0[j]);
      a0[j] = fdot2u(hp.z, w02, a0[j]); a0[j] = fdot2u(hp.w, w03, a0[j]);
      a1[j] = fdot2u(hp.x, w10, a1[j]); a1[j] = fdot2u(hp.y, w11, a1[j]);
      a1[j] = fdot2u(hp.z, w12, a1[j]); a1[j] = fdot2u(hp.w, w13, a1[j]);
    }
  }
  #pragma unroll
  for (int j = 0; j < 8; j++){
    xlo[(t*NN + n0 + j)*C + c0] = a0[j];
    xlo[(t*NN + n0 + j)*C + c1] = a1[j];
  }
  float aS0 = attS[(t*LL + l)*C + c0], aS1 = attS[(t*LL + l)*C + c1];
  float aD0 = attD[(t*LL + l)*C + c0], aD1 = attD[(t*LL + l)*C + c1];
  int lane = tid & 63, w = tid >> 6;
  #pragma unroll
  for (int j = 0; j < 8; j++){
    float v1 = a0[j]*aS0 + a1[j]*aS1;
    float v2 = a0[j]*aD0 + a1[j]*aD1;
    #pragma unroll
    for (int off = 32; off > 0; off >>= 1){ v1 += __shfl_down(v1, off); v2 += __shfl_down(v2, off); }
    if (lane == 0){ red[j*4 + w*2 + 0] = v1; red[j*4 + w*2 + 1] = v2; }
  }
  __syncthreads();
  if (tid < 16){
    int j = tid >> 1, which = tid & 1;
    float s = red[j*4 + which] + red[j*4 + 2 + which];
    (which ? sdst : ssrc)[t*NN + n0 + j] = s;
  }
}

// all layers at once: se[l][e]
__global__ __launch_bounds__(256) void se_k(const float* __restrict__ eattr, const int* __restrict__ ety,
                                            const float* __restrict__ we, float* se){
  int e = blockIdx.x*256 + threadIdx.x;
  int l = blockIdx.y;
  if (e < EE){
    const float* w = we + (ety[e]*LL + l)*10;
    const float* ea = eattr + e*10;
    float s = 0.f;
    #pragma unroll
    for (int k = 0; k < 10; k++) s += ea[k]*w[k];
    se[(size_t)l*EE + e] = s;
  }
}

// all layers at once: sloop[l][i]
__global__ __launch_bounds__(256) void sloop_k(const int* __restrict__ off, const int* __restrict__ sorted,
                                               const float* __restrict__ se, float* sloop){
  int i = blockIdx.x*256 + threadIdx.x;
  int l = blockIdx.y;
  if (i < NN*T){
    int o0 = off[i], o1 = off[i+1];
    const float* sel = se + (size_t)l*EE;
    float s = 0.f;
    for (int j = o0; j < o1; j++) s += sel[sorted[j]];
    int dg = o1 - o0;
    sloop[(size_t)l*(NN*T) + i] = s / (float)(dg > 0 ? dg : 1);
  }
}

__global__ __launch_bounds__(256) void agg_k(const float* __restrict__ xl, const float* __restrict__ ssrc,
                                             const float* __restrict__ sdst, const float* __restrict__ se,
                                             const float* __restrict__ sloop, const int* __restrict__ off,
                                             const int* __restrict__ sorted, const int* __restrict__ srcv,
                                             const float* __restrict__ bias, float* __restrict__ hout, int l){
  int n = blockIdx.x, t = blockIdx.y;
  int i = n*T + t;
  int o0 = off[i];
  int deg = off[i+1] - o0;
  if (deg > 512) deg = 512;
  __shared__ float sc[512];
  __shared__ int sj[512];
  __shared__ float sInv, sAL;
  for (int j = threadIdx.x; j < deg; j += 256){
    int e = sorted[o0 + j];
    int sn = srcv[e];
    sc[j] = lrelu(ssrc[t*NN + sn] + sdst[t*NN + n] + se[e]);
    sj[j] = sn;
  }
  __syncthreads();
  if (threadIdx.x == 0){
    float al = lrelu(ssrc[t*NN + n] + sdst[t*NN + n] + sloop[i]);
    float mx = al;
    for (int j = 0; j < deg; j++) mx = fmaxf(mx, sc[j]);
    float al_e = __expf(al - mx);
    float ssum = al_e;
    for (int j = 0; j < deg; j++){ float ex = __expf(sc[j] - mx); sc[j] = ex; ssum += ex; }
    sInv = 1.f/(ssum + 1e-16f);
    sAL = al_e;
  }
  __syncthreads();
  int c = threadIdx.x;
  float acc = sAL * xl[(t*NN + n)*C + c];
  for (int j = 0; j < deg; j++) acc += sc[j] * xl[(t*NN + sj[j])*C + c];
  acc = acc*sInv + bias[(t*LL + l)*C + c];
  hout[(t*NN + n)*C + c] = eluf(acc);
}

__global__ __launch_bounds__(256) void hacc_k(const float* __restrict__ h, const float* __restrict__ etw,
                                              float* __restrict__ hacc){
  int n = blockIdx.x, c = threadIdx.x;
  float e0 = etw[0], e1 = etw[1], e2 = etw[2], e3 = etw[3];
  float m = fmaxf(fmaxf(e0,e1), fmaxf(e2,e3));
  float w0 = __expf(e0-m), w1 = __expf(e1-m), w2 = __expf(e2-m), w3 = __expf(e3-m);
  float inv = 1.f/(w0+w1+w2+w3);
  float s = w0*h[(0*NN+n)*C+c] + w1*h[(1*NN+n)*C+c] + w2*h[(2*NN+n)*C+c] + w3*h[(3*NN+n)*C+c];
  hacc[n*C + c] = s*inv;
}

__global__ __launch_bounds__(256) void colstats_k(const float* __restrict__ hacc, float* meanp, float* maxp){
  int r0 = blockIdx.x*128, c = threadIdx.x;
  float sm = 0.f, mx = -1e30f;
  for (int r = 0; r < 128; r++){
    float v = hacc[(r0+r)*C + c];
    sm += v; mx = fmaxf(mx, v);
  }
  atomicAdd(&meanp[c], sm*(1.f/4096.f));
  atomicMaxF(&maxp[c], mx);
}

// qkv as f16-pair dot2 GEMM (R10), packed WT
__global__ __launch_bounds__(128) void qkv16_k(const float* __restrict__ hacc,
                                               const unsigned* __restrict__ wtp,
                                               const float* __restrict__ ipb, float* __restrict__ qkv){
  int p = blockIdx.y;
  int n0 = blockIdx.x*8;
  int tid = threadIdx.x;
  __shared__ unsigned sh[8*128];
  #pragma unroll
  for (int j = 0; j < 8; j++){
    float2 hv = *(const float2*)&hacc[(size_t)(n0+j)*C + 2*tid];
    sh[j*128 + tid] = pk2(hv.x, hv.y);
  }
  __syncthreads();
  float a0[8] = {0,0,0,0,0,0,0,0};
  float a1[8] = {0,0,0,0,0,0,0,0};
  int c0 = p*256 + tid, c1 = c0 + 128;
  for (int k2 = 0; k2 < 128; k2 += 4){
    unsigned w00 = wtp[(k2+0)*768 + c0], w01 = wtp[(k2+1)*768 + c0],
             w02 = wtp[(k2+2)*768 + c0], w03 = wtp[(k2+3)*768 + c0];
    unsigned w10 = wtp[(k2+0)*768 + c1], w11 = wtp[(k2+1)*768 + c1],
             w12 = wtp[(k2+2)*768 + c1], w13 = wtp[(k2+3)*768 + c1];
    #pragma unroll
    for (int j = 0; j < 8; j++){
      uint4 hp = *(uint4*)&sh[j*128 + k2];
      a0[j] = fdot2u(hp.x, w00, a0[j]); a0[j] = fdot2u(hp.y, w01, a0[j]);
      a0[j] = fdot2u(hp.z, w02, a0[j]); a0[j] = fdot2u(hp.w, w03, a0[j]);
      a1[j] = fdot2u(hp.x, w10, a1[j]); a1[j] = fdot2u(hp.y, w11, a1[j]);
      a1[j] = fdot2u(hp.z, w12, a1[j]); a1[j] = fdot2u(hp.w, w13, a1[j]);
    }
  }
  float b0 = ipb[c0], b1 = ipb[c1];
  #pragma unroll
  for (int j = 0; j < 8; j++){
    qkv[(size_t)(n0+j)*768 + c0] = a0[j] + b0;
    qkv[(size_t)(n0+j)*768 + c1] = a1[j] + b1;
  }
}

// R11: single-wave MFMA flash attention. Block = 1 wave = (64-row n-tile, head,
// m-chunk). S^T = K.Q^T via mfma_f32_16x16x32_f16 (A=K[m][k], B-frag reads
// Q[n][k]; both contiguous b128 at stride-72 -> 2-way-free banks). C-layout of
// S^T gives each lane 4 m-consecutive values -> P[n][m] via 16 ds_write_b64.
// O = P.V with V^T staged as B. ~88 LDS instr/wave-tile vs dot2's ~420
// (R10 post-mortem: dot2 attn still LDS-issue-bound at 223us). No barriers
// needed (single wave); dpart direct-stored (no atomics/zeroing).
__global__ __launch_bounds__(64, 1) void attn_k(const float* __restrict__ qkv,
                                                float* __restrict__ opart,
                                                float* __restrict__ dpart){
  __shared__ __align__(16) _Float16 Qs[64*QKS];   // [n][k]
  __shared__ __align__(16) _Float16 Ks[64*QKS];   // [m][k]
  __shared__ __align__(16) _Float16 VTs[64*QKS];  // [d][m]
  __shared__ __align__(16) _Float16 Ps[64*QKS];   // [n][m]
  int l = threadIdx.x;
  int nb = blockIdx.x*64, h = blockIdx.y, mc = blockIdx.z;
  int r16 = l & 15, q = l >> 4;

  // stage Q (one row per thread), prescaled by 1/8
  {
    const float* qrow = qkv + (size_t)(nb + l)*768 + h*64;
    _Float16* dq = Qs + l*QKS;
    #pragma unroll
    for (int i = 0; i < 8; i++){
      float4 a = *(const float4*)(qrow + 8*i);
      float4 b = *(const float4*)(qrow + 8*i + 4);
      v8h hv = {(_Float16)(a.x*0.125f), (_Float16)(a.y*0.125f),
                (_Float16)(a.z*0.125f), (_Float16)(a.w*0.125f),
                (_Float16)(b.x*0.125f), (_Float16)(b.y*0.125f),
                (_Float16)(b.z*0.125f), (_Float16)(b.w*0.125f)};
      *(v8h*)(dq + 8*i) = hv;
    }
  }

  v4f o[4][4];
  #pragma unroll
  for (int i = 0; i < 4; i++)
    #pragma unroll
    for (int j = 0; j < 4; j++) o[i][j] = (v4f){0.f,0.f,0.f,0.f};
  float dn[4] = {0.f,0.f,0.f,0.f};

  for (int mt = 0; mt < NN/MCH/64; mt++){
    int mb = mc*(NN/MCH) + mt*64;
    __syncthreads();
    // stage K (one row per thread)
    {
      const float* krow = qkv + (size_t)(mb + l)*768 + 256 + h*64;
      _Float16* dk = Ks + l*QKS;
      #pragma unroll
      for (int i = 0; i < 8; i++){
        float4 a = *(const float4*)(krow + 8*i);
        float4 b = *(const float4*)(krow + 8*i + 4);
        v8h hv = {(_Float16)a.x, (_Float16)a.y, (_Float16)a.z, (_Float16)a.w,
                  (_Float16)b.x, (_Float16)b.y, (_Float16)b.z, (_Float16)b.w};
        *(v8h*)(dk + 8*i) = hv;
      }
    }
    // stage V transposed: thread = (m-pair, d-half); paired u32 writes
    {
      int m0 = (l & 31)*2;
      int db = (l >> 5)*32;
      const float* v0 = qkv + (size_t)(mb + m0)*768 + 512 + h*64 + db;
      const float* v1 = v0 + 768;
      #pragma unroll
      for (int i = 0; i < 8; i++){
        float4 a = *(const float4*)(v0 + 4*i);
        float4 b = *(const float4*)(v1 + 4*i);
        int d = db + 4*i;
        *(unsigned*)(VTs + (size_t)(d+0)*QKS + m0) = pk2(a.x, b.x);
        *(unsigned*)(VTs + (size_t)(d+1)*QKS + m0) = pk2(a.y, b.y);
        *(unsigned*)(VTs + (size_t)(d+2)*QKS + m0) = pk2(a.z, b.z);
        *(unsigned*)(VTs + (size_t)(d+3)*QKS + m0) = pk2(a.w, b.w);
      }
    }
    __syncthreads();
    // S^T = K.Q^T : c[mi][ni]; A-frag K rows, B-frag Q rows
    v4f c[4][4];
    #pragma unroll
    for (int i = 0; i < 4; i++)
      #pragma unroll
      for (int j = 0; j < 4; j++) c[i][j] = (v4f){0.f,0.f,0.f,0.f};
    #pragma unroll
    for (int kk = 0; kk < 2; kk++){
      v8h a[4], b[4];
      #pragma unroll
      for (int mi = 0; mi < 4; mi++) a[mi] = *(v8h*)(Ks + (size_t)(mi*16 + r16)*QKS + kk*32 + q*8);
      #pragma unroll
      for (int ni = 0; ni < 4; ni++) b[ni] = *(v8h*)(Qs + (size_t)(ni*16 + r16)*QKS + kk*32 + q*8);
      #pragma unroll
      for (int mi = 0; mi < 4; mi++)
        #pragma unroll
        for (int ni = 0; ni < 4; ni++)
          c[mi][ni] = __builtin_amdgcn_mfma_f32_16x16x32_f16(a[mi], b[ni], c[mi][ni], 0, 0, 0);
    }
    // exp + denominator + pack P[n][m] (lane's 4 vals are m-consecutive)
    #pragma unroll
    for (int mi = 0; mi < 4; mi++)
      #pragma unroll
      for (int ni = 0; ni < 4; ni++){
        float e0 = __expf(c[mi][ni][0]), e1 = __expf(c[mi][ni][1]),
              e2 = __expf(c[mi][ni][2]), e3 = __expf(c[mi][ni][3]);
        dn[ni] += e0 + e1 + e2 + e3;
        *(uint2*)(Ps + (size_t)(ni*16 + r16)*QKS + mi*16 + q*4) = make_uint2(pk2(e0,e1), pk2(e2,e3));
      }
    __syncthreads();
    // O += P.V : A-frag P rows, B-frag VT rows
    #pragma unroll
    for (int km = 0; km < 2; km++){
      v8h pa[4], vb[4];
      #pragma unroll
      for (int ni = 0; ni < 4; ni++) pa[ni] = *(v8h*)(Ps + (size_t)(ni*16 + r16)*QKS + km*32 + q*8);
      #pragma unroll
      for (int di = 0; di < 4; di++) vb[di] = *(v8h*)(VTs + (size_t)(di*16 + r16)*QKS + km*32 + q*8);
      #pragma unroll
      for (int ni = 0; ni < 4; ni++)
        #pragma unroll
        for (int di = 0; di < 4; di++)
          o[ni][di] = __builtin_amdgcn_mfma_f32_16x16x32_f16(pa[ni], vb[di], o[ni][di], 0, 0, 0);
    }
  }

  // write O: lane holds O[n=ni*16+q*4+r][d=di*16+r16]
  float* ob = opart + ((size_t)mc*NN + nb)*C + h*64;
  #pragma unroll
  for (int ni = 0; ni < 4; ni++)
    #pragma unroll
    for (int di = 0; di < 4; di++)
      #pragma unroll
      for (int r = 0; r < 4; r++)
        ob[(size_t)(ni*16 + q*4 + r)*C + di*16 + r16] = o[ni][di][r];
  // dn: quad-partial sums -> reduce across quads, quad 0 stores (no atomics)
  #pragma unroll
  for (int ni = 0; ni < 4; ni++){
    dn[ni] += __shfl_xor(dn[ni], 16);
    dn[ni] += __shfl_xor(dn[ni], 32);
  }
  if (q == 0){
    #pragma unroll
    for (int ni = 0; ni < 4; ni++)
      dpart[((size_t)mc*NN + nb + ni*16 + r16)*AHD + h] = dn[ni];
  }
}

__global__ __launch_bounds__(256) void attnred_k(const float* __restrict__ opart, const float* __restrict__ dpart,
                                                 float* omean){
  int r0 = blockIdx.x*128, c = threadIdx.x;
  int head = c >> 6;
  float s = 0.f;
  for (int r = 0; r < 128; r++){
    int n = r0 + r;
    float dsum = 0.f, osum = 0.f;
    #pragma unroll
    for (int mc = 0; mc < MCH; mc++){
      dsum += dpart[((size_t)mc*NN + n)*AHD + head];
      osum += opart[((size_t)mc*NN + n)*C + c];
    }
    s += osum / (dsum + 1e-16f);
  }
  atomicAdd(&omean[c], s*(1.f/4096.f));
}

__global__ __launch_bounds__(256) void attnproj_k(const float* __restrict__ omean, const float* __restrict__ opw,
                                                  const float* __restrict__ opb, float* attnp){
  __shared__ float sh[256];
  int j = threadIdx.x;
  sh[j] = omean[j];
  __syncthreads();
  float acc = opb[j];
  for (int k = 0; k < 256; k++) acc += sh[k]*opw[j*256 + k];
  attnp[j] = acc;
}

__global__ __launch_bounds__(512) void fus1_k(const float* __restrict__ meanp, const float* __restrict__ maxp,
                                              const float* __restrict__ attnp, const float* __restrict__ fw1,
                                              const float* __restrict__ fb1, float* g1){
  __shared__ float comb[768];
  for (int i = threadIdx.x; i < 768; i += 512)
    comb[i] = (i < 256) ? meanp[i] : (i < 512 ? maxp[i-256] : attnp[i-512]);
  __syncthreads();
  int j = threadIdx.x;
  float acc = fb1[j];
  for (int k = 0; k < 768; k++) acc += comb[k]*fw1[k*512 + j];
  g1[j] = fmaxf(acc, 0.f);
}

__global__ __launch_bounds__(256) void fus2_k(const float* __restrict__ g1, const float* __restrict__ fw2,
                                              const float* __restrict__ fb2, float* __restrict__ out){
  __shared__ float g[512];
  g[threadIdx.x] = g1[threadIdx.x];
  g[threadIdx.x + 256] = g1[threadIdx.x + 256];
  __syncthreads();
  int j = threadIdx.x;
  float acc = fb2[j];
  for (int k = 0; k < 512; k++) acc += g[k]*fw2[k*256 + j];
  out[j] = fmaxf(acc, 0.f);
}

extern "C" void kernel_launch(void* const* d_in, const int* in_sizes, int n_in,
                              void* d_out, int out_size, void* d_ws, size_t ws_size,
                              hipStream_t stream){
  const float* x     = (const float*)d_in[0];
  const int*   srcv  = (const int*)d_in[1];
  const int*   dstv  = (const int*)d_in[2];
  const float* eattr = (const float*)d_in[3];
  const int*   etyp  = (const int*)d_in[4];
  const float* W0    = (const float*)d_in[5];
  const float* W12   = (const float*)d_in[6];
  const float* attS  = (const float*)d_in[7];
  const float* attD  = (const float*)d_in[8];
  const float* attE  = (const float*)d_in[9];
  const float* linE  = (const float*)d_in[10];
  const float* bias  = (const float*)d_in[11];
  const float* etw   = (const float*)d_in[12];
  const float* ipw   = (const float*)d_in[13];
  const float* ipb   = (const float*)d_in[14];
  const float* opw   = (const float*)d_in[15];
  const float* opb   = (const float*)d_in[16];
  const float* fw1   = (const float*)d_in[17];
  const float* fb1   = (const float*)d_in[18];
  const float* fw2   = (const float*)d_in[19];
  const float* fb2   = (const float*)d_in[20];
  float* out = (float*)d_out;

  if (ws_size < (size_t)WS_WORDS*4) return;

  int*      ip   = (int*)d_ws;
  float*    fp   = (float*)d_ws;
  unsigned* wtp  = (unsigned*)(fp + F_WT);
  unsigned* w12p = (unsigned*)(fp + U_W12P);

  zero_k<<<(NN*T + 255)/256, 256, 0, stream>>>(fp + F_MEANP, NZERO, ip + W_CURSOR, NN*T);
  initmax_k<<<1, 256, 0, stream>>>(fp + F_MAXP);

  hist_k<<<EE/256, 256, 0, stream>>>(dstv, etyp, ip + W_CURSOR);
  scan_k<<<1, 1024, 0, stream>>>(ip + W_CURSOR, ip + W_OFF, ip + W_CURSOR);
  scatter_k<<<EE/256, 256, 0, stream>>>(dstv, etyp, ip + W_CURSOR, ip + W_SORTED);

  // weight packing prepass
  pack12_k<<<dim3(128, T*2), 256, 0, stream>>>(W12, w12p);
  packT_k<<<dim3(128, 3), 256, 0, stream>>>(ipw, wtp);

  // all-layer prepass: we, se, sloop
  we2_k<<<dim3(T, LL), 256, 0, stream>>>(linE, attE, fp + F_WE);
  se_k<<<dim3(EE/256, LL), 256, 0, stream>>>(eattr, etyp, fp + F_WE, fp + F_SE);
  sloop_k<<<dim3((NN*T)/256, LL), 256, 0, stream>>>(ip + W_OFF, ip + W_SORTED, fp + F_SE, fp + F_SLOOP);

  for (int l = 0; l < 3; l++){
    if (l == 0)
      gemm_k<<<dim3(NN/8, T), 256, 0, stream>>>(x, DIN, W0, (long)DIN*C, attS, attD, 0,
                                                fp + F_XL, fp + F_SSRC, fp + F_SDST);
    else
      gemm16_k<<<dim3(NN/8, T), 128, 0, stream>>>(fp + F_H, w12p, attS, attD, l,
                                                  fp + F_XL, fp + F_SSRC, fp + F_SDST);
    agg_k<<<dim3(NN, T), 256, 0, stream>>>(fp + F_XL, fp + F_SSRC, fp + F_SDST,
                                           fp + F_SE + (size_t)l*EE,
                                           fp + F_SLOOP + (size_t)l*(NN*T),
                                           ip + W_OFF, ip + W_SORTED, srcv,
                                           bias, fp + F_H, l);
  }

  hacc_k<<<NN, 256, 0, stream>>>(fp + F_H, etw, fp + F_HACC);
  colstats_k<<<32, 256, 0, stream>>>(fp + F_HACC, fp + F_MEANP, fp + F_MAXP);

  qkv16_k<<<dim3(NN/8, 3), 128, 0, stream>>>(fp + F_HACC, wtp, ipb, fp + F_QKV);
  attn_k<<<dim3(NN/64, AHD, MCH), 64, 0, stream>>>(fp + F_QKV, fp + F_OPART, fp + F_DPART);
  attnred_k<<<32, 256, 0, stream>>>(fp + F_OPART, fp + F_DPART, fp + F_OMEAN);
  attnproj_k<<<1, 256, 0, stream>>>(fp + F_OMEAN, opw, opb, fp + F_ATTNP);

  fus1_k<<<1, 512, 0, stream>>>(fp + F_MEANP, fp + F_MAXP, fp + F_ATTNP, fw1, fb1, fp + F_G1);
  fus2_k<<<1, 256, 0, stream>>>(fp + F_G1, fw2, fb2, out);
}

// Round 12
// 549.993 us; speedup vs baseline: 1.8326x; 1.0251x over previous
//
#include <hip/hip_runtime.h>
#include <math.h>

#define T 4
#define LL 3
#define C 256
#define DIN 20
#define NN 4096
#define EE 65536
#define AHD 4
#define MCH 8     // attention m-chunks (blockIdx.z); grid 16x4x8=512 blocks = 2/CU
#define QKS 72    // padded LDS row stride in halfs (64+8): +4 banks/row -> 2-way (free)

// ---- workspace layout (4-byte word offsets) ----
#define W_OFF    0                    // int[N*T+1]
#define W_CURSOR 16640                // int[N*T]  (also hist counts)
#define W_SORTED 33024                // int[E]
#define F_XL     98560                // float[T][N][C]
#define F_H      (F_XL + T*NN*C)      // float[T][N][C]
#define F_OPART  F_XL                 // alias: float[MCH][N][C] == exactly F_XL+F_H extent (dead at attn time)
#define F_SSRC   (F_H + T*NN*C)       // float[T][N]
#define F_SDST   (F_SSRC + T*NN)      // float[T][N]
#define F_SE     (F_SDST + T*NN)      // float[LL][E]
#define F_SLOOP  (F_SE + LL*EE)       // float[LL][N*T] indexed l*NT + n*T+t
#define F_WE     (F_SLOOP + LL*T*NN)  // float[T*LL][10] (padded 128)
#define F_HACC   (F_WE + 128)         // float[N][C]
#define F_WT     (F_HACC + NN*C)      // u32[128][768] packed f16-pair in_proj_w^T (region reserved 768*256)
#define F_QKV    (F_WT + 768*256)     // float[N][768]
#define F_DPART  (F_QKV + NN*768)     // float[MCH][N][AH]
#define F_MEANP  (F_DPART + MCH*NN*AHD) // float[C]
#define F_MAXP   (F_MEANP + C)        // float[C]
#define F_OMEAN  (F_MAXP + C)         // float[C]
#define F_ATTNP  (F_OMEAN + C)        // float[C]
#define F_G1     (F_ATTNP + C)        // float[512]
#define U_W12P   (F_G1 + 512)         // u32[T*2][128][256] packed f16-pair W12
#define WS_WORDS (U_W12P + 262144)
#define NZERO (3*C)                   // meanp, maxp, omean (opart/dpart fully direct-stored)

static __device__ __forceinline__ float lrelu(float x){ return x > 0.f ? x : 0.2f*x; }
static __device__ __forceinline__ float eluf(float x){ return x > 0.f ? x : __expf(x) - 1.f; }

typedef _Float16 half2_t __attribute__((ext_vector_type(2)));
typedef _Float16 v8h __attribute__((ext_vector_type(8)));
typedef float v4f __attribute__((ext_vector_type(4)));

static __device__ __forceinline__ unsigned pk2(float x, float y){
  half2_t h; h.x = (_Float16)x; h.y = (_Float16)y;
  return __builtin_bit_cast(unsigned, h);
}
#if __has_builtin(__builtin_amdgcn_fdot2)
static __device__ __forceinline__ float fdot2u(unsigned a, unsigned b, float c){
  return __builtin_amdgcn_fdot2(__builtin_bit_cast(half2_t, a), __builtin_bit_cast(half2_t, b), c, false);
}
#else
static __device__ __forceinline__ float fdot2u(unsigned a, unsigned b, float c){
  half2_t ha = __builtin_bit_cast(half2_t, a), hb = __builtin_bit_cast(half2_t, b);
  return c + (float)ha.x*(float)hb.x + (float)ha.y*(float)hb.y;
}
#endif

static __device__ inline void atomicMaxF(float* addr, float val){
  int* ai = (int*)addr;
  int old = __float_as_int(*addr);
  while (__int_as_float(old) < val){
    int assumed = old;
    old = atomicCAS(ai, assumed, __float_as_int(val));
    if (old == assumed) break;
  }
}

__global__ __launch_bounds__(256) void zero_k(float* fz, int nf, int* iz, int ni){
  int i = blockIdx.x*256 + threadIdx.x;
  if (i < nf) fz[i] = 0.f;
  if (i < ni) iz[i] = 0;
}
__global__ __launch_bounds__(256) void initmax_k(float* maxp){ maxp[threadIdx.x] = -1e30f; }

__global__ __launch_bounds__(256) void hist_k(const int* __restrict__ dst, const int* __restrict__ ety, int* cnt){
  int e = blockIdx.x*256 + threadIdx.x;
  if (e < EE) atomicAdd(&cnt[dst[e]*T + ety[e]], 1);
}

__global__ __launch_bounds__(1024) void scan_k(int* cnt, int* off, int* cursor){
  __shared__ int part[1024];
  int tid = threadIdx.x;
  int base = tid*16;
  int loc[16]; int s = 0;
  for (int i = 0; i < 16; i++){ loc[i] = cnt[base+i]; s += loc[i]; }
  part[tid] = s; __syncthreads();
  int v = s;
  for (int offn = 1; offn < 1024; offn <<= 1){
    int add = (tid >= offn) ? part[tid-offn] : 0;
    __syncthreads();
    v += add; part[tid] = v;
    __syncthreads();
  }
  int excl = v - s;
  for (int i = 0; i < 16; i++){ off[base+i] = excl; cursor[base+i] = excl; excl += loc[i]; }
  if (tid == 1023) off[NN*T] = excl;
}

__global__ __launch_bounds__(256) void scatter_k(const int* __restrict__ dst, const int* __restrict__ ety,
                                                 int* cursor, int* sorted){
  int e = blockIdx.x*256 + threadIdx.x;
  if (e < EE){
    int p = atomicAdd(&cursor[dst[e]*T + ety[e]], 1);
    sorted[p] = e;
  }
}

// pack W12 [t][i][256][256] -> f16-pair u32 [t*2+i][128][256]
__global__ __launch_bounds__(256) void pack12_k(const float* __restrict__ w, unsigned* __restrict__ wp){
  int b = blockIdx.y, k2 = blockIdx.x, c = threadIdx.x;
  const float* s = w + (size_t)b*C*C;
  wp[((size_t)b*128 + k2)*C + c] = pk2(s[(2*k2)*C + c], s[(2*k2+1)*C + c]);
}

// pack in_proj_w [768][256] -> transposed f16-pair u32 [128][768]
__global__ __launch_bounds__(256) void packT_k(const float* __restrict__ ipw, unsigned* __restrict__ wtp){
  int k2 = blockIdx.x, j = blockIdx.y*256 + threadIdx.x;
  wtp[k2*768 + j] = pk2(ipw[(size_t)j*C + 2*k2], ipw[(size_t)j*C + 2*k2 + 1]);
}

// we[t][l][k] = sum_c lin_edge_w[t,l,k,c] * att_edge[t,l,0,c]  -- all (t,l) in one launch
__global__ __launch_bounds__(256) void we2_k(const float* __restrict__ linE, const float* __restrict__ attE,
                                             float* we){
  int t = blockIdx.x, l = blockIdx.y, c = threadIdx.x;
  __shared__ float part[10*C];
  float ae = attE[(t*LL + l)*C + c];
  const float* lw = linE + (size_t)((t*LL + l)*10)*C;
  for (int k = 0; k < 10; k++) part[k*C + c] = lw[k*C + c]*ae;
  __syncthreads();
  if (c < 10){
    float s = 0.f;
    for (int i = 0; i < C; i++) s += part[c*C + i];
    we[(t*LL + l)*10 + c] = s;
  }
}

// layer 0 only (K=20, cheap): fp32 path, fused ssd reduction
__global__ __launch_bounds__(256) void gemm_k(const float* __restrict__ hin, int K,
                                              const float* __restrict__ Wb, long wtstr,
                                              const float* __restrict__ attS, const float* __restrict__ attD,
                                              int l, float* __restrict__ xlo,
                                              float* __restrict__ ssrc, float* __restrict__ sdst){
  int t = blockIdx.y;
  const float* h = hin;
  const float* W = Wb + (size_t)t*wtstr;
  int n0 = blockIdx.x*8;
  __shared__ float sh[8*256];
  __shared__ float red[64];
  for (int j = 0; j < 8; j++)
    for (int k = threadIdx.x; k < K; k += 256)
      sh[j*K + k] = h[(n0+j)*K + k];
  __syncthreads();
  float acc[8] = {0,0,0,0,0,0,0,0};
  int c = threadIdx.x;
  for (int k = 0; k < K; k += 4){
    float w0 = W[(k+0)*C + c], w1 = W[(k+1)*C + c], w2 = W[(k+2)*C + c], w3 = W[(k+3)*C + c];
    #pragma unroll
    for (int j = 0; j < 8; j++){
      float4 h4 = *(const float4*)&sh[j*K + k];
      acc[j] += w0*h4.x + w1*h4.y + w2*h4.z + w3*h4.w;
    }
  }
  #pragma unroll
  for (int j = 0; j < 8; j++) xlo[(t*NN + n0 + j)*C + c] = acc[j];
  float aS = attS[(t*LL + l)*C + c], aD = attD[(t*LL + l)*C + c];
  int lane = c & 63, w = c >> 6;
  #pragma unroll
  for (int j = 0; j < 8; j++){
    float v1 = acc[j]*aS, v2 = acc[j]*aD;
    #pragma unroll
    for (int off = 32; off > 0; off >>= 1){ v1 += __shfl_down(v1, off); v2 += __shfl_down(v2, off); }
    if (lane == 0){ red[j*8 + w] = v1; red[j*8 + 4 + w] = v2; }
  }
  __syncthreads();
  if (c < 16){
    int j = c >> 1, which = c & 1;
    const float* r = red + j*8 + which*4;
    float s = r[0] + r[1] + r[2] + r[3];
    (which ? sdst : ssrc)[t*NN + n0 + j] = s;
  }
}

// layers 1,2 (K=256) as f16-pair dot2 GEMM (R10)
__global__ __launch_bounds__(128) void gemm16_k(const float* __restrict__ hin,
                                                const unsigned* __restrict__ w12p,
                                                const float* __restrict__ attS, const float* __restrict__ attD,
                                                int l, float* __restrict__ xlo,
                                                float* __restrict__ ssrc, float* __restrict__ sdst){
  int t = blockIdx.y;
  const float* h = hin + (size_t)t*NN*C;
  const unsigned* W = w12p + ((size_t)(t*2 + (l-1)))*128*C;
  int n0 = blockIdx.x*8;
  int tid = threadIdx.x;
  __shared__ unsigned sh[8*128];
  __shared__ float red[32];
  #pragma unroll
  for (int j = 0; j < 8; j++){
    float2 hv = *(const float2*)&h[(size_t)(n0+j)*C + 2*tid];
    sh[j*128 + tid] = pk2(hv.x, hv.y);
  }
  __syncthreads();
  float a0[8] = {0,0,0,0,0,0,0,0};
  float a1[8] = {0,0,0,0,0,0,0,0};
  int c0 = tid, c1 = tid + 128;
  for (int k2 = 0; k2 < 128; k2 += 4){
    unsigned w00 = W[(k2+0)*C + c0], w01 = W[(k2+1)*C + c0],
             w02 = W[(k2+2)*C + c0], w03 = W[(k2+3)*C + c0];
    unsigned w10 = W[(k2+0)*C + c1], w11 = W[(k2+1)*C + c1],
             w12 = W[(k2+2)*C + c1], w13 = W[(k2+3)*C + c1];
    #pragma unroll
    for (int j = 0; j < 8; j++){
      uint4 hp = *(uint4*)&sh[j*128 + k2];
      a0[j] = fdot2u(hp.x, w00, a0[j]); a0[j] = fdot2u(hp.y, w01, a0[j]);
      a0[j] = fdot2u(hp.z, w02, a0[j]); a0[j] = fdot2u(hp.w, w03, a0[j]);
      a1[j] = fdot2u(hp.x, w10, a1[j]); a1[j] = fdot2u(hp.y, w11, a1[j]);
      a1[j] = fdot2u(hp.z, w12, a1[j]); a1[j] = fdot2u(hp.w, w13, a1[j]);
    }
  }
  #pragma unroll
  for (int j = 0; j < 8; j++){
    xlo[(t*NN + n0 + j)*C + c0] = a0[j];
    xlo[(t*NN + n0 + j)*C + c1] = a1[j];
  }
  float aS0 = attS[(t*LL + l)*C + c0], aS1 = attS[(t*LL + l)*C + c1];
  float aD0 = attD[(t*LL + l)*C + c0], aD1 = attD[(t*LL + l)*C + c1];
  int lane = tid & 63, w = tid >> 6;
  #pragma unroll
  for (int j = 0; j < 8; j++){
    float v1 = a0[j]*aS0 + a1[j]*aS1;
    float v2 = a0[j]*aD0 + a1[j]*aD1;
    #pragma unroll
    for (int off = 32; off > 0; off >>= 1){ v1 += __shfl_down(v1, off); v2 += __shfl_down(v2, off); }
    if (lane == 0){ red[j*4 + w*2 + 0] = v1; red[j*4 + w*2 + 1] = v2; }
  }
  __syncthreads();
  if (tid < 16){
    int j = tid >> 1, which = tid & 1;
    float s = red[j*4 + which] + red[j*4 + 2 + which];
    (which ? sdst : ssrc)[t*NN + n0 + j] = s;
  }
}

// all layers at once: se[l][e]
__global__ __launch_bounds__(256) void se_k(const float* __restrict__ eattr, const int* __restrict__ ety,
                                            const float* __restrict__ we, float* se){
  int e = blockIdx.x*256 + threadIdx.x;
  int l = blockIdx.y;
  if (e < EE){
    const float* w = we + (ety[e]*LL + l)*10;
    const float* ea = eattr + e*10;
    float s = 0.f;
    #pragma unroll
    for (int k = 0; k < 10; k++) s += ea[k]*w[k];
    se[(size_t)l*EE + e] = s;
  }
}

// all layers at once: sloop[l][i]
__global__ __launch_bounds__(256) void sloop_k(const int* __restrict__ off, const int* __restrict__ sorted,
                                               const float* __restrict__ se, float* sloop){
  int i = blockIdx.x*256 + threadIdx.x;
  int l = blockIdx.y;
  if (i < NN*T){
    int o0 = off[i], o1 = off[i+1];
    const float* sel = se + (size_t)l*EE;
    float s = 0.f;
    for (int j = o0; j < o1; j++) s += sel[sorted[j]];
    int dg = o1 - o0;
    sloop[(size_t)l*(NN*T) + i] = s / (float)(dg > 0 ? dg : 1);
  }
}

__global__ __launch_bounds__(256) void agg_k(const float* __restrict__ xl, const float* __restrict__ ssrc,
                                             const float* __restrict__ sdst, const float* __restrict__ se,
                                             const float* __restrict__ sloop, const int* __restrict__ off,
                                             const int* __restrict__ sorted, const int* __restrict__ srcv,
                                             const float* __restrict__ bias, float* __restrict__ hout, int l){
  int n = blockIdx.x, t = blockIdx.y;
  int i = n*T + t;
  int o0 = off[i];
  int deg = off[i+1] - o0;
  if (deg > 512) deg = 512;
  __shared__ float sc[512];
  __shared__ int sj[512];
  __shared__ float sInv, sAL;
  for (int j = threadIdx.x; j < deg; j += 256){
    int e = sorted[o0 + j];
    int sn = srcv[e];
    sc[j] = lrelu(ssrc[t*NN + sn] + sdst[t*NN + n] + se[e]);
    sj[j] = sn;
  }
  __syncthreads();
  if (threadIdx.x == 0){
    float al = lrelu(ssrc[t*NN + n] + sdst[t*NN + n] + sloop[i]);
    float mx = al;
    for (int j = 0; j < deg; j++) mx = fmaxf(mx, sc[j]);
    float al_e = __expf(al - mx);
    float ssum = al_e;
    for (int j = 0; j < deg; j++){ float ex = __expf(sc[j] - mx); sc[j] = ex; ssum += ex; }
    sInv = 1.f/(ssum + 1e-16f);
    sAL = al_e;
  }
  __syncthreads();
  int c = threadIdx.x;
  float acc = sAL * xl[(t*NN + n)*C + c];
  for (int j = 0; j < deg; j++) acc += sc[j] * xl[(t*NN + sj[j])*C + c];
  acc = acc*sInv + bias[(t*LL + l)*C + c];
  hout[(t*NN + n)*C + c] = eluf(acc);
}

__global__ __launch_bounds__(256) void hacc_k(const float* __restrict__ h, const float* __restrict__ etw,
                                              float* __restrict__ hacc){
  int n = blockIdx.x, c = threadIdx.x;
  float e0 = etw[0], e1 = etw[1], e2 = etw[2], e3 = etw[3];
  float m = fmaxf(fmaxf(e0,e1), fmaxf(e2,e3));
  float w0 = __expf(e0-m), w1 = __expf(e1-m), w2 = __expf(e2-m), w3 = __expf(e3-m);
  float inv = 1.f/(w0+w1+w2+w3);
  float s = w0*h[(0*NN+n)*C+c] + w1*h[(1*NN+n)*C+c] + w2*h[(2*NN+n)*C+c] + w3*h[(3*NN+n)*C+c];
  hacc[n*C + c] = s*inv;
}

__global__ __launch_bounds__(256) void colstats_k(const float* __restrict__ hacc, float* meanp, float* maxp){
  int r0 = blockIdx.x*128, c = threadIdx.x;
  float sm = 0.f, mx = -1e30f;
  for (int r = 0; r < 128; r++){
    float v = hacc[(r0+r)*C + c];
    sm += v; mx = fmaxf(mx, v);
  }
  atomicAdd(&meanp[c], sm*(1.f/4096.f));
  atomicMaxF(&maxp[c], mx);
}

// qkv as f16-pair dot2 GEMM (R10), packed WT
__global__ __launch_bounds__(128) void qkv16_k(const float* __restrict__ hacc,
                                               const unsigned* __restrict__ wtp,
                                               const float* __restrict__ ipb, float* __restrict__ qkv){
  int p = blockIdx.y;
  int n0 = blockIdx.x*8;
  int tid = threadIdx.x;
  __shared__ unsigned sh[8*128];
  #pragma unroll
  for (int j = 0; j < 8; j++){
    float2 hv = *(const float2*)&hacc[(size_t)(n0+j)*C + 2*tid];
    sh[j*128 + tid] = pk2(hv.x, hv.y);
  }
  __syncthreads();
  float a0[8] = {0,0,0,0,0,0,0,0};
  float a1[8] = {0,0,0,0,0,0,0,0};
  int c0 = p*256 + tid, c1 = c0 + 128;
  for (int k2 = 0; k2 < 128; k2 += 4){
    unsigned w00 = wtp[(k2+0)*768 + c0], w01 = wtp[(k2+1)*768 + c0],
             w02 = wtp[(k2+2)*768 + c0], w03 = wtp[(k2+3)*768 + c0];
    unsigned w10 = wtp[(k2+0)*768 + c1], w11 = wtp[(k2+1)*768 + c1],
             w12 = wtp[(k2+2)*768 + c1], w13 = wtp[(k2+3)*768 + c1];
    #pragma unroll
    for (int j = 0; j < 8; j++){
      uint4 hp = *(uint4*)&sh[j*128 + k2];
      a0[j] = fdot2u(hp.x, w00, a0[j]); a0[j] = fdot2u(hp.y, w01, a0[j]);
      a0[j] = fdot2u(hp.z, w02, a0[j]); a0[j] = fdot2u(hp.w, w03, a0[j]);
      a1[j] = fdot2u(hp.x, w10, a1[j]); a1[j] = fdot2u(hp.y, w11, a1[j]);
      a1[j] = fdot2u(hp.z, w12, a1[j]); a1[j] = fdot2u(hp.w, w13, a1[j]);
    }
  }
  float b0 = ipb[c0], b1 = ipb[c1];
  #pragma unroll
  for (int j = 0; j < 8; j++){
    qkv[(size_t)(n0+j)*768 + c0] = a0[j] + b0;
    qkv[(size_t)(n0+j)*768 + c1] = a1[j] + b1;
  }
}

// R12: multi-wave MFMA flash attention. Block = 4 waves (256 thr); each wave
// owns one 64-row n-tile of a 256-row n-block. K and V^T staged cooperatively
// ONCE per block (4x fewer global loads / LDS writes per wave); Q fragments
// live in REGISTERS (32 VGPR, loaded once -- no Qs buffer, no per-tile Q reads);
// per-wave private P buffer -> PV phase needs no barrier (in-wave lgkmcnt
// ordering). 54KB LDS -> 2 blocks/CU = 2 waves/SIMD (R11 post-mortem: 1
// wave/SIMD left ds_read->MFMA and exp latency fully exposed: MfmaUtil 6.8%,
// VALU 17%, occupancy 8%).
__global__ __launch_bounds__(256, 2) void attn_k(const float* __restrict__ qkv,
                                                 float* __restrict__ opart,
                                                 float* __restrict__ dpart){
  __shared__ __align__(16) _Float16 Ks[64*QKS];    // [m][k]
  __shared__ __align__(16) _Float16 VTs[64*QKS];   // [d][m]
  __shared__ __align__(16) _Float16 Ps[4][64*QKS]; // per-wave [n][m]
  int tid = threadIdx.x;
  int wave = tid >> 6, l = tid & 63;
  int nb = blockIdx.x*256 + wave*64;
  int h = blockIdx.y, mc = blockIdx.z;
  int r16 = l & 15, q = l >> 4;
  _Float16* Pw = Ps[wave];

  // Q fragments (B operand) in registers, prescaled by 1/8
  v8h qf[4][2];
  #pragma unroll
  for (int ni = 0; ni < 4; ni++){
    const float* qrow = qkv + (size_t)(nb + ni*16 + r16)*768 + h*64;
    #pragma unroll
    for (int kk = 0; kk < 2; kk++){
      float4 a = *(const float4*)(qrow + kk*32 + q*8);
      float4 b = *(const float4*)(qrow + kk*32 + q*8 + 4);
      v8h hv = {(_Float16)(a.x*0.125f), (_Float16)(a.y*0.125f),
                (_Float16)(a.z*0.125f), (_Float16)(a.w*0.125f),
                (_Float16)(b.x*0.125f), (_Float16)(b.y*0.125f),
                (_Float16)(b.z*0.125f), (_Float16)(b.w*0.125f)};
      qf[ni][kk] = hv;
    }
  }

  v4f o[4][4];
  #pragma unroll
  for (int i = 0; i < 4; i++)
    #pragma unroll
    for (int j = 0; j < 4; j++) o[i][j] = (v4f){0.f,0.f,0.f,0.f};
  float dn[4] = {0.f,0.f,0.f,0.f};

  for (int mt = 0; mt < NN/MCH/64; mt++){
    int mb = mc*(NN/MCH) + mt*64;
    __syncthreads();                    // all waves done reading prev Ks/VTs
    // cooperative K stage: thread = (row, 16-half quarter)
    {
      int sr = tid >> 2, sc = (tid & 3)*16;
      const float* krow = qkv + (size_t)(mb + sr)*768 + 256 + h*64 + sc;
      float4 a = *(const float4*)(krow + 0);
      float4 b = *(const float4*)(krow + 4);
      float4 cc = *(const float4*)(krow + 8);
      float4 d = *(const float4*)(krow + 12);
      v8h h0 = {(_Float16)a.x, (_Float16)a.y, (_Float16)a.z, (_Float16)a.w,
                (_Float16)b.x, (_Float16)b.y, (_Float16)b.z, (_Float16)b.w};
      v8h h1 = {(_Float16)cc.x, (_Float16)cc.y, (_Float16)cc.z, (_Float16)cc.w,
                (_Float16)d.x, (_Float16)d.y, (_Float16)d.z, (_Float16)d.w};
      *(v8h*)(Ks + (size_t)sr*QKS + sc) = h0;
      *(v8h*)(Ks + (size_t)sr*QKS + sc + 8) = h1;
    }
    // cooperative V^T stage: thread = (m-pair, d-eighth); paired u32 writes
    {
      int m0 = (tid & 31)*2;
      int db = (tid >> 5)*8;
      const float* v0 = qkv + (size_t)(mb + m0)*768 + 512 + h*64 + db;
      const float* v1 = v0 + 768;
      #pragma unroll
      for (int i = 0; i < 2; i++){
        float4 a = *(const float4*)(v0 + 4*i);
        float4 b = *(const float4*)(v1 + 4*i);
        int d = db + 4*i;
        *(unsigned*)(VTs + (size_t)(d+0)*QKS + m0) = pk2(a.x, b.x);
        *(unsigned*)(VTs + (size_t)(d+1)*QKS + m0) = pk2(a.y, b.y);
        *(unsigned*)(VTs + (size_t)(d+2)*QKS + m0) = pk2(a.z, b.z);
        *(unsigned*)(VTs + (size_t)(d+3)*QKS + m0) = pk2(a.w, b.w);
      }
    }
    __syncthreads();
    // S^T = K.Q^T : c[mi][ni]; A-frag K rows, B-frag Q regs
    v4f c[4][4];
    #pragma unroll
    for (int i = 0; i < 4; i++)
      #pragma unroll
      for (int j = 0; j < 4; j++) c[i][j] = (v4f){0.f,0.f,0.f,0.f};
    #pragma unroll
    for (int kk = 0; kk < 2; kk++){
      v8h a[4];
      #pragma unroll
      for (int mi = 0; mi < 4; mi++) a[mi] = *(v8h*)(Ks + (size_t)(mi*16 + r16)*QKS + kk*32 + q*8);
      #pragma unroll
      for (int mi = 0; mi < 4; mi++)
        #pragma unroll
        for (int ni = 0; ni < 4; ni++)
          c[mi][ni] = __builtin_amdgcn_mfma_f32_16x16x32_f16(a[mi], qf[ni][kk], c[mi][ni], 0, 0, 0);
    }
    // exp + denominator + pack P[n][m] (lane's 4 vals m-consecutive)
    #pragma unroll
    for (int mi = 0; mi < 4; mi++)
      #pragma unroll
      for (int ni = 0; ni < 4; ni++){
        float e0 = __expf(c[mi][ni][0]), e1 = __expf(c[mi][ni][1]),
              e2 = __expf(c[mi][ni][2]), e3 = __expf(c[mi][ni][3]);
        dn[ni] += e0 + e1 + e2 + e3;
        *(uint2*)(Pw + (size_t)(ni*16 + r16)*QKS + mi*16 + q*4) = make_uint2(pk2(e0,e1), pk2(e2,e3));
      }
    // O += P.V : no barrier (Pw private to wave; VTs stable until next barrier)
    #pragma unroll
    for (int km = 0; km < 2; km++){
      v8h pa[4], vb[4];
      #pragma unroll
      for (int ni = 0; ni < 4; ni++) pa[ni] = *(v8h*)(Pw + (size_t)(ni*16 + r16)*QKS + km*32 + q*8);
      #pragma unroll
      for (int di = 0; di < 4; di++) vb[di] = *(v8h*)(VTs + (size_t)(di*16 + r16)*QKS + km*32 + q*8);
      #pragma unroll
      for (int ni = 0; ni < 4; ni++)
        #pragma unroll
        for (int di = 0; di < 4; di++)
          o[ni][di] = __builtin_amdgcn_mfma_f32_16x16x32_f16(pa[ni], vb[di], o[ni][di], 0, 0, 0);
    }
  }

  // write O: lane holds O[n=ni*16+q*4+r][d=di*16+r16]
  float* ob = opart + ((size_t)mc*NN + nb)*C + h*64;
  #pragma unroll
  for (int ni = 0; ni < 4; ni++)
    #pragma unroll
    for (int di = 0; di < 4; di++)
      #pragma unroll
      for (int r = 0; r < 4; r++)
        ob[(size_t)(ni*16 + q*4 + r)*C + di*16 + r16] = o[ni][di][r];
  // dn: quad-partial sums -> reduce across quads, quad 0 stores (no atomics)
  #pragma unroll
  for (int ni = 0; ni < 4; ni++){
    dn[ni] += __shfl_xor(dn[ni], 16);
    dn[ni] += __shfl_xor(dn[ni], 32);
  }
  if (q == 0){
    #pragma unroll
    for (int ni = 0; ni < 4; ni++)
      dpart[((size_t)mc*NN + nb + ni*16 + r16)*AHD + h] = dn[ni];
  }
}

__global__ __launch_bounds__(256) void attnred_k(const float* __restrict__ opart, const float* __restrict__ dpart,
                                                 float* omean){
  int r0 = blockIdx.x*128, c = threadIdx.x;
  int head = c >> 6;
  float s = 0.f;
  for (int r = 0; r < 128; r++){
    int n = r0 + r;
    float dsum = 0.f, osum = 0.f;
    #pragma unroll
    for (int mc = 0; mc < MCH; mc++){
      dsum += dpart[((size_t)mc*NN + n)*AHD + head];
      osum += opart[((size_t)mc*NN + n)*C + c];
    }
    s += osum / (dsum + 1e-16f);
  }
  atomicAdd(&omean[c], s*(1.f/4096.f));
}

__global__ __launch_bounds__(256) void attnproj_k(const float* __restrict__ omean, const float* __restrict__ opw,
                                                  const float* __restrict__ opb, float* attnp){
  __shared__ float sh[256];
  int j = threadIdx.x;
  sh[j] = omean[j];
  __syncthreads();
  float acc = opb[j];
  for (int k = 0; k < 256; k++) acc += sh[k]*opw[j*256 + k];
  attnp[j] = acc;
}

__global__ __launch_bounds__(512) void fus1_k(const float* __restrict__ meanp, const float* __restrict__ maxp,
                                              const float* __restrict__ attnp, const float* __restrict__ fw1,
                                              const float* __restrict__ fb1, float* g1){
  __shared__ float comb[768];
  for (int i = threadIdx.x; i < 768; i += 512)
    comb[i] = (i < 256) ? meanp[i] : (i < 512 ? maxp[i-256] : attnp[i-512]);
  __syncthreads();
  int j = threadIdx.x;
  float acc = fb1[j];
  for (int k = 0; k < 768; k++) acc += comb[k]*fw1[k*512 + j];
  g1[j] = fmaxf(acc, 0.f);
}

__global__ __launch_bounds__(256) void fus2_k(const float* __restrict__ g1, const float* __restrict__ fw2,
                                              const float* __restrict__ fb2, float* __restrict__ out){
  __shared__ float g[512];
  g[threadIdx.x] = g1[threadIdx.x];
  g[threadIdx.x + 256] = g1[threadIdx.x + 256];
  __syncthreads();
  int j = threadIdx.x;
  float acc = fb2[j];
  for (int k = 0; k < 512; k++) acc += g[k]*fw2[k*256 + j];
  out[j] = fmaxf(acc, 0.f);
}

extern "C" void kernel_launch(void* const* d_in, const int* in_sizes, int n_in,
                              void* d_out, int out_size, void* d_ws, size_t ws_size,
                              hipStream_t stream){
  const float* x     = (const float*)d_in[0];
  const int*   srcv  = (const int*)d_in[1];
  const int*   dstv  = (const int*)d_in[2];
  const float* eattr = (const float*)d_in[3];
  const int*   etyp  = (const int*)d_in[4];
  const float* W0    = (const float*)d_in[5];
  const float* W12   = (const float*)d_in[6];
  const float* attS  = (const float*)d_in[7];
  const float* attD  = (const float*)d_in[8];
  const float* attE  = (const float*)d_in[9];
  const float* linE  = (const float*)d_in[10];
  const float* bias  = (const float*)d_in[11];
  const float* etw   = (const float*)d_in[12];
  const float* ipw   = (const float*)d_in[13];
  const float* ipb   = (const float*)d_in[14];
  const float* opw   = (const float*)d_in[15];
  const float* opb   = (const float*)d_in[16];
  const float* fw1   = (const float*)d_in[17];
  const float* fb1   = (const float*)d_in[18];
  const float* fw2   = (const float*)d_in[19];
  const float* fb2   = (const float*)d_in[20];
  float* out = (float*)d_out;

  if (ws_size < (size_t)WS_WORDS*4) return;

  int*      ip   = (int*)d_ws;
  float*    fp   = (float*)d_ws;
  unsigned* wtp  = (unsigned*)(fp + F_WT);
  unsigned* w12p = (unsigned*)(fp + U_W12P);

  zero_k<<<(NN*T + 255)/256, 256, 0, stream>>>(fp + F_MEANP, NZERO, ip + W_CURSOR, NN*T);
  initmax_k<<<1, 256, 0, stream>>>(fp + F_MAXP);

  hist_k<<<EE/256, 256, 0, stream>>>(dstv, etyp, ip + W_CURSOR);
  scan_k<<<1, 1024, 0, stream>>>(ip + W_CURSOR, ip + W_OFF, ip + W_CURSOR);
  scatter_k<<<EE/256, 256, 0, stream>>>(dstv, etyp, ip + W_CURSOR, ip + W_SORTED);

  // weight packing prepass
  pack12_k<<<dim3(128, T*2), 256, 0, stream>>>(W12, w12p);
  packT_k<<<dim3(128, 3), 256, 0, stream>>>(ipw, wtp);

  // all-layer prepass: we, se, sloop
  we2_k<<<dim3(T, LL), 256, 0, stream>>>(linE, attE, fp + F_WE);
  se_k<<<dim3(EE/256, LL), 256, 0, stream>>>(eattr, etyp, fp + F_WE, fp + F_SE);
  sloop_k<<<dim3((NN*T)/256, LL), 256, 0, stream>>>(ip + W_OFF, ip + W_SORTED, fp + F_SE, fp + F_SLOOP);

  for (int l = 0; l < 3; l++){
    if (l == 0)
      gemm_k<<<dim3(NN/8, T), 256, 0, stream>>>(x, DIN, W0, (long)DIN*C, attS, attD, 0,
                                                fp + F_XL, fp + F_SSRC, fp + F_SDST);
    else
      gemm16_k<<<dim3(NN/8, T), 128, 0, stream>>>(fp + F_H, w12p, attS, attD, l,
                                                  fp + F_XL, fp + F_SSRC, fp + F_SDST);
    agg_k<<<dim3(NN, T), 256, 0, stream>>>(fp + F_XL, fp + F_SSRC, fp + F_SDST,
                                           fp + F_SE + (size_t)l*EE,
                                           fp + F_SLOOP + (size_t)l*(NN*T),
                                           ip + W_OFF, ip + W_SORTED, srcv,
                                           bias, fp + F_H, l);
  }

  hacc_k<<<NN, 256, 0, stream>>>(fp + F_H, etw, fp + F_HACC);
  colstats_k<<<32, 256, 0, stream>>>(fp + F_HACC, fp + F_MEANP, fp + F_MAXP);

  qkv16_k<<<dim3(NN/8, 3), 128, 0, stream>>>(fp + F_HACC, wtp, ipb, fp + F_QKV);
  attn_k<<<dim3(NN/256, AHD, MCH), 256, 0, stream>>>(fp + F_QKV, fp + F_OPART, fp + F_DPART);
  attnred_k<<<32, 256, 0, stream>>>(fp + F_OPART, fp + F_DPART, fp + F_OMEAN);
  attnproj_k<<<1, 256, 0, stream>>>(fp + F_OMEAN, opw, opb, fp + F_ATTNP);

  fus1_k<<<1, 512, 0, stream>>>(fp + F_MEANP, fp + F_MAXP, fp + F_ATTNP, fw1, fb1, fp + F_G1);
  fus2_k<<<1, 256, 0, stream>>>(fp + F_G1, fw2, fb2, out);
}

// Round 13
// 486.075 us; speedup vs baseline: 2.0736x; 1.1315x over previous
//
#include <hip/hip_runtime.h>
#include <math.h>

#define T 4
#define LL 3
#define C 256
#define DIN 20
#define NN 4096
#define EE 65536
#define AHD 4
#define MCH 8     // attention m-chunks (blockIdx.z); grid 16x4x8=512 blocks = 2/CU
#define QKS 72    // padded LDS row stride in halfs (64+8): +4 banks/row -> 2-way (free)

// ---- workspace layout (4-byte word offsets) ----
#define W_OFF    0                    // int[N*T+1]
#define W_CURSOR 16640                // int[N*T]  (also hist counts)
#define W_SORTED 33024                // int[E]
#define F_XL     98560                // float[T][N][C]
#define F_H      (F_XL + T*NN*C)      // float[T][N][C]
#define F_OPART  F_XL                 // alias: float[MCH][N][C] == exactly F_XL+F_H extent (dead at attn time)
#define F_SSRC   (F_H + T*NN*C)       // float[T][N]
#define F_SDST   (F_SSRC + T*NN)      // float[T][N]
#define F_SE     (F_SDST + T*NN)      // float[LL][E]
#define F_SLOOP  (F_SE + LL*EE)       // float[LL][N*T] indexed l*NT + n*T+t
#define F_WE     (F_SLOOP + LL*T*NN)  // float[T*LL][10] (padded 128)
#define F_HACC   (F_WE + 128)         // float[N][C]
#define F_WT     (F_HACC + NN*C)      // u32[128][768] packed f16-pair in_proj_w^T (region reserved 768*256)
#define F_QKV    (F_WT + 768*256)     // float[N][768]
#define F_DPART  (F_QKV + NN*768)     // float[MCH][N][AH]
#define F_MEANP  (F_DPART + MCH*NN*AHD) // float[C]
#define F_MAXP   (F_MEANP + C)        // float[C]
#define F_OMEAN  (F_MAXP + C)         // float[C]
#define F_ATTNP  (F_OMEAN + C)        // float[C]
#define F_G1     (F_ATTNP + C)        // float[512]
#define U_W12P   (F_G1 + 512)         // u32[T*2][128][256] packed f16-pair W12
#define WS_WORDS (U_W12P + 262144)
#define NZERO (3*C)                   // meanp, maxp, omean (opart/dpart fully direct-stored)

static __device__ __forceinline__ float lrelu(float x){ return x > 0.f ? x : 0.2f*x; }
static __device__ __forceinline__ float eluf(float x){ return x > 0.f ? x : __expf(x) - 1.f; }

typedef _Float16 half2_t __attribute__((ext_vector_type(2)));
typedef _Float16 v8h __attribute__((ext_vector_type(8)));
typedef float v4f __attribute__((ext_vector_type(4)));

static __device__ __forceinline__ unsigned pk2(float x, float y){
  half2_t h; h.x = (_Float16)x; h.y = (_Float16)y;
  return __builtin_bit_cast(unsigned, h);
}
#if __has_builtin(__builtin_amdgcn_fdot2)
static __device__ __forceinline__ float fdot2u(unsigned a, unsigned b, float c){
  return __builtin_amdgcn_fdot2(__builtin_bit_cast(half2_t, a), __builtin_bit_cast(half2_t, b), c, false);
}
#else
static __device__ __forceinline__ float fdot2u(unsigned a, unsigned b, float c){
  half2_t ha = __builtin_bit_cast(half2_t, a), hb = __builtin_bit_cast(half2_t, b);
  return c + (float)ha.x*(float)hb.x + (float)ha.y*(float)hb.y;
}
#endif

static __device__ inline void atomicMaxF(float* addr, float val){
  int* ai = (int*)addr;
  int old = __float_as_int(*addr);
  while (__int_as_float(old) < val){
    int assumed = old;
    old = atomicCAS(ai, assumed, __float_as_int(val));
    if (old == assumed) break;
  }
}

__global__ __launch_bounds__(256) void zero_k(float* fz, int nf, int* iz, int ni){
  int i = blockIdx.x*256 + threadIdx.x;
  if (i < nf) fz[i] = 0.f;
  if (i < ni) iz[i] = 0;
}
__global__ __launch_bounds__(256) void initmax_k(float* maxp){ maxp[threadIdx.x] = -1e30f; }

__global__ __launch_bounds__(256) void hist_k(const int* __restrict__ dst, const int* __restrict__ ety, int* cnt){
  int e = blockIdx.x*256 + threadIdx.x;
  if (e < EE) atomicAdd(&cnt[dst[e]*T + ety[e]], 1);
}

__global__ __launch_bounds__(1024) void scan_k(int* cnt, int* off, int* cursor){
  __shared__ int part[1024];
  int tid = threadIdx.x;
  int base = tid*16;
  int loc[16]; int s = 0;
  for (int i = 0; i < 16; i++){ loc[i] = cnt[base+i]; s += loc[i]; }
  part[tid] = s; __syncthreads();
  int v = s;
  for (int offn = 1; offn < 1024; offn <<= 1){
    int add = (tid >= offn) ? part[tid-offn] : 0;
    __syncthreads();
    v += add; part[tid] = v;
    __syncthreads();
  }
  int excl = v - s;
  for (int i = 0; i < 16; i++){ off[base+i] = excl; cursor[base+i] = excl; excl += loc[i]; }
  if (tid == 1023) off[NN*T] = excl;
}

__global__ __launch_bounds__(256) void scatter_k(const int* __restrict__ dst, const int* __restrict__ ety,
                                                 int* cursor, int* sorted){
  int e = blockIdx.x*256 + threadIdx.x;
  if (e < EE){
    int p = atomicAdd(&cursor[dst[e]*T + ety[e]], 1);
    sorted[p] = e;
  }
}

// pack W12 [t][i][256][256] -> f16-pair u32 [t*2+i][128][256]
__global__ __launch_bounds__(256) void pack12_k(const float* __restrict__ w, unsigned* __restrict__ wp){
  int b = blockIdx.y, k2 = blockIdx.x, c = threadIdx.x;
  const float* s = w + (size_t)b*C*C;
  wp[((size_t)b*128 + k2)*C + c] = pk2(s[(2*k2)*C + c], s[(2*k2+1)*C + c]);
}

// pack in_proj_w [768][256] -> transposed f16-pair u32 [128][768]
__global__ __launch_bounds__(256) void packT_k(const float* __restrict__ ipw, unsigned* __restrict__ wtp){
  int k2 = blockIdx.x, j = blockIdx.y*256 + threadIdx.x;
  wtp[k2*768 + j] = pk2(ipw[(size_t)j*C + 2*k2], ipw[(size_t)j*C + 2*k2 + 1]);
}

// we[t][l][k] = sum_c lin_edge_w[t,l,k,c] * att_edge[t,l,0,c]  -- all (t,l) in one launch
__global__ __launch_bounds__(256) void we2_k(const float* __restrict__ linE, const float* __restrict__ attE,
                                             float* we){
  int t = blockIdx.x, l = blockIdx.y, c = threadIdx.x;
  __shared__ float part[10*C];
  float ae = attE[(t*LL + l)*C + c];
  const float* lw = linE + (size_t)((t*LL + l)*10)*C;
  for (int k = 0; k < 10; k++) part[k*C + c] = lw[k*C + c]*ae;
  __syncthreads();
  if (c < 10){
    float s = 0.f;
    for (int i = 0; i < C; i++) s += part[c*C + i];
    we[(t*LL + l)*10 + c] = s;
  }
}

// layer 0 only (K=20, cheap): fp32 path, fused ssd reduction
__global__ __launch_bounds__(256) void gemm_k(const float* __restrict__ hin, int K,
                                              const float* __restrict__ Wb, long wtstr,
                                              const float* __restrict__ attS, const float* __restrict__ attD,
                                              int l, float* __restrict__ xlo,
                                              float* __restrict__ ssrc, float* __restrict__ sdst){
  int t = blockIdx.y;
  const float* h = hin;
  const float* W = Wb + (size_t)t*wtstr;
  int n0 = blockIdx.x*8;
  __shared__ float sh[8*256];
  __shared__ float red[64];
  for (int j = 0; j < 8; j++)
    for (int k = threadIdx.x; k < K; k += 256)
      sh[j*K + k] = h[(n0+j)*K + k];
  __syncthreads();
  float acc[8] = {0,0,0,0,0,0,0,0};
  int c = threadIdx.x;
  for (int k = 0; k < K; k += 4){
    float w0 = W[(k+0)*C + c], w1 = W[(k+1)*C + c], w2 = W[(k+2)*C + c], w3 = W[(k+3)*C + c];
    #pragma unroll
    for (int j = 0; j < 8; j++){
      float4 h4 = *(const float4*)&sh[j*K + k];
      acc[j] += w0*h4.x + w1*h4.y + w2*h4.z + w3*h4.w;
    }
  }
  #pragma unroll
  for (int j = 0; j < 8; j++) xlo[(t*NN + n0 + j)*C + c] = acc[j];
  float aS = attS[(t*LL + l)*C + c], aD = attD[(t*LL + l)*C + c];
  int lane = c & 63, w = c >> 6;
  #pragma unroll
  for (int j = 0; j < 8; j++){
    float v1 = acc[j]*aS, v2 = acc[j]*aD;
    #pragma unroll
    for (int off = 32; off > 0; off >>= 1){ v1 += __shfl_down(v1, off); v2 += __shfl_down(v2, off); }
    if (lane == 0){ red[j*8 + w] = v1; red[j*8 + 4 + w] = v2; }
  }
  __syncthreads();
  if (c < 16){
    int j = c >> 1, which = c & 1;
    const float* r = red + j*8 + which*4;
    float s = r[0] + r[1] + r[2] + r[3];
    (which ? sdst : ssrc)[t*NN + n0 + j] = s;
  }
}

// layers 1,2 (K=256) as f16-pair dot2 GEMM (R10)
__global__ __launch_bounds__(128) void gemm16_k(const float* __restrict__ hin,
                                                const unsigned* __restrict__ w12p,
                                                const float* __restrict__ attS, const float* __restrict__ attD,
                                                int l, float* __restrict__ xlo,
                                                float* __restrict__ ssrc, float* __restrict__ sdst){
  int t = blockIdx.y;
  const float* h = hin + (size_t)t*NN*C;
  const unsigned* W = w12p + ((size_t)(t*2 + (l-1)))*128*C;
  int n0 = blockIdx.x*8;
  int tid = threadIdx.x;
  __shared__ unsigned sh[8*128];
  __shared__ float red[32];
  #pragma unroll
  for (int j = 0; j < 8; j++){
    float2 hv = *(const float2*)&h[(size_t)(n0+j)*C + 2*tid];
    sh[j*128 + tid] = pk2(hv.x, hv.y);
  }
  __syncthreads();
  float a0[8] = {0,0,0,0,0,0,0,0};
  float a1[8] = {0,0,0,0,0,0,0,0};
  int c0 = tid, c1 = tid + 128;
  for (int k2 = 0; k2 < 128; k2 += 4){
    unsigned w00 = W[(k2+0)*C + c0], w01 = W[(k2+1)*C + c0],
             w02 = W[(k2+2)*C + c0], w03 = W[(k2+3)*C + c0];
    unsigned w10 = W[(k2+0)*C + c1], w11 = W[(k2+1)*C + c1],
             w12 = W[(k2+2)*C + c1], w13 = W[(k2+3)*C + c1];
    #pragma unroll
    for (int j = 0; j < 8; j++){
      uint4 hp = *(uint4*)&sh[j*128 + k2];
      a0[j] = fdot2u(hp.x, w00, a0[j]); a0[j] = fdot2u(hp.y, w01, a0[j]);
      a0[j] = fdot2u(hp.z, w02, a0[j]); a0[j] = fdot2u(hp.w, w03, a0[j]);
      a1[j] = fdot2u(hp.x, w10, a1[j]); a1[j] = fdot2u(hp.y, w11, a1[j]);
      a1[j] = fdot2u(hp.z, w12, a1[j]); a1[j] = fdot2u(hp.w, w13, a1[j]);
    }
  }
  #pragma unroll
  for (int j = 0; j < 8; j++){
    xlo[(t*NN + n0 + j)*C + c0] = a0[j];
    xlo[(t*NN + n0 + j)*C + c1] = a1[j];
  }
  float aS0 = attS[(t*LL + l)*C + c0], aS1 = attS[(t*LL + l)*C + c1];
  float aD0 = attD[(t*LL + l)*C + c0], aD1 = attD[(t*LL + l)*C + c1];
  int lane = tid & 63, w = tid >> 6;
  #pragma unroll
  for (int j = 0; j < 8; j++){
    float v1 = a0[j]*aS0 + a1[j]*aS1;
    float v2 = a0[j]*aD0 + a1[j]*aD1;
    #pragma unroll
    for (int off = 32; off > 0; off >>= 1){ v1 += __shfl_down(v1, off); v2 += __shfl_down(v2, off); }
    if (lane == 0){ red[j*4 + w*2 + 0] = v1; red[j*4 + w*2 + 1] = v2; }
  }
  __syncthreads();
  if (tid < 16){
    int j = tid >> 1, which = tid & 1;
    float s = red[j*4 + which] + red[j*4 + 2 + which];
    (which ? sdst : ssrc)[t*NN + n0 + j] = s;
  }
}

// all layers at once: se[l][e]
__global__ __launch_bounds__(256) void se_k(const float* __restrict__ eattr, const int* __restrict__ ety,
                                            const float* __restrict__ we, float* se){
  int e = blockIdx.x*256 + threadIdx.x;
  int l = blockIdx.y;
  if (e < EE){
    const float* w = we + (ety[e]*LL + l)*10;
    const float* ea = eattr + e*10;
    float s = 0.f;
    #pragma unroll
    for (int k = 0; k < 10; k++) s += ea[k]*w[k];
    se[(size_t)l*EE + e] = s;
  }
}

// all layers at once: sloop[l][i]
__global__ __launch_bounds__(256) void sloop_k(const int* __restrict__ off, const int* __restrict__ sorted,
                                               const float* __restrict__ se, float* sloop){
  int i = blockIdx.x*256 + threadIdx.x;
  int l = blockIdx.y;
  if (i < NN*T){
    int o0 = off[i], o1 = off[i+1];
    const float* sel = se + (size_t)l*EE;
    float s = 0.f;
    for (int j = o0; j < o1; j++) s += sel[sorted[j]];
    int dg = o1 - o0;
    sloop[(size_t)l*(NN*T) + i] = s / (float)(dg > 0 ? dg : 1);
  }
}

__global__ __launch_bounds__(256) void agg_k(const float* __restrict__ xl, const float* __restrict__ ssrc,
                                             const float* __restrict__ sdst, const float* __restrict__ se,
                                             const float* __restrict__ sloop, const int* __restrict__ off,
                                             const int* __restrict__ sorted, const int* __restrict__ srcv,
                                             const float* __restrict__ bias, float* __restrict__ hout, int l){
  int n = blockIdx.x, t = blockIdx.y;
  int i = n*T + t;
  int o0 = off[i];
  int deg = off[i+1] - o0;
  if (deg > 512) deg = 512;
  __shared__ float sc[512];
  __shared__ int sj[512];
  __shared__ float sInv, sAL;
  for (int j = threadIdx.x; j < deg; j += 256){
    int e = sorted[o0 + j];
    int sn = srcv[e];
    sc[j] = lrelu(ssrc[t*NN + sn] + sdst[t*NN + n] + se[e]);
    sj[j] = sn;
  }
  __syncthreads();
  if (threadIdx.x == 0){
    float al = lrelu(ssrc[t*NN + n] + sdst[t*NN + n] + sloop[i]);
    float mx = al;
    for (int j = 0; j < deg; j++) mx = fmaxf(mx, sc[j]);
    float al_e = __expf(al - mx);
    float ssum = al_e;
    for (int j = 0; j < deg; j++){ float ex = __expf(sc[j] - mx); sc[j] = ex; ssum += ex; }
    sInv = 1.f/(ssum + 1e-16f);
    sAL = al_e;
  }
  __syncthreads();
  int c = threadIdx.x;
  float acc = sAL * xl[(t*NN + n)*C + c];
  for (int j = 0; j < deg; j++) acc += sc[j] * xl[(t*NN + sj[j])*C + c];
  acc = acc*sInv + bias[(t*LL + l)*C + c];
  hout[(t*NN + n)*C + c] = eluf(acc);
}

__global__ __launch_bounds__(256) void hacc_k(const float* __restrict__ h, const float* __restrict__ etw,
                                              float* __restrict__ hacc){
  int n = blockIdx.x, c = threadIdx.x;
  float e0 = etw[0], e1 = etw[1], e2 = etw[2], e3 = etw[3];
  float m = fmaxf(fmaxf(e0,e1), fmaxf(e2,e3));
  float w0 = __expf(e0-m), w1 = __expf(e1-m), w2 = __expf(e2-m), w3 = __expf(e3-m);
  float inv = 1.f/(w0+w1+w2+w3);
  float s = w0*h[(0*NN+n)*C+c] + w1*h[(1*NN+n)*C+c] + w2*h[(2*NN+n)*C+c] + w3*h[(3*NN+n)*C+c];
  hacc[n*C + c] = s*inv;
}

__global__ __launch_bounds__(256) void colstats_k(const float* __restrict__ hacc, float* meanp, float* maxp){
  int r0 = blockIdx.x*128, c = threadIdx.x;
  float sm = 0.f, mx = -1e30f;
  for (int r = 0; r < 128; r++){
    float v = hacc[(r0+r)*C + c];
    sm += v; mx = fmaxf(mx, v);
  }
  atomicAdd(&meanp[c], sm*(1.f/4096.f));
  atomicMaxF(&maxp[c], mx);
}

// qkv as f16-pair dot2 GEMM (R10), packed WT
__global__ __launch_bounds__(128) void qkv16_k(const float* __restrict__ hacc,
                                               const unsigned* __restrict__ wtp,
                                               const float* __restrict__ ipb, float* __restrict__ qkv){
  int p = blockIdx.y;
  int n0 = blockIdx.x*8;
  int tid = threadIdx.x;
  __shared__ unsigned sh[8*128];
  #pragma unroll
  for (int j = 0; j < 8; j++){
    float2 hv = *(const float2*)&hacc[(size_t)(n0+j)*C + 2*tid];
    sh[j*128 + tid] = pk2(hv.x, hv.y);
  }
  __syncthreads();
  float a0[8] = {0,0,0,0,0,0,0,0};
  float a1[8] = {0,0,0,0,0,0,0,0};
  int c0 = p*256 + tid, c1 = c0 + 128;
  for (int k2 = 0; k2 < 128; k2 += 4){
    unsigned w00 = wtp[(k2+0)*768 + c0], w01 = wtp[(k2+1)*768 + c0],
             w02 = wtp[(k2+2)*768 + c0], w03 = wtp[(k2+3)*768 + c0];
    unsigned w10 = wtp[(k2+0)*768 + c1], w11 = wtp[(k2+1)*768 + c1],
             w12 = wtp[(k2+2)*768 + c1], w13 = wtp[(k2+3)*768 + c1];
    #pragma unroll
    for (int j = 0; j < 8; j++){
      uint4 hp = *(uint4*)&sh[j*128 + k2];
      a0[j] = fdot2u(hp.x, w00, a0[j]); a0[j] = fdot2u(hp.y, w01, a0[j]);
      a0[j] = fdot2u(hp.z, w02, a0[j]); a0[j] = fdot2u(hp.w, w03, a0[j]);
      a1[j] = fdot2u(hp.x, w10, a1[j]); a1[j] = fdot2u(hp.y, w11, a1[j]);
      a1[j] = fdot2u(hp.z, w12, a1[j]); a1[j] = fdot2u(hp.w, w13, a1[j]);
    }
  }
  float b0 = ipb[c0], b1 = ipb[c1];
  #pragma unroll
  for (int j = 0; j < 8; j++){
    qkv[(size_t)(n0+j)*768 + c0] = a0[j] + b0;
    qkv[(size_t)(n0+j)*768 + c1] = a1[j] + b1;
  }
}

// R12: multi-wave MFMA flash attention (4 waves/block, coop K/V^T stage,
// Q in registers, per-wave P buffer; 2 blocks/CU)
__global__ __launch_bounds__(256, 2) void attn_k(const float* __restrict__ qkv,
                                                 float* __restrict__ opart,
                                                 float* __restrict__ dpart){
  __shared__ __align__(16) _Float16 Ks[64*QKS];    // [m][k]
  __shared__ __align__(16) _Float16 VTs[64*QKS];   // [d][m]
  __shared__ __align__(16) _Float16 Ps[4][64*QKS]; // per-wave [n][m]
  int tid = threadIdx.x;
  int wave = tid >> 6, l = tid & 63;
  int nb = blockIdx.x*256 + wave*64;
  int h = blockIdx.y, mc = blockIdx.z;
  int r16 = l & 15, q = l >> 4;
  _Float16* Pw = Ps[wave];

  // Q fragments (B operand) in registers, prescaled by 1/8
  v8h qf[4][2];
  #pragma unroll
  for (int ni = 0; ni < 4; ni++){
    const float* qrow = qkv + (size_t)(nb + ni*16 + r16)*768 + h*64;
    #pragma unroll
    for (int kk = 0; kk < 2; kk++){
      float4 a = *(const float4*)(qrow + kk*32 + q*8);
      float4 b = *(const float4*)(qrow + kk*32 + q*8 + 4);
      v8h hv = {(_Float16)(a.x*0.125f), (_Float16)(a.y*0.125f),
                (_Float16)(a.z*0.125f), (_Float16)(a.w*0.125f),
                (_Float16)(b.x*0.125f), (_Float16)(b.y*0.125f),
                (_Float16)(b.z*0.125f), (_Float16)(b.w*0.125f)};
      qf[ni][kk] = hv;
    }
  }

  v4f o[4][4];
  #pragma unroll
  for (int i = 0; i < 4; i++)
    #pragma unroll
    for (int j = 0; j < 4; j++) o[i][j] = (v4f){0.f,0.f,0.f,0.f};
  float dn[4] = {0.f,0.f,0.f,0.f};

  for (int mt = 0; mt < NN/MCH/64; mt++){
    int mb = mc*(NN/MCH) + mt*64;
    __syncthreads();                    // all waves done reading prev Ks/VTs
    // cooperative K stage: thread = (row, 16-half quarter)
    {
      int sr = tid >> 2, sc = (tid & 3)*16;
      const float* krow = qkv + (size_t)(mb + sr)*768 + 256 + h*64 + sc;
      float4 a = *(const float4*)(krow + 0);
      float4 b = *(const float4*)(krow + 4);
      float4 cc = *(const float4*)(krow + 8);
      float4 d = *(const float4*)(krow + 12);
      v8h h0 = {(_Float16)a.x, (_Float16)a.y, (_Float16)a.z, (_Float16)a.w,
                (_Float16)b.x, (_Float16)b.y, (_Float16)b.z, (_Float16)b.w};
      v8h h1 = {(_Float16)cc.x, (_Float16)cc.y, (_Float16)cc.z, (_Float16)cc.w,
                (_Float16)d.x, (_Float16)d.y, (_Float16)d.z, (_Float16)d.w};
      *(v8h*)(Ks + (size_t)sr*QKS + sc) = h0;
      *(v8h*)(Ks + (size_t)sr*QKS + sc + 8) = h1;
    }
    // cooperative V^T stage: thread = (m-pair, d-eighth); paired u32 writes
    {
      int m0 = (tid & 31)*2;
      int db = (tid >> 5)*8;
      const float* v0 = qkv + (size_t)(mb + m0)*768 + 512 + h*64 + db;
      const float* v1 = v0 + 768;
      #pragma unroll
      for (int i = 0; i < 2; i++){
        float4 a = *(const float4*)(v0 + 4*i);
        float4 b = *(const float4*)(v1 + 4*i);
        int d = db + 4*i;
        *(unsigned*)(VTs + (size_t)(d+0)*QKS + m0) = pk2(a.x, b.x);
        *(unsigned*)(VTs + (size_t)(d+1)*QKS + m0) = pk2(a.y, b.y);
        *(unsigned*)(VTs + (size_t)(d+2)*QKS + m0) = pk2(a.z, b.z);
        *(unsigned*)(VTs + (size_t)(d+3)*QKS + m0) = pk2(a.w, b.w);
      }
    }
    __syncthreads();
    // S^T = K.Q^T : c[mi][ni]; A-frag K rows, B-frag Q regs
    v4f c[4][4];
    #pragma unroll
    for (int i = 0; i < 4; i++)
      #pragma unroll
      for (int j = 0; j < 4; j++) c[i][j] = (v4f){0.f,0.f,0.f,0.f};
    #pragma unroll
    for (int kk = 0; kk < 2; kk++){
      v8h a[4];
      #pragma unroll
      for (int mi = 0; mi < 4; mi++) a[mi] = *(v8h*)(Ks + (size_t)(mi*16 + r16)*QKS + kk*32 + q*8);
      #pragma unroll
      for (int mi = 0; mi < 4; mi++)
        #pragma unroll
        for (int ni = 0; ni < 4; ni++)
          c[mi][ni] = __builtin_amdgcn_mfma_f32_16x16x32_f16(a[mi], qf[ni][kk], c[mi][ni], 0, 0, 0);
    }
    // exp + denominator + pack P[n][m] (lane's 4 vals m-consecutive)
    #pragma unroll
    for (int mi = 0; mi < 4; mi++)
      #pragma unroll
      for (int ni = 0; ni < 4; ni++){
        float e0 = __expf(c[mi][ni][0]), e1 = __expf(c[mi][ni][1]),
              e2 = __expf(c[mi][ni][2]), e3 = __expf(c[mi][ni][3]);
        dn[ni] += e0 + e1 + e2 + e3;
        *(uint2*)(Pw + (size_t)(ni*16 + r16)*QKS + mi*16 + q*4) = make_uint2(pk2(e0,e1), pk2(e2,e3));
      }
    // O += P.V : no barrier (Pw private to wave; VTs stable until next barrier)
    #pragma unroll
    for (int km = 0; km < 2; km++){
      v8h pa[4], vb[4];
      #pragma unroll
      for (int ni = 0; ni < 4; ni++) pa[ni] = *(v8h*)(Pw + (size_t)(ni*16 + r16)*QKS + km*32 + q*8);
      #pragma unroll
      for (int di = 0; di < 4; di++) vb[di] = *(v8h*)(VTs + (size_t)(di*16 + r16)*QKS + km*32 + q*8);
      #pragma unroll
      for (int ni = 0; ni < 4; ni++)
        #pragma unroll
        for (int di = 0; di < 4; di++)
          o[ni][di] = __builtin_amdgcn_mfma_f32_16x16x32_f16(pa[ni], vb[di], o[ni][di], 0, 0, 0);
    }
  }

  // write O: lane holds O[n=ni*16+q*4+r][d=di*16+r16]
  float* ob = opart + ((size_t)mc*NN + nb)*C + h*64;
  #pragma unroll
  for (int ni = 0; ni < 4; ni++)
    #pragma unroll
    for (int di = 0; di < 4; di++)
      #pragma unroll
      for (int r = 0; r < 4; r++)
        ob[(size_t)(ni*16 + q*4 + r)*C + di*16 + r16] = o[ni][di][r];
  // dn: quad-partial sums -> reduce across quads, quad 0 stores (no atomics)
  #pragma unroll
  for (int ni = 0; ni < 4; ni++){
    dn[ni] += __shfl_xor(dn[ni], 16);
    dn[ni] += __shfl_xor(dn[ni], 32);
  }
  if (q == 0){
    #pragma unroll
    for (int ni = 0; ni < 4; ni++)
      dpart[((size_t)mc*NN + nb + ni*16 + r16)*AHD + h] = dn[ni];
  }
}

// R13: 256 blocks (16 rows each) -- R12 post-mortem: 32-block launch left 87%
// of CUs idle (occupancy 1.3%, 213 GB/s on a 33.5MB read = 80us; roofline 5us)
__global__ __launch_bounds__(256) void attnred_k(const float* __restrict__ opart, const float* __restrict__ dpart,
                                                 float* omean){
  int r0 = blockIdx.x*(NN/256), c = threadIdx.x;
  int head = c >> 6;
  float s = 0.f;
  for (int r = 0; r < NN/256; r++){
    int n = r0 + r;
    float dsum = 0.f, osum = 0.f;
    #pragma unroll
    for (int mc = 0; mc < MCH; mc++){
      dsum += dpart[((size_t)mc*NN + n)*AHD + head];
      osum += opart[((size_t)mc*NN + n)*C + c];
    }
    s += osum / (dsum + 1e-16f);
  }
  atomicAdd(&omean[c], s*(1.f/4096.f));
}

__global__ __launch_bounds__(256) void attnproj_k(const float* __restrict__ omean, const float* __restrict__ opw,
                                                  const float* __restrict__ opb, float* attnp){
  __shared__ float sh[256];
  int j = threadIdx.x;
  sh[j] = omean[j];
  __syncthreads();
  float acc = opb[j];
  for (int k = 0; k < 256; k++) acc += sh[k]*opw[j*256 + k];
  attnp[j] = acc;
}

__global__ __launch_bounds__(512) void fus1_k(const float* __restrict__ meanp, const float* __restrict__ maxp,
                                              const float* __restrict__ attnp, const float* __restrict__ fw1,
                                              const float* __restrict__ fb1, float* g1){
  __shared__ float comb[768];
  for (int i = threadIdx.x; i < 768; i += 512)
    comb[i] = (i < 256) ? meanp[i] : (i < 512 ? maxp[i-256] : attnp[i-512]);
  __syncthreads();
  int j = threadIdx.x;
  float acc = fb1[j];
  for (int k = 0; k < 768; k++) acc += comb[k]*fw1[k*512 + j];
  g1[j] = fmaxf(acc, 0.f);
}

__global__ __launch_bounds__(256) void fus2_k(const float* __restrict__ g1, const float* __restrict__ fw2,
                                              const float* __restrict__ fb2, float* __restrict__ out){
  __shared__ float g[512];
  g[threadIdx.x] = g1[threadIdx.x];
  g[threadIdx.x + 256] = g1[threadIdx.x + 256];
  __syncthreads();
  int j = threadIdx.x;
  float acc = fb2[j];
  for (int k = 0; k < 512; k++) acc += g[k]*fw2[k*256 + j];
  out[j] = fmaxf(acc, 0.f);
}

extern "C" void kernel_launch(void* const* d_in, const int* in_sizes, int n_in,
                              void* d_out, int out_size, void* d_ws, size_t ws_size,
                              hipStream_t stream){
  const float* x     = (const float*)d_in[0];
  const int*   srcv  = (const int*)d_in[1];
  const int*   dstv  = (const int*)d_in[2];
  const float* eattr = (const float*)d_in[3];
  const int*   etyp  = (const int*)d_in[4];
  const float* W0    = (const float*)d_in[5];
  const float* W12   = (const float*)d_in[6];
  const float* attS  = (const float*)d_in[7];
  const float* attD  = (const float*)d_in[8];
  const float* attE  = (const float*)d_in[9];
  const float* linE  = (const float*)d_in[10];
  const float* bias  = (const float*)d_in[11];
  const float* etw   = (const float*)d_in[12];
  const float* ipw   = (const float*)d_in[13];
  const float* ipb   = (const float*)d_in[14];
  const float* opw   = (const float*)d_in[15];
  const float* opb   = (const float*)d_in[16];
  const float* fw1   = (const float*)d_in[17];
  const float* fb1   = (const float*)d_in[18];
  const float* fw2   = (const float*)d_in[19];
  const float* fb2   = (const float*)d_in[20];
  float* out = (float*)d_out;

  if (ws_size < (size_t)WS_WORDS*4) return;

  int*      ip   = (int*)d_ws;
  float*    fp   = (float*)d_ws;
  unsigned* wtp  = (unsigned*)(fp + F_WT);
  unsigned* w12p = (unsigned*)(fp + U_W12P);

  zero_k<<<(NN*T + 255)/256, 256, 0, stream>>>(fp + F_MEANP, NZERO, ip + W_CURSOR, NN*T);
  initmax_k<<<1, 256, 0, stream>>>(fp + F_MAXP);

  hist_k<<<EE/256, 256, 0, stream>>>(dstv, etyp, ip + W_CURSOR);
  scan_k<<<1, 1024, 0, stream>>>(ip + W_CURSOR, ip + W_OFF, ip + W_CURSOR);
  scatter_k<<<EE/256, 256, 0, stream>>>(dstv, etyp, ip + W_CURSOR, ip + W_SORTED);

  // weight packing prepass
  pack12_k<<<dim3(128, T*2), 256, 0, stream>>>(W12, w12p);
  packT_k<<<dim3(128, 3), 256, 0, stream>>>(ipw, wtp);

  // all-layer prepass: we, se, sloop
  we2_k<<<dim3(T, LL), 256, 0, stream>>>(linE, attE, fp + F_WE);
  se_k<<<dim3(EE/256, LL), 256, 0, stream>>>(eattr, etyp, fp + F_WE, fp + F_SE);
  sloop_k<<<dim3((NN*T)/256, LL), 256, 0, stream>>>(ip + W_OFF, ip + W_SORTED, fp + F_SE, fp + F_SLOOP);

  for (int l = 0; l < 3; l++){
    if (l == 0)
      gemm_k<<<dim3(NN/8, T), 256, 0, stream>>>(x, DIN, W0, (long)DIN*C, attS, attD, 0,
                                                fp + F_XL, fp + F_SSRC, fp + F_SDST);
    else
      gemm16_k<<<dim3(NN/8, T), 128, 0, stream>>>(fp + F_H, w12p, attS, attD, l,
                                                  fp + F_XL, fp + F_SSRC, fp + F_SDST);
    agg_k<<<dim3(NN, T), 256, 0, stream>>>(fp + F_XL, fp + F_SSRC, fp + F_SDST,
                                           fp + F_SE + (size_t)l*EE,
                                           fp + F_SLOOP + (size_t)l*(NN*T),
                                           ip + W_OFF, ip + W_SORTED, srcv,
                                           bias, fp + F_H, l);
  }

  hacc_k<<<NN, 256, 0, stream>>>(fp + F_H, etw, fp + F_HACC);
  colstats_k<<<32, 256, 0, stream>>>(fp + F_HACC, fp + F_MEANP, fp + F_MAXP);

  qkv16_k<<<dim3(NN/8, 3), 128, 0, stream>>>(fp + F_HACC, wtp, ipb, fp + F_QKV);
  attn_k<<<dim3(NN/256, AHD, MCH), 256, 0, stream>>>(fp + F_QKV, fp + F_OPART, fp + F_DPART);
  attnred_k<<<256, 256, 0, stream>>>(fp + F_OPART, fp + F_DPART, fp + F_OMEAN);
  attnproj_k<<<1, 256, 0, stream>>>(fp + F_OMEAN, opw, opb, fp + F_ATTNP);

  fus1_k<<<1, 512, 0, stream>>>(fp + F_MEANP, fp + F_MAXP, fp + F_ATTNP, fw1, fb1, fp + F_G1);
  fus2_k<<<1, 256, 0, stream>>>(fp + F_G1, fw2, fb2, out);
}

// Round 14
// 441.862 us; speedup vs baseline: 2.2811x; 1.1001x over previous
//
#include <hip/hip_runtime.h>
#include <math.h>

#define T 4
#define LL 3
#define C 256
#define DIN 20
#define NN 4096
#define EE 65536
#define AHD 4
#define MCH 8     // attention m-chunks (blockIdx.z); grid 16x4x8=512 blocks = 2/CU
#define QKS 72    // padded LDS row stride in halfs (64+8): +4 banks/row -> 2-way (free)

// ---- workspace layout (4-byte word offsets) ----
#define W_OFF    0                    // int[N*T+1]
#define W_CURSOR 16640                // int[N*T]  (also hist counts)
#define W_SORTED 33024                // int[E]
#define F_XL     98560                // float[T][N][C]
#define F_H      (F_XL + T*NN*C)      // float[T][N][C]
#define F_OPART  F_XL                 // alias: float[MCH][N][C] == exactly F_XL+F_H extent (dead at attn time)
#define F_SSRC   (F_H + T*NN*C)       // float[T][N]
#define F_SDST   (F_SSRC + T*NN)      // float[T][N]
#define F_SE     (F_SDST + T*NN)      // float[LL][E]
#define F_SLOOP  (F_SE + LL*EE)       // float[LL][N*T] indexed l*NT + n*T+t
#define F_WE     (F_SLOOP + LL*T*NN)  // float[T*LL][10] (padded 128)
#define F_HACC   (F_WE + 128)         // float[N][C]
#define F_WT     (F_HACC + NN*C)      // u32[128][768] packed f16-pair in_proj_w^T (region reserved 768*256)
#define F_QKV    (F_WT + 768*256)     // float[N][768]
#define F_DPART  (F_QKV + NN*768)     // float[MCH][N][AH]
#define F_MEANP  (F_DPART + MCH*NN*AHD) // float[C]
#define F_MAXP   (F_MEANP + C)        // float[C]
#define F_OMEAN  (F_MAXP + C)         // float[C]
#define F_ATTNP  (F_OMEAN + C)        // float[C]
#define F_G1     (F_ATTNP + C)        // float[512]
#define U_W12P   (F_G1 + 512)         // u32[T*2][128][256] packed f16-pair W12
#define WS_WORDS (U_W12P + 262144)
#define NZERO (3*C)                   // meanp, maxp, omean (opart/dpart fully direct-stored)

static __device__ __forceinline__ float lrelu(float x){ return x > 0.f ? x : 0.2f*x; }
static __device__ __forceinline__ float eluf(float x){ return x > 0.f ? x : __expf(x) - 1.f; }

typedef _Float16 half2_t __attribute__((ext_vector_type(2)));
typedef _Float16 v8h __attribute__((ext_vector_type(8)));
typedef float v4f __attribute__((ext_vector_type(4)));

static __device__ __forceinline__ unsigned pk2(float x, float y){
  half2_t h; h.x = (_Float16)x; h.y = (_Float16)y;
  return __builtin_bit_cast(unsigned, h);
}
#if __has_builtin(__builtin_amdgcn_fdot2)
static __device__ __forceinline__ float fdot2u(unsigned a, unsigned b, float c){
  return __builtin_amdgcn_fdot2(__builtin_bit_cast(half2_t, a), __builtin_bit_cast(half2_t, b), c, false);
}
#else
static __device__ __forceinline__ float fdot2u(unsigned a, unsigned b, float c){
  half2_t ha = __builtin_bit_cast(half2_t, a), hb = __builtin_bit_cast(half2_t, b);
  return c + (float)ha.x*(float)hb.x + (float)ha.y*(float)hb.y;
}
#endif

static __device__ inline void atomicMaxF(float* addr, float val){
  int* ai = (int*)addr;
  int old = __float_as_int(*addr);
  while (__int_as_float(old) < val){
    int assumed = old;
    old = atomicCAS(ai, assumed, __float_as_int(val));
    if (old == assumed) break;
  }
}

__global__ __launch_bounds__(256) void zero_k(float* fz, int nf, int* iz, int ni){
  int i = blockIdx.x*256 + threadIdx.x;
  if (i < nf) fz[i] = 0.f;
  if (i < ni) iz[i] = 0;
}
__global__ __launch_bounds__(256) void initmax_k(float* maxp){ maxp[threadIdx.x] = -1e30f; }

__global__ __launch_bounds__(256) void hist_k(const int* __restrict__ dst, const int* __restrict__ ety, int* cnt){
  int e = blockIdx.x*256 + threadIdx.x;
  if (e < EE) atomicAdd(&cnt[dst[e]*T + ety[e]], 1);
}

__global__ __launch_bounds__(1024) void scan_k(int* cnt, int* off, int* cursor){
  __shared__ int part[1024];
  int tid = threadIdx.x;
  int base = tid*16;
  int loc[16]; int s = 0;
  for (int i = 0; i < 16; i++){ loc[i] = cnt[base+i]; s += loc[i]; }
  part[tid] = s; __syncthreads();
  int v = s;
  for (int offn = 1; offn < 1024; offn <<= 1){
    int add = (tid >= offn) ? part[tid-offn] : 0;
    __syncthreads();
    v += add; part[tid] = v;
    __syncthreads();
  }
  int excl = v - s;
  for (int i = 0; i < 16; i++){ off[base+i] = excl; cursor[base+i] = excl; excl += loc[i]; }
  if (tid == 1023) off[NN*T] = excl;
}

__global__ __launch_bounds__(256) void scatter_k(const int* __restrict__ dst, const int* __restrict__ ety,
                                                 int* cursor, int* sorted){
  int e = blockIdx.x*256 + threadIdx.x;
  if (e < EE){
    int p = atomicAdd(&cursor[dst[e]*T + ety[e]], 1);
    sorted[p] = e;
  }
}

// pack W12 [t][i][256][256] -> f16-pair u32 [t*2+i][128][256]
__global__ __launch_bounds__(256) void pack12_k(const float* __restrict__ w, unsigned* __restrict__ wp){
  int b = blockIdx.y, k2 = blockIdx.x, c = threadIdx.x;
  const float* s = w + (size_t)b*C*C;
  wp[((size_t)b*128 + k2)*C + c] = pk2(s[(2*k2)*C + c], s[(2*k2+1)*C + c]);
}

// pack in_proj_w [768][256] -> transposed f16-pair u32 [128][768]
__global__ __launch_bounds__(256) void packT_k(const float* __restrict__ ipw, unsigned* __restrict__ wtp){
  int k2 = blockIdx.x, j = blockIdx.y*256 + threadIdx.x;
  wtp[k2*768 + j] = pk2(ipw[(size_t)j*C + 2*k2], ipw[(size_t)j*C + 2*k2 + 1]);
}

// we[t][l][k] = sum_c lin_edge_w[t,l,k,c] * att_edge[t,l,0,c]  -- all (t,l) in one launch
__global__ __launch_bounds__(256) void we2_k(const float* __restrict__ linE, const float* __restrict__ attE,
                                             float* we){
  int t = blockIdx.x, l = blockIdx.y, c = threadIdx.x;
  __shared__ float part[10*C];
  float ae = attE[(t*LL + l)*C + c];
  const float* lw = linE + (size_t)((t*LL + l)*10)*C;
  for (int k = 0; k < 10; k++) part[k*C + c] = lw[k*C + c]*ae;
  __syncthreads();
  if (c < 10){
    float s = 0.f;
    for (int i = 0; i < C; i++) s += part[c*C + i];
    we[(t*LL + l)*10 + c] = s;
  }
}

// layer 0 only (K=20, cheap): fp32 path, fused ssd reduction
__global__ __launch_bounds__(256) void gemm_k(const float* __restrict__ hin, int K,
                                              const float* __restrict__ Wb, long wtstr,
                                              const float* __restrict__ attS, const float* __restrict__ attD,
                                              int l, float* __restrict__ xlo,
                                              float* __restrict__ ssrc, float* __restrict__ sdst){
  int t = blockIdx.y;
  const float* h = hin;
  const float* W = Wb + (size_t)t*wtstr;
  int n0 = blockIdx.x*8;
  __shared__ float sh[8*256];
  __shared__ float red[64];
  for (int j = 0; j < 8; j++)
    for (int k = threadIdx.x; k < K; k += 256)
      sh[j*K + k] = h[(n0+j)*K + k];
  __syncthreads();
  float acc[8] = {0,0,0,0,0,0,0,0};
  int c = threadIdx.x;
  for (int k = 0; k < K; k += 4){
    float w0 = W[(k+0)*C + c], w1 = W[(k+1)*C + c], w2 = W[(k+2)*C + c], w3 = W[(k+3)*C + c];
    #pragma unroll
    for (int j = 0; j < 8; j++){
      float4 h4 = *(const float4*)&sh[j*K + k];
      acc[j] += w0*h4.x + w1*h4.y + w2*h4.z + w3*h4.w;
    }
  }
  #pragma unroll
  for (int j = 0; j < 8; j++) xlo[(t*NN + n0 + j)*C + c] = acc[j];
  float aS = attS[(t*LL + l)*C + c], aD = attD[(t*LL + l)*C + c];
  int lane = c & 63, w = c >> 6;
  #pragma unroll
  for (int j = 0; j < 8; j++){
    float v1 = acc[j]*aS, v2 = acc[j]*aD;
    #pragma unroll
    for (int off = 32; off > 0; off >>= 1){ v1 += __shfl_down(v1, off); v2 += __shfl_down(v2, off); }
    if (lane == 0){ red[j*8 + w] = v1; red[j*8 + 4 + w] = v2; }
  }
  __syncthreads();
  if (c < 16){
    int j = c >> 1, which = c & 1;
    const float* r = red + j*8 + which*4;
    float s = r[0] + r[1] + r[2] + r[3];
    (which ? sdst : ssrc)[t*NN + n0 + j] = s;
  }
}

// layers 1,2 (K=256) as f16-pair dot2 GEMM (R10)
__global__ __launch_bounds__(128) void gemm16_k(const float* __restrict__ hin,
                                                const unsigned* __restrict__ w12p,
                                                const float* __restrict__ attS, const float* __restrict__ attD,
                                                int l, float* __restrict__ xlo,
                                                float* __restrict__ ssrc, float* __restrict__ sdst){
  int t = blockIdx.y;
  const float* h = hin + (size_t)t*NN*C;
  const unsigned* W = w12p + ((size_t)(t*2 + (l-1)))*128*C;
  int n0 = blockIdx.x*8;
  int tid = threadIdx.x;
  __shared__ unsigned sh[8*128];
  __shared__ float red[32];
  #pragma unroll
  for (int j = 0; j < 8; j++){
    float2 hv = *(const float2*)&h[(size_t)(n0+j)*C + 2*tid];
    sh[j*128 + tid] = pk2(hv.x, hv.y);
  }
  __syncthreads();
  float a0[8] = {0,0,0,0,0,0,0,0};
  float a1[8] = {0,0,0,0,0,0,0,0};
  int c0 = tid, c1 = tid + 128;
  for (int k2 = 0; k2 < 128; k2 += 4){
    unsigned w00 = W[(k2+0)*C + c0], w01 = W[(k2+1)*C + c0],
             w02 = W[(k2+2)*C + c0], w03 = W[(k2+3)*C + c0];
    unsigned w10 = W[(k2+0)*C + c1], w11 = W[(k2+1)*C + c1],
             w12 = W[(k2+2)*C + c1], w13 = W[(k2+3)*C + c1];
    #pragma unroll
    for (int j = 0; j < 8; j++){
      uint4 hp = *(uint4*)&sh[j*128 + k2];
      a0[j] = fdot2u(hp.x, w00, a0[j]); a0[j] = fdot2u(hp.y, w01, a0[j]);
      a0[j] = fdot2u(hp.z, w02, a0[j]); a0[j] = fdot2u(hp.w, w03, a0[j]);
      a1[j] = fdot2u(hp.x, w10, a1[j]); a1[j] = fdot2u(hp.y, w11, a1[j]);
      a1[j] = fdot2u(hp.z, w12, a1[j]); a1[j] = fdot2u(hp.w, w13, a1[j]);
    }
  }
  #pragma unroll
  for (int j = 0; j < 8; j++){
    xlo[(t*NN + n0 + j)*C + c0] = a0[j];
    xlo[(t*NN + n0 + j)*C + c1] = a1[j];
  }
  float aS0 = attS[(t*LL + l)*C + c0], aS1 = attS[(t*LL + l)*C + c1];
  float aD0 = attD[(t*LL + l)*C + c0], aD1 = attD[(t*LL + l)*C + c1];
  int lane = tid & 63, w = tid >> 6;
  #pragma unroll
  for (int j = 0; j < 8; j++){
    float v1 = a0[j]*aS0 + a1[j]*aS1;
    float v2 = a0[j]*aD0 + a1[j]*aD1;
    #pragma unroll
    for (int off = 32; off > 0; off >>= 1){ v1 += __shfl_down(v1, off); v2 += __shfl_down(v2, off); }
    if (lane == 0){ red[j*4 + w*2 + 0] = v1; red[j*4 + w*2 + 1] = v2; }
  }
  __syncthreads();
  if (tid < 16){
    int j = tid >> 1, which = tid & 1;
    float s = red[j*4 + which] + red[j*4 + 2 + which];
    (which ? sdst : ssrc)[t*NN + n0 + j] = s;
  }
}

// all layers at once: se[l][e]
__global__ __launch_bounds__(256) void se_k(const float* __restrict__ eattr, const int* __restrict__ ety,
                                            const float* __restrict__ we, float* se){
  int e = blockIdx.x*256 + threadIdx.x;
  int l = blockIdx.y;
  if (e < EE){
    const float* w = we + (ety[e]*LL + l)*10;
    const float* ea = eattr + e*10;
    float s = 0.f;
    #pragma unroll
    for (int k = 0; k < 10; k++) s += ea[k]*w[k];
    se[(size_t)l*EE + e] = s;
  }
}

// all layers at once: sloop[l][i]
__global__ __launch_bounds__(256) void sloop_k(const int* __restrict__ off, const int* __restrict__ sorted,
                                               const float* __restrict__ se, float* sloop){
  int i = blockIdx.x*256 + threadIdx.x;
  int l = blockIdx.y;
  if (i < NN*T){
    int o0 = off[i], o1 = off[i+1];
    const float* sel = se + (size_t)l*EE;
    float s = 0.f;
    for (int j = o0; j < o1; j++) s += sel[sorted[j]];
    int dg = o1 - o0;
    sloop[(size_t)l*(NN*T) + i] = s / (float)(dg > 0 ? dg : 1);
  }
}

// R14: wave-per-(n,t) aggregation. 4 waves/block, zero barriers (R13 structure
// had 2 syncthreads + serial thread0 softmax with 255 threads idle, 16384 tiny
// blocks). deg <= 64 (Poisson(4): P(deg>64) ~ e^-60). Softmax via 64-lane
// shuffle reduce; neighbor weights broadcast with __shfl; c-dim = 64 lanes x f4.
__global__ __launch_bounds__(256) void agg_k(const float* __restrict__ xl, const float* __restrict__ ssrc,
                                             const float* __restrict__ sdst, const float* __restrict__ se,
                                             const float* __restrict__ sloop, const int* __restrict__ off,
                                             const int* __restrict__ sorted, const int* __restrict__ srcv,
                                             const float* __restrict__ bias, float* __restrict__ hout, int l){
  int gid = blockIdx.x*4 + (threadIdx.x >> 6);   // over N*T, == n*T+t
  int lane = threadIdx.x & 63;
  int n = gid >> 2, t = gid & 3;                 // T==4
  int o0 = off[gid];
  int deg = off[gid+1] - o0;
  if (deg > 64) deg = 64;
  float sd = sdst[t*NN + n];
  float sc = -1e30f; int sj = 0;
  if (lane < deg){
    int e = sorted[o0 + lane];
    sj = srcv[e];
    sc = lrelu(ssrc[t*NN + sj] + sd + se[e]);
  }
  float al = lrelu(ssrc[t*NN + n] + sd + sloop[gid]);
  // wave max (includes al)
  float mx = fmaxf(sc, al);
  #pragma unroll
  for (int o = 32; o > 0; o >>= 1) mx = fmaxf(mx, __shfl_xor(mx, o));
  float ex = (lane < deg) ? __expf(sc - mx) : 0.f;
  float ale = __expf(al - mx);
  float ssum = ex;
  #pragma unroll
  for (int o = 32; o > 0; o >>= 1) ssum += __shfl_xor(ssum, o);
  float inv = 1.f/(ssum + ale + 1e-16f);
  // c-loop: lane owns float4 at c = lane*4
  const float4* xl4 = (const float4*)xl;
  float4 acc = xl4[((size_t)(t*NN + n))*64 + lane];
  acc.x *= ale; acc.y *= ale; acc.z *= ale; acc.w *= ale;
  for (int j = 0; j < deg; j++){
    float p = __shfl(ex, j);
    int s = __shfl(sj, j);
    float4 v = xl4[((size_t)(t*NN + s))*64 + lane];
    acc.x += p*v.x; acc.y += p*v.y; acc.z += p*v.z; acc.w += p*v.w;
  }
  float4 b4 = *(const float4*)&bias[(t*LL + l)*C + lane*4];
  acc.x = eluf(acc.x*inv + b4.x); acc.y = eluf(acc.y*inv + b4.y);
  acc.z = eluf(acc.z*inv + b4.z); acc.w = eluf(acc.w*inv + b4.w);
  ((float4*)hout)[((size_t)(t*NN + n))*64 + lane] = acc;
}

__global__ __launch_bounds__(256) void hacc_k(const float* __restrict__ h, const float* __restrict__ etw,
                                              float* __restrict__ hacc){
  int n = blockIdx.x, c = threadIdx.x;
  float e0 = etw[0], e1 = etw[1], e2 = etw[2], e3 = etw[3];
  float m = fmaxf(fmaxf(e0,e1), fmaxf(e2,e3));
  float w0 = __expf(e0-m), w1 = __expf(e1-m), w2 = __expf(e2-m), w3 = __expf(e3-m);
  float inv = 1.f/(w0+w1+w2+w3);
  float s = w0*h[(0*NN+n)*C+c] + w1*h[(1*NN+n)*C+c] + w2*h[(2*NN+n)*C+c] + w3*h[(3*NN+n)*C+c];
  hacc[n*C + c] = s*inv;
}

// R14: 256 blocks (16 rows each) -- same under-parallelization fix as attnred
__global__ __launch_bounds__(256) void colstats_k(const float* __restrict__ hacc, float* meanp, float* maxp){
  int r0 = blockIdx.x*(NN/256), c = threadIdx.x;
  float sm = 0.f, mx = -1e30f;
  for (int r = 0; r < NN/256; r++){
    float v = hacc[(r0+r)*C + c];
    sm += v; mx = fmaxf(mx, v);
  }
  atomicAdd(&meanp[c], sm*(1.f/4096.f));
  atomicMaxF(&maxp[c], mx);
}

// qkv as f16-pair dot2 GEMM (R10), packed WT
__global__ __launch_bounds__(128) void qkv16_k(const float* __restrict__ hacc,
                                               const unsigned* __restrict__ wtp,
                                               const float* __restrict__ ipb, float* __restrict__ qkv){
  int p = blockIdx.y;
  int n0 = blockIdx.x*8;
  int tid = threadIdx.x;
  __shared__ unsigned sh[8*128];
  #pragma unroll
  for (int j = 0; j < 8; j++){
    float2 hv = *(const float2*)&hacc[(size_t)(n0+j)*C + 2*tid];
    sh[j*128 + tid] = pk2(hv.x, hv.y);
  }
  __syncthreads();
  float a0[8] = {0,0,0,0,0,0,0,0};
  float a1[8] = {0,0,0,0,0,0,0,0};
  int c0 = p*256 + tid, c1 = c0 + 128;
  for (int k2 = 0; k2 < 128; k2 += 4){
    unsigned w00 = wtp[(k2+0)*768 + c0], w01 = wtp[(k2+1)*768 + c0],
             w02 = wtp[(k2+2)*768 + c0], w03 = wtp[(k2+3)*768 + c0];
    unsigned w10 = wtp[(k2+0)*768 + c1], w11 = wtp[(k2+1)*768 + c1],
             w12 = wtp[(k2+2)*768 + c1], w13 = wtp[(k2+3)*768 + c1];
    #pragma unroll
    for (int j = 0; j < 8; j++){
      uint4 hp = *(uint4*)&sh[j*128 + k2];
      a0[j] = fdot2u(hp.x, w00, a0[j]); a0[j] = fdot2u(hp.y, w01, a0[j]);
      a0[j] = fdot2u(hp.z, w02, a0[j]); a0[j] = fdot2u(hp.w, w03, a0[j]);
      a1[j] = fdot2u(hp.x, w10, a1[j]); a1[j] = fdot2u(hp.y, w11, a1[j]);
      a1[j] = fdot2u(hp.z, w12, a1[j]); a1[j] = fdot2u(hp.w, w13, a1[j]);
    }
  }
  float b0 = ipb[c0], b1 = ipb[c1];
  #pragma unroll
  for (int j = 0; j < 8; j++){
    qkv[(size_t)(n0+j)*768 + c0] = a0[j] + b0;
    qkv[(size_t)(n0+j)*768 + c1] = a1[j] + b1;
  }
}

// R12: multi-wave MFMA flash attention (4 waves/block, coop K/V^T stage,
// Q in registers, per-wave P buffer; 2 blocks/CU)
__global__ __launch_bounds__(256, 2) void attn_k(const float* __restrict__ qkv,
                                                 float* __restrict__ opart,
                                                 float* __restrict__ dpart){
  __shared__ __align__(16) _Float16 Ks[64*QKS];    // [m][k]
  __shared__ __align__(16) _Float16 VTs[64*QKS];   // [d][m]
  __shared__ __align__(16) _Float16 Ps[4][64*QKS]; // per-wave [n][m]
  int tid = threadIdx.x;
  int wave = tid >> 6, l = tid & 63;
  int nb = blockIdx.x*256 + wave*64;
  int h = blockIdx.y, mc = blockIdx.z;
  int r16 = l & 15, q = l >> 4;
  _Float16* Pw = Ps[wave];

  // Q fragments (B operand) in registers, prescaled by 1/8
  v8h qf[4][2];
  #pragma unroll
  for (int ni = 0; ni < 4; ni++){
    const float* qrow = qkv + (size_t)(nb + ni*16 + r16)*768 + h*64;
    #pragma unroll
    for (int kk = 0; kk < 2; kk++){
      float4 a = *(const float4*)(qrow + kk*32 + q*8);
      float4 b = *(const float4*)(qrow + kk*32 + q*8 + 4);
      v8h hv = {(_Float16)(a.x*0.125f), (_Float16)(a.y*0.125f),
                (_Float16)(a.z*0.125f), (_Float16)(a.w*0.125f),
                (_Float16)(b.x*0.125f), (_Float16)(b.y*0.125f),
                (_Float16)(b.z*0.125f), (_Float16)(b.w*0.125f)};
      qf[ni][kk] = hv;
    }
  }

  v4f o[4][4];
  #pragma unroll
  for (int i = 0; i < 4; i++)
    #pragma unroll
    for (int j = 0; j < 4; j++) o[i][j] = (v4f){0.f,0.f,0.f,0.f};
  float dn[4] = {0.f,0.f,0.f,0.f};

  for (int mt = 0; mt < NN/MCH/64; mt++){
    int mb = mc*(NN/MCH) + mt*64;
    __syncthreads();                    // all waves done reading prev Ks/VTs
    // cooperative K stage: thread = (row, 16-half quarter)
    {
      int sr = tid >> 2, sc = (tid & 3)*16;
      const float* krow = qkv + (size_t)(mb + sr)*768 + 256 + h*64 + sc;
      float4 a = *(const float4*)(krow + 0);
      float4 b = *(const float4*)(krow + 4);
      float4 cc = *(const float4*)(krow + 8);
      float4 d = *(const float4*)(krow + 12);
      v8h h0 = {(_Float16)a.x, (_Float16)a.y, (_Float16)a.z, (_Float16)a.w,
                (_Float16)b.x, (_Float16)b.y, (_Float16)b.z, (_Float16)b.w};
      v8h h1 = {(_Float16)cc.x, (_Float16)cc.y, (_Float16)cc.z, (_Float16)cc.w,
                (_Float16)d.x, (_Float16)d.y, (_Float16)d.z, (_Float16)d.w};
      *(v8h*)(Ks + (size_t)sr*QKS + sc) = h0;
      *(v8h*)(Ks + (size_t)sr*QKS + sc + 8) = h1;
    }
    // cooperative V^T stage: thread = (m-pair, d-eighth); paired u32 writes
    {
      int m0 = (tid & 31)*2;
      int db = (tid >> 5)*8;
      const float* v0 = qkv + (size_t)(mb + m0)*768 + 512 + h*64 + db;
      const float* v1 = v0 + 768;
      #pragma unroll
      for (int i = 0; i < 2; i++){
        float4 a = *(const float4*)(v0 + 4*i);
        float4 b = *(const float4*)(v1 + 4*i);
        int d = db + 4*i;
        *(unsigned*)(VTs + (size_t)(d+0)*QKS + m0) = pk2(a.x, b.x);
        *(unsigned*)(VTs + (size_t)(d+1)*QKS + m0) = pk2(a.y, b.y);
        *(unsigned*)(VTs + (size_t)(d+2)*QKS + m0) = pk2(a.z, b.z);
        *(unsigned*)(VTs + (size_t)(d+3)*QKS + m0) = pk2(a.w, b.w);
      }
    }
    __syncthreads();
    // S^T = K.Q^T : c[mi][ni]; A-frag K rows, B-frag Q regs
    v4f c[4][4];
    #pragma unroll
    for (int i = 0; i < 4; i++)
      #pragma unroll
      for (int j = 0; j < 4; j++) c[i][j] = (v4f){0.f,0.f,0.f,0.f};
    #pragma unroll
    for (int kk = 0; kk < 2; kk++){
      v8h a[4];
      #pragma unroll
      for (int mi = 0; mi < 4; mi++) a[mi] = *(v8h*)(Ks + (size_t)(mi*16 + r16)*QKS + kk*32 + q*8);
      #pragma unroll
      for (int mi = 0; mi < 4; mi++)
        #pragma unroll
        for (int ni = 0; ni < 4; ni++)
          c[mi][ni] = __builtin_amdgcn_mfma_f32_16x16x32_f16(a[mi], qf[ni][kk], c[mi][ni], 0, 0, 0);
    }
    // exp + denominator + pack P[n][m] (lane's 4 vals m-consecutive)
    #pragma unroll
    for (int mi = 0; mi < 4; mi++)
      #pragma unroll
      for (int ni = 0; ni < 4; ni++){
        float e0 = __expf(c[mi][ni][0]), e1 = __expf(c[mi][ni][1]),
              e2 = __expf(c[mi][ni][2]), e3 = __expf(c[mi][ni][3]);
        dn[ni] += e0 + e1 + e2 + e3;
        *(uint2*)(Pw + (size_t)(ni*16 + r16)*QKS + mi*16 + q*4) = make_uint2(pk2(e0,e1), pk2(e2,e3));
      }
    // O += P.V : no barrier (Pw private to wave; VTs stable until next barrier)
    #pragma unroll
    for (int km = 0; km < 2; km++){
      v8h pa[4], vb[4];
      #pragma unroll
      for (int ni = 0; ni < 4; ni++) pa[ni] = *(v8h*)(Pw + (size_t)(ni*16 + r16)*QKS + km*32 + q*8);
      #pragma unroll
      for (int di = 0; di < 4; di++) vb[di] = *(v8h*)(VTs + (size_t)(di*16 + r16)*QKS + km*32 + q*8);
      #pragma unroll
      for (int ni = 0; ni < 4; ni++)
        #pragma unroll
        for (int di = 0; di < 4; di++)
          o[ni][di] = __builtin_amdgcn_mfma_f32_16x16x32_f16(pa[ni], vb[di], o[ni][di], 0, 0, 0);
    }
  }

  // write O: lane holds O[n=ni*16+q*4+r][d=di*16+r16]
  float* ob = opart + ((size_t)mc*NN + nb)*C + h*64;
  #pragma unroll
  for (int ni = 0; ni < 4; ni++)
    #pragma unroll
    for (int di = 0; di < 4; di++)
      #pragma unroll
      for (int r = 0; r < 4; r++)
        ob[(size_t)(ni*16 + q*4 + r)*C + di*16 + r16] = o[ni][di][r];
  // dn: quad-partial sums -> reduce across quads, quad 0 stores (no atomics)
  #pragma unroll
  for (int ni = 0; ni < 4; ni++){
    dn[ni] += __shfl_xor(dn[ni], 16);
    dn[ni] += __shfl_xor(dn[ni], 32);
  }
  if (q == 0){
    #pragma unroll
    for (int ni = 0; ni < 4; ni++)
      dpart[((size_t)mc*NN + nb + ni*16 + r16)*AHD + h] = dn[ni];
  }
}

// 256 blocks (16 rows each)
__global__ __launch_bounds__(256) void attnred_k(const float* __restrict__ opart, const float* __restrict__ dpart,
                                                 float* omean){
  int r0 = blockIdx.x*(NN/256), c = threadIdx.x;
  int head = c >> 6;
  float s = 0.f;
  for (int r = 0; r < NN/256; r++){
    int n = r0 + r;
    float dsum = 0.f, osum = 0.f;
    #pragma unroll
    for (int mc = 0; mc < MCH; mc++){
      dsum += dpart[((size_t)mc*NN + n)*AHD + head];
      osum += opart[((size_t)mc*NN + n)*C + c];
    }
    s += osum / (dsum + 1e-16f);
  }
  atomicAdd(&omean[c], s*(1.f/4096.f));
}

__global__ __launch_bounds__(256) void attnproj_k(const float* __restrict__ omean, const float* __restrict__ opw,
                                                  const float* __restrict__ opb, float* attnp){
  __shared__ float sh[256];
  int j = threadIdx.x;
  sh[j] = omean[j];
  __syncthreads();
  float acc = opb[j];
  for (int k = 0; k < 256; k++) acc += sh[k]*opw[j*256 + k];
  attnp[j] = acc;
}

__global__ __launch_bounds__(512) void fus1_k(const float* __restrict__ meanp, const float* __restrict__ maxp,
                                              const float* __restrict__ attnp, const float* __restrict__ fw1,
                                              const float* __restrict__ fb1, float* g1){
  __shared__ float comb[768];
  for (int i = threadIdx.x; i < 768; i += 512)
    comb[i] = (i < 256) ? meanp[i] : (i < 512 ? maxp[i-256] : attnp[i-512]);
  __syncthreads();
  int j = threadIdx.x;
  float acc = fb1[j];
  for (int k = 0; k < 768; k++) acc += comb[k]*fw1[k*512 + j];
  g1[j] = fmaxf(acc, 0.f);
}

__global__ __launch_bounds__(256) void fus2_k(const float* __restrict__ g1, const float* __restrict__ fw2,
                                              const float* __restrict__ fb2, float* __restrict__ out){
  __shared__ float g[512];
  g[threadIdx.x] = g1[threadIdx.x];
  g[threadIdx.x + 256] = g1[threadIdx.x + 256];
  __syncthreads();
  int j = threadIdx.x;
  float acc = fb2[j];
  for (int k = 0; k < 512; k++) acc += g[k]*fw2[k*256 + j];
  out[j] = fmaxf(acc, 0.f);
}

extern "C" void kernel_launch(void* const* d_in, const int* in_sizes, int n_in,
                              void* d_out, int out_size, void* d_ws, size_t ws_size,
                              hipStream_t stream){
  const float* x     = (const float*)d_in[0];
  const int*   srcv  = (const int*)d_in[1];
  const int*   dstv  = (const int*)d_in[2];
  const float* eattr = (const float*)d_in[3];
  const int*   etyp  = (const int*)d_in[4];
  const float* W0    = (const float*)d_in[5];
  const float* W12   = (const float*)d_in[6];
  const float* attS  = (const float*)d_in[7];
  const float* attD  = (const float*)d_in[8];
  const float* attE  = (const float*)d_in[9];
  const float* linE  = (const float*)d_in[10];
  const float* bias  = (const float*)d_in[11];
  const float* etw   = (const float*)d_in[12];
  const float* ipw   = (const float*)d_in[13];
  const float* ipb   = (const float*)d_in[14];
  const float* opw   = (const float*)d_in[15];
  const float* opb   = (const float*)d_in[16];
  const float* fw1   = (const float*)d_in[17];
  const float* fb1   = (const float*)d_in[18];
  const float* fw2   = (const float*)d_in[19];
  const float* fb2   = (const float*)d_in[20];
  float* out = (float*)d_out;

  if (ws_size < (size_t)WS_WORDS*4) return;

  int*      ip   = (int*)d_ws;
  float*    fp   = (float*)d_ws;
  unsigned* wtp  = (unsigned*)(fp + F_WT);
  unsigned* w12p = (unsigned*)(fp + U_W12P);

  zero_k<<<(NN*T + 255)/256, 256, 0, stream>>>(fp + F_MEANP, NZERO, ip + W_CURSOR, NN*T);
  initmax_k<<<1, 256, 0, stream>>>(fp + F_MAXP);

  hist_k<<<EE/256, 256, 0, stream>>>(dstv, etyp, ip + W_CURSOR);
  scan_k<<<1, 1024, 0, stream>>>(ip + W_CURSOR, ip + W_OFF, ip + W_CURSOR);
  scatter_k<<<EE/256, 256, 0, stream>>>(dstv, etyp, ip + W_CURSOR, ip + W_SORTED);

  // weight packing prepass
  pack12_k<<<dim3(128, T*2), 256, 0, stream>>>(W12, w12p);
  packT_k<<<dim3(128, 3), 256, 0, stream>>>(ipw, wtp);

  // all-layer prepass: we, se, sloop
  we2_k<<<dim3(T, LL), 256, 0, stream>>>(linE, attE, fp + F_WE);
  se_k<<<dim3(EE/256, LL), 256, 0, stream>>>(eattr, etyp, fp + F_WE, fp + F_SE);
  sloop_k<<<dim3((NN*T)/256, LL), 256, 0, stream>>>(ip + W_OFF, ip + W_SORTED, fp + F_SE, fp + F_SLOOP);

  for (int l = 0; l < 3; l++){
    if (l == 0)
      gemm_k<<<dim3(NN/8, T), 256, 0, stream>>>(x, DIN, W0, (long)DIN*C, attS, attD, 0,
                                                fp + F_XL, fp + F_SSRC, fp + F_SDST);
    else
      gemm16_k<<<dim3(NN/8, T), 128, 0, stream>>>(fp + F_H, w12p, attS, attD, l,
                                                  fp + F_XL, fp + F_SSRC, fp + F_SDST);
    agg_k<<<(NN*T)/4, 256, 0, stream>>>(fp + F_XL, fp + F_SSRC, fp + F_SDST,
                                        fp + F_SE + (size_t)l*EE,
                                        fp + F_SLOOP + (size_t)l*(NN*T),
                                        ip + W_OFF, ip + W_SORTED, srcv,
                                        bias, fp + F_H, l);
  }

  hacc_k<<<NN, 256, 0, stream>>>(fp + F_H, etw, fp + F_HACC);
  colstats_k<<<256, 256, 0, stream>>>(fp + F_HACC, fp + F_MEANP, fp + F_MAXP);

  qkv16_k<<<dim3(NN/8, 3), 128, 0, stream>>>(fp + F_HACC, wtp, ipb, fp + F_QKV);
  attn_k<<<dim3(NN/256, AHD, MCH), 256, 0, stream>>>(fp + F_QKV, fp + F_OPART, fp + F_DPART);
  attnred_k<<<256, 256, 0, stream>>>(fp + F_OPART, fp + F_DPART, fp + F_OMEAN);
  attnproj_k<<<1, 256, 0, stream>>>(fp + F_OMEAN, opw, opb, fp + F_ATTNP);

  fus1_k<<<1, 512, 0, stream>>>(fp + F_MEANP, fp + F_MAXP, fp + F_ATTNP, fw1, fb1, fp + F_G1);
  fus2_k<<<1, 256, 0, stream>>>(fp + F_G1, fw2, fb2, out);
}

// Round 15
// 390.285 us; speedup vs baseline: 2.5826x; 1.1322x over previous
//
#include <hip/hip_runtime.h>
#include <math.h>

#define T 4
#define LL 3
#define C 256
#define DIN 20
#define NN 4096
#define EE 65536
#define AHD 4
#define MCH 8     // attention m-chunks (blockIdx.z); grid 16x4x8=512 blocks = 2/CU
#define QKS 72    // padded LDS row stride in halfs (64+8): +4 banks/row -> 2-way (free)
#define AST 264   // GEMM A-tile LDS row stride in halfs (256+8): 2-way (free)

// ---- workspace layout (4-byte word offsets) ----
#define W_OFF    0                    // int[N*T+1]
#define W_CURSOR 16640                // int[N*T]  (also hist counts)
#define W_SORTED 33024                // int[E]
#define F_XL     98560                // float[T][N][C]
#define F_H      (F_XL + T*NN*C)      // float[T][N][C]
#define F_OPART  F_XL                 // alias: float[MCH][N][C] == exactly F_XL+F_H extent (dead at attn time)
#define F_SSRC   (F_H + T*NN*C)       // float[T][N]
#define F_SDST   (F_SSRC + T*NN)      // float[T][N]
#define F_SE     (F_SDST + T*NN)      // float[LL][E]
#define F_SLOOP  (F_SE + LL*EE)       // float[LL][N*T] indexed l*NT + n*T+t
#define F_WE     (F_SLOOP + LL*T*NN)  // float[T*LL][10] (padded 128)
#define F_HACC   (F_WE + 128)         // float[N][C]
#define F_WT     (F_HACC + NN*C)      // f16[768][256] in_proj_w (region reserved 768*256 words)
#define F_QKV    (F_WT + 768*256)     // float[N][768]
#define F_DPART  (F_QKV + NN*768)     // float[MCH][N][AH]
#define F_MEANP  (F_DPART + MCH*NN*AHD) // float[C]
#define F_MAXP   (F_MEANP + C)        // float[C]
#define F_OMEAN  (F_MAXP + C)         // float[C]
#define F_ATTNP  (F_OMEAN + C)        // float[C]
#define F_G1     (F_ATTNP + C)        // float[512]
#define U_W12P   (F_G1 + 512)         // f16[T*2][256 n][256 k] transposed W12
#define WS_WORDS (U_W12P + 262144)
#define NZERO (3*C)                   // meanp, maxp, omean

static __device__ __forceinline__ float lrelu(float x){ return x > 0.f ? x : 0.2f*x; }
static __device__ __forceinline__ float eluf(float x){ return x > 0.f ? x : __expf(x) - 1.f; }

typedef _Float16 half2_t __attribute__((ext_vector_type(2)));
typedef _Float16 v8h __attribute__((ext_vector_type(8)));
typedef float v4f __attribute__((ext_vector_type(4)));

static __device__ __forceinline__ unsigned pk2(float x, float y){
  half2_t h; h.x = (_Float16)x; h.y = (_Float16)y;
  return __builtin_bit_cast(unsigned, h);
}

static __device__ inline void atomicMaxF(float* addr, float val){
  int* ai = (int*)addr;
  int old = __float_as_int(*addr);
  while (__int_as_float(old) < val){
    int assumed = old;
    old = atomicCAS(ai, assumed, __float_as_int(val));
    if (old == assumed) break;
  }
}

__global__ __launch_bounds__(256) void zero_k(float* fz, int nf, int* iz, int ni){
  int i = blockIdx.x*256 + threadIdx.x;
  if (i < nf) fz[i] = 0.f;
  if (i < ni) iz[i] = 0;
}
__global__ __launch_bounds__(256) void initmax_k(float* maxp){ maxp[threadIdx.x] = -1e30f; }

__global__ __launch_bounds__(256) void hist_k(const int* __restrict__ dst, const int* __restrict__ ety, int* cnt){
  int e = blockIdx.x*256 + threadIdx.x;
  if (e < EE) atomicAdd(&cnt[dst[e]*T + ety[e]], 1);
}

__global__ __launch_bounds__(1024) void scan_k(int* cnt, int* off, int* cursor){
  __shared__ int part[1024];
  int tid = threadIdx.x;
  int base = tid*16;
  int loc[16]; int s = 0;
  for (int i = 0; i < 16; i++){ loc[i] = cnt[base+i]; s += loc[i]; }
  part[tid] = s; __syncthreads();
  int v = s;
  for (int offn = 1; offn < 1024; offn <<= 1){
    int add = (tid >= offn) ? part[tid-offn] : 0;
    __syncthreads();
    v += add; part[tid] = v;
    __syncthreads();
  }
  int excl = v - s;
  for (int i = 0; i < 16; i++){ off[base+i] = excl; cursor[base+i] = excl; excl += loc[i]; }
  if (tid == 1023) off[NN*T] = excl;
}

__global__ __launch_bounds__(256) void scatter_k(const int* __restrict__ dst, const int* __restrict__ ety,
                                                 int* cursor, int* sorted){
  int e = blockIdx.x*256 + threadIdx.x;
  if (e < EE){
    int p = atomicAdd(&cursor[dst[e]*T + ety[e]], 1);
    sorted[p] = e;
  }
}

// R15: W12 [b][k][n] -> transposed f16 [b][n][k] (B-fragment reads contiguous)
__global__ __launch_bounds__(256) void pack12T_k(const float* __restrict__ w, _Float16* __restrict__ wp){
  int n = blockIdx.x, b = blockIdx.y, k = threadIdx.x;
  wp[((size_t)b*256 + n)*256 + k] = (_Float16)w[((size_t)b*256 + k)*256 + n];
}

// R15: in_proj_w [768][256] -> f16 copy (row j = output col; already B-friendly)
__global__ __launch_bounds__(256) void packT16_k(const float* __restrict__ ipw, _Float16* __restrict__ wp){
  int j = blockIdx.x, c = threadIdx.x;
  wp[(size_t)j*256 + c] = (_Float16)ipw[(size_t)j*256 + c];
}

// we[t][l][k] = sum_c lin_edge_w[t,l,k,c] * att_edge[t,l,0,c]  -- all (t,l) in one launch
__global__ __launch_bounds__(256) void we2_k(const float* __restrict__ linE, const float* __restrict__ attE,
                                             float* we){
  int t = blockIdx.x, l = blockIdx.y, c = threadIdx.x;
  __shared__ float part[10*C];
  float ae = attE[(t*LL + l)*C + c];
  const float* lw = linE + (size_t)((t*LL + l)*10)*C;
  for (int k = 0; k < 10; k++) part[k*C + c] = lw[k*C + c]*ae;
  __syncthreads();
  if (c < 10){
    float s = 0.f;
    for (int i = 0; i < C; i++) s += part[c*C + i];
    we[(t*LL + l)*10 + c] = s;
  }
}

// layer 0 only (K=20, cheap): fp32 path, fused ssd reduction
__global__ __launch_bounds__(256) void gemm_k(const float* __restrict__ hin, int K,
                                              const float* __restrict__ Wb, long wtstr,
                                              const float* __restrict__ attS, const float* __restrict__ attD,
                                              int l, float* __restrict__ xlo,
                                              float* __restrict__ ssrc, float* __restrict__ sdst){
  int t = blockIdx.y;
  const float* h = hin;
  const float* W = Wb + (size_t)t*wtstr;
  int n0 = blockIdx.x*8;
  __shared__ float sh[8*256];
  __shared__ float red[64];
  for (int j = 0; j < 8; j++)
    for (int k = threadIdx.x; k < K; k += 256)
      sh[j*K + k] = h[(n0+j)*K + k];
  __syncthreads();
  float acc[8] = {0,0,0,0,0,0,0,0};
  int c = threadIdx.x;
  for (int k = 0; k < K; k += 4){
    float w0 = W[(k+0)*C + c], w1 = W[(k+1)*C + c], w2 = W[(k+2)*C + c], w3 = W[(k+3)*C + c];
    #pragma unroll
    for (int j = 0; j < 8; j++){
      float4 h4 = *(const float4*)&sh[j*K + k];
      acc[j] += w0*h4.x + w1*h4.y + w2*h4.z + w3*h4.w;
    }
  }
  #pragma unroll
  for (int j = 0; j < 8; j++) xlo[(t*NN + n0 + j)*C + c] = acc[j];
  float aS = attS[(t*LL + l)*C + c], aD = attD[(t*LL + l)*C + c];
  int lane = c & 63, w = c >> 6;
  #pragma unroll
  for (int j = 0; j < 8; j++){
    float v1 = acc[j]*aS, v2 = acc[j]*aD;
    #pragma unroll
    for (int off = 32; off > 0; off >>= 1){ v1 += __shfl_down(v1, off); v2 += __shfl_down(v2, off); }
    if (lane == 0){ red[j*8 + w] = v1; red[j*8 + 4 + w] = v2; }
  }
  __syncthreads();
  if (c < 16){
    int j = c >> 1, which = c & 1;
    const float* r = red + j*8 + which*4;
    float s = r[0] + r[1] + r[2] + r[3];
    (which ? sdst : ssrc)[t*NN + n0 + j] = s;
  }
}

// R15: layers 1,2 as MFMA GEMM. Block = 64 rows x 256 cols (4 waves x 64x64).
// A (h rows) staged f16 in LDS once; B = pre-transposed f16 W12 read as
// fragments from global (L2-hot, 128KB/slab). 128 MFMAs/wave vs 2048
// dot2/thread in R10's kernel (VALU-bound at 315 TF vs 2.4 PF MFMA).
// ssd fused: per-lane col-partials -> r16 shuffle -> cross-wave LDS reduce.
__global__ __launch_bounds__(256, 2) void gemm16m_k(const float* __restrict__ hin,
                                                    const _Float16* __restrict__ wpT,
                                                    const float* __restrict__ attS, const float* __restrict__ attD,
                                                    int l, float* __restrict__ xlo,
                                                    float* __restrict__ ssrc, float* __restrict__ sdst){
  __shared__ __align__(16) _Float16 As[64*AST];
  __shared__ float redS[4*64], redD[4*64];
  int t = blockIdx.y;
  int mb = blockIdx.x*64;
  int tid = threadIdx.x;
  int w = tid >> 6, lane = tid & 63;
  int r16 = lane & 15, q = lane >> 4;
  const float* h = hin + ((size_t)t*NN + mb)*C;
  {
    int sr = tid >> 2, sc = (tid & 3)*64;
    const float* hr = h + (size_t)sr*C + sc;
    #pragma unroll
    for (int i = 0; i < 8; i++){
      float4 a = *(const float4*)(hr + 8*i);
      float4 b = *(const float4*)(hr + 8*i + 4);
      v8h hv = {(_Float16)a.x,(_Float16)a.y,(_Float16)a.z,(_Float16)a.w,
                (_Float16)b.x,(_Float16)b.y,(_Float16)b.z,(_Float16)b.w};
      *(v8h*)(As + (size_t)sr*AST + sc + 8*i) = hv;
    }
  }
  __syncthreads();
  int cb = w*64;
  const _Float16* WB = wpT + ((size_t)((t*2 + (l-1))*256 + cb))*256;
  v4f o[4][4];
  #pragma unroll
  for (int i = 0; i < 4; i++)
    #pragma unroll
    for (int j = 0; j < 4; j++) o[i][j] = (v4f){0.f,0.f,0.f,0.f};
  #pragma unroll
  for (int kk = 0; kk < 8; kk++){
    v8h a[4], b[4];
    #pragma unroll
    for (int mi = 0; mi < 4; mi++) a[mi] = *(v8h*)(As + (size_t)(mi*16 + r16)*AST + kk*32 + q*8);
    #pragma unroll
    for (int ni = 0; ni < 4; ni++) b[ni] = *(const v8h*)(WB + (size_t)(ni*16 + r16)*256 + kk*32 + q*8);
    #pragma unroll
    for (int mi = 0; mi < 4; mi++)
      #pragma unroll
      for (int ni = 0; ni < 4; ni++)
        o[mi][ni] = __builtin_amdgcn_mfma_f32_16x16x32_f16(a[mi], b[ni], o[mi][ni], 0, 0, 0);
  }
  int tl = t*LL + l;
  float aS[4], aD[4];
  #pragma unroll
  for (int ni = 0; ni < 4; ni++){
    aS[ni] = attS[tl*C + cb + ni*16 + r16];
    aD[ni] = attD[tl*C + cb + ni*16 + r16];
  }
  #pragma unroll
  for (int mi = 0; mi < 4; mi++)
    #pragma unroll
    for (int rr = 0; rr < 4; rr++){
      int row = mb + mi*16 + q*4 + rr;
      float v1 = 0.f, v2 = 0.f;
      #pragma unroll
      for (int ni = 0; ni < 4; ni++){
        float ov = o[mi][ni][rr];
        xlo[((size_t)t*NN + row)*C + cb + ni*16 + r16] = ov;
        v1 += ov*aS[ni]; v2 += ov*aD[ni];
      }
      v1 += __shfl_xor(v1, 1); v2 += __shfl_xor(v2, 1);
      v1 += __shfl_xor(v1, 2); v2 += __shfl_xor(v2, 2);
      v1 += __shfl_xor(v1, 4); v2 += __shfl_xor(v2, 4);
      v1 += __shfl_xor(v1, 8); v2 += __shfl_xor(v2, 8);
      if (r16 == 0){
        redS[w*64 + mi*16 + q*4 + rr] = v1;
        redD[w*64 + mi*16 + q*4 + rr] = v2;
      }
    }
  __syncthreads();
  if (tid < 64)
    ssrc[t*NN + mb + tid] = redS[tid] + redS[64+tid] + redS[128+tid] + redS[192+tid];
  else if (tid < 128){
    int i = tid - 64;
    sdst[t*NN + mb + i] = redD[i] + redD[64+i] + redD[128+i] + redD[192+i];
  }
}

// R15: qkv as MFMA GEMM (same structure, N=768 via blockIdx.y col-group, +bias)
__global__ __launch_bounds__(256, 2) void qkv16m_k(const float* __restrict__ hacc,
                                                   const _Float16* __restrict__ ip16,
                                                   const float* __restrict__ ipb, float* __restrict__ qkv){
  __shared__ __align__(16) _Float16 As[64*AST];
  int p = blockIdx.y;
  int mb = blockIdx.x*64;
  int tid = threadIdx.x;
  int w = tid >> 6, lane = tid & 63;
  int r16 = lane & 15, q = lane >> 4;
  {
    int sr = tid >> 2, sc = (tid & 3)*64;
    const float* hr = hacc + ((size_t)(mb + sr))*C + sc;
    #pragma unroll
    for (int i = 0; i < 8; i++){
      float4 a = *(const float4*)(hr + 8*i);
      float4 b = *(const float4*)(hr + 8*i + 4);
      v8h hv = {(_Float16)a.x,(_Float16)a.y,(_Float16)a.z,(_Float16)a.w,
                (_Float16)b.x,(_Float16)b.y,(_Float16)b.z,(_Float16)b.w};
      *(v8h*)(As + (size_t)sr*AST + sc + 8*i) = hv;
    }
  }
  __syncthreads();
  int cb = p*256 + w*64;
  v4f o[4][4];
  #pragma unroll
  for (int i = 0; i < 4; i++)
    #pragma unroll
    for (int j = 0; j < 4; j++) o[i][j] = (v4f){0.f,0.f,0.f,0.f};
  #pragma unroll
  for (int kk = 0; kk < 8; kk++){
    v8h a[4], b[4];
    #pragma unroll
    for (int mi = 0; mi < 4; mi++) a[mi] = *(v8h*)(As + (size_t)(mi*16 + r16)*AST + kk*32 + q*8);
    #pragma unroll
    for (int ni = 0; ni < 4; ni++) b[ni] = *(const v8h*)(ip16 + (size_t)(cb + ni*16 + r16)*256 + kk*32 + q*8);
    #pragma unroll
    for (int mi = 0; mi < 4; mi++)
      #pragma unroll
      for (int ni = 0; ni < 4; ni++)
        o[mi][ni] = __builtin_amdgcn_mfma_f32_16x16x32_f16(a[mi], b[ni], o[mi][ni], 0, 0, 0);
  }
  float bn[4];
  #pragma unroll
  for (int ni = 0; ni < 4; ni++) bn[ni] = ipb[cb + ni*16 + r16];
  #pragma unroll
  for (int mi = 0; mi < 4; mi++)
    #pragma unroll
    for (int rr = 0; rr < 4; rr++){
      int row = mb + mi*16 + q*4 + rr;
      #pragma unroll
      for (int ni = 0; ni < 4; ni++)
        qkv[(size_t)row*768 + cb + ni*16 + r16] = o[mi][ni][rr] + bn[ni];
    }
}

// all layers at once: se[l][e]
__global__ __launch_bounds__(256) void se_k(const float* __restrict__ eattr, const int* __restrict__ ety,
                                            const float* __restrict__ we, float* se){
  int e = blockIdx.x*256 + threadIdx.x;
  int l = blockIdx.y;
  if (e < EE){
    const float* w = we + (ety[e]*LL + l)*10;
    const float* ea = eattr + e*10;
    float s = 0.f;
    #pragma unroll
    for (int k = 0; k < 10; k++) s += ea[k]*w[k];
    se[(size_t)l*EE + e] = s;
  }
}

// all layers at once: sloop[l][i]
__global__ __launch_bounds__(256) void sloop_k(const int* __restrict__ off, const int* __restrict__ sorted,
                                               const float* __restrict__ se, float* sloop){
  int i = blockIdx.x*256 + threadIdx.x;
  int l = blockIdx.y;
  if (i < NN*T){
    int o0 = off[i], o1 = off[i+1];
    const float* sel = se + (size_t)l*EE;
    float s = 0.f;
    for (int j = o0; j < o1; j++) s += sel[sorted[j]];
    int dg = o1 - o0;
    sloop[(size_t)l*(NN*T) + i] = s / (float)(dg > 0 ? dg : 1);
  }
}

// R14: wave-per-(n,t) aggregation (zero barriers, shuffle softmax, deg<=64)
__global__ __launch_bounds__(256) void agg_k(const float* __restrict__ xl, const float* __restrict__ ssrc,
                                             const float* __restrict__ sdst, const float* __restrict__ se,
                                             const float* __restrict__ sloop, const int* __restrict__ off,
                                             const int* __restrict__ sorted, const int* __restrict__ srcv,
                                             const float* __restrict__ bias, float* __restrict__ hout, int l){
  int gid = blockIdx.x*4 + (threadIdx.x >> 6);   // over N*T, == n*T+t
  int lane = threadIdx.x & 63;
  int n = gid >> 2, t = gid & 3;                 // T==4
  int o0 = off[gid];
  int deg = off[gid+1] - o0;
  if (deg > 64) deg = 64;
  float sd = sdst[t*NN + n];
  float sc = -1e30f; int sj = 0;
  if (lane < deg){
    int e = sorted[o0 + lane];
    sj = srcv[e];
    sc = lrelu(ssrc[t*NN + sj] + sd + se[e]);
  }
  float al = lrelu(ssrc[t*NN + n] + sd + sloop[gid]);
  float mx = fmaxf(sc, al);
  #pragma unroll
  for (int o = 32; o > 0; o >>= 1) mx = fmaxf(mx, __shfl_xor(mx, o));
  float ex = (lane < deg) ? __expf(sc - mx) : 0.f;
  float ale = __expf(al - mx);
  float ssum = ex;
  #pragma unroll
  for (int o = 32; o > 0; o >>= 1) ssum += __shfl_xor(ssum, o);
  float inv = 1.f/(ssum + ale + 1e-16f);
  const float4* xl4 = (const float4*)xl;
  float4 acc = xl4[((size_t)(t*NN + n))*64 + lane];
  acc.x *= ale; acc.y *= ale; acc.z *= ale; acc.w *= ale;
  for (int j = 0; j < deg; j++){
    float p = __shfl(ex, j);
    int s = __shfl(sj, j);
    float4 v = xl4[((size_t)(t*NN + s))*64 + lane];
    acc.x += p*v.x; acc.y += p*v.y; acc.z += p*v.z; acc.w += p*v.w;
  }
  float4 b4 = *(const float4*)&bias[(t*LL + l)*C + lane*4];
  acc.x = eluf(acc.x*inv + b4.x); acc.y = eluf(acc.y*inv + b4.y);
  acc.z = eluf(acc.z*inv + b4.z); acc.w = eluf(acc.w*inv + b4.w);
  ((float4*)hout)[((size_t)(t*NN + n))*64 + lane] = acc;
}

__global__ __launch_bounds__(256) void hacc_k(const float* __restrict__ h, const float* __restrict__ etw,
                                              float* __restrict__ hacc){
  int n = blockIdx.x, c = threadIdx.x;
  float e0 = etw[0], e1 = etw[1], e2 = etw[2], e3 = etw[3];
  float m = fmaxf(fmaxf(e0,e1), fmaxf(e2,e3));
  float w0 = __expf(e0-m), w1 = __expf(e1-m), w2 = __expf(e2-m), w3 = __expf(e3-m);
  float inv = 1.f/(w0+w1+w2+w3);
  float s = w0*h[(0*NN+n)*C+c] + w1*h[(1*NN+n)*C+c] + w2*h[(2*NN+n)*C+c] + w3*h[(3*NN+n)*C+c];
  hacc[n*C + c] = s*inv;
}

__global__ __launch_bounds__(256) void colstats_k(const float* __restrict__ hacc, float* meanp, float* maxp){
  int r0 = blockIdx.x*(NN/256), c = threadIdx.x;
  float sm = 0.f, mx = -1e30f;
  for (int r = 0; r < NN/256; r++){
    float v = hacc[(r0+r)*C + c];
    sm += v; mx = fmaxf(mx, v);
  }
  atomicAdd(&meanp[c], sm*(1.f/4096.f));
  atomicMaxF(&maxp[c], mx);
}

// R12: multi-wave MFMA flash attention (4 waves/block, coop K/V^T stage,
// Q in registers, per-wave P buffer; 2 blocks/CU)
__global__ __launch_bounds__(256, 2) void attn_k(const float* __restrict__ qkv,
                                                 float* __restrict__ opart,
                                                 float* __restrict__ dpart){
  __shared__ __align__(16) _Float16 Ks[64*QKS];    // [m][k]
  __shared__ __align__(16) _Float16 VTs[64*QKS];   // [d][m]
  __shared__ __align__(16) _Float16 Ps[4][64*QKS]; // per-wave [n][m]
  int tid = threadIdx.x;
  int wave = tid >> 6, l = tid & 63;
  int nb = blockIdx.x*256 + wave*64;
  int h = blockIdx.y, mc = blockIdx.z;
  int r16 = l & 15, q = l >> 4;
  _Float16* Pw = Ps[wave];

  v8h qf[4][2];
  #pragma unroll
  for (int ni = 0; ni < 4; ni++){
    const float* qrow = qkv + (size_t)(nb + ni*16 + r16)*768 + h*64;
    #pragma unroll
    for (int kk = 0; kk < 2; kk++){
      float4 a = *(const float4*)(qrow + kk*32 + q*8);
      float4 b = *(const float4*)(qrow + kk*32 + q*8 + 4);
      v8h hv = {(_Float16)(a.x*0.125f), (_Float16)(a.y*0.125f),
                (_Float16)(a.z*0.125f), (_Float16)(a.w*0.125f),
                (_Float16)(b.x*0.125f), (_Float16)(b.y*0.125f),
                (_Float16)(b.z*0.125f), (_Float16)(b.w*0.125f)};
      qf[ni][kk] = hv;
    }
  }

  v4f o[4][4];
  #pragma unroll
  for (int i = 0; i < 4; i++)
    #pragma unroll
    for (int j = 0; j < 4; j++) o[i][j] = (v4f){0.f,0.f,0.f,0.f};
  float dn[4] = {0.f,0.f,0.f,0.f};

  for (int mt = 0; mt < NN/MCH/64; mt++){
    int mb = mc*(NN/MCH) + mt*64;
    __syncthreads();
    {
      int sr = tid >> 2, sc = (tid & 3)*16;
      const float* krow = qkv + (size_t)(mb + sr)*768 + 256 + h*64 + sc;
      float4 a = *(const float4*)(krow + 0);
      float4 b = *(const float4*)(krow + 4);
      float4 cc = *(const float4*)(krow + 8);
      float4 d = *(const float4*)(krow + 12);
      v8h h0 = {(_Float16)a.x, (_Float16)a.y, (_Float16)a.z, (_Float16)a.w,
                (_Float16)b.x, (_Float16)b.y, (_Float16)b.z, (_Float16)b.w};
      v8h h1 = {(_Float16)cc.x, (_Float16)cc.y, (_Float16)cc.z, (_Float16)cc.w,
                (_Float16)d.x, (_Float16)d.y, (_Float16)d.z, (_Float16)d.w};
      *(v8h*)(Ks + (size_t)sr*QKS + sc) = h0;
      *(v8h*)(Ks + (size_t)sr*QKS + sc + 8) = h1;
    }
    {
      int m0 = (tid & 31)*2;
      int db = (tid >> 5)*8;
      const float* v0 = qkv + (size_t)(mb + m0)*768 + 512 + h*64 + db;
      const float* v1 = v0 + 768;
      #pragma unroll
      for (int i = 0; i < 2; i++){
        float4 a = *(const float4*)(v0 + 4*i);
        float4 b = *(const float4*)(v1 + 4*i);
        int d = db + 4*i;
        *(unsigned*)(VTs + (size_t)(d+0)*QKS + m0) = pk2(a.x, b.x);
        *(unsigned*)(VTs + (size_t)(d+1)*QKS + m0) = pk2(a.y, b.y);
        *(unsigned*)(VTs + (size_t)(d+2)*QKS + m0) = pk2(a.z, b.z);
        *(unsigned*)(VTs + (size_t)(d+3)*QKS + m0) = pk2(a.w, b.w);
      }
    }
    __syncthreads();
    v4f c[4][4];
    #pragma unroll
    for (int i = 0; i < 4; i++)
      #pragma unroll
      for (int j = 0; j < 4; j++) c[i][j] = (v4f){0.f,0.f,0.f,0.f};
    #pragma unroll
    for (int kk = 0; kk < 2; kk++){
      v8h a[4];
      #pragma unroll
      for (int mi = 0; mi < 4; mi++) a[mi] = *(v8h*)(Ks + (size_t)(mi*16 + r16)*QKS + kk*32 + q*8);
      #pragma unroll
      for (int mi = 0; mi < 4; mi++)
        #pragma unroll
        for (int ni = 0; ni < 4; ni++)
          c[mi][ni] = __builtin_amdgcn_mfma_f32_16x16x32_f16(a[mi], qf[ni][kk], c[mi][ni], 0, 0, 0);
    }
    #pragma unroll
    for (int mi = 0; mi < 4; mi++)
      #pragma unroll
      for (int ni = 0; ni < 4; ni++){
        float e0 = __expf(c[mi][ni][0]), e1 = __expf(c[mi][ni][1]),
              e2 = __expf(c[mi][ni][2]), e3 = __expf(c[mi][ni][3]);
        dn[ni] += e0 + e1 + e2 + e3;
        *(uint2*)(Pw + (size_t)(ni*16 + r16)*QKS + mi*16 + q*4) = make_uint2(pk2(e0,e1), pk2(e2,e3));
      }
    #pragma unroll
    for (int km = 0; km < 2; km++){
      v8h pa[4], vb[4];
      #pragma unroll
      for (int ni = 0; ni < 4; ni++) pa[ni] = *(v8h*)(Pw + (size_t)(ni*16 + r16)*QKS + km*32 + q*8);
      #pragma unroll
      for (int di = 0; di < 4; di++) vb[di] = *(v8h*)(VTs + (size_t)(di*16 + r16)*QKS + km*32 + q*8);
      #pragma unroll
      for (int ni = 0; ni < 4; ni++)
        #pragma unroll
        for (int di = 0; di < 4; di++)
          o[ni][di] = __builtin_amdgcn_mfma_f32_16x16x32_f16(pa[ni], vb[di], o[ni][di], 0, 0, 0);
    }
  }

  float* ob = opart + ((size_t)mc*NN + nb)*C + h*64;
  #pragma unroll
  for (int ni = 0; ni < 4; ni++)
    #pragma unroll
    for (int di = 0; di < 4; di++)
      #pragma unroll
      for (int r = 0; r < 4; r++)
        ob[(size_t)(ni*16 + q*4 + r)*C + di*16 + r16] = o[ni][di][r];
  #pragma unroll
  for (int ni = 0; ni < 4; ni++){
    dn[ni] += __shfl_xor(dn[ni], 16);
    dn[ni] += __shfl_xor(dn[ni], 32);
  }
  if (q == 0){
    #pragma unroll
    for (int ni = 0; ni < 4; ni++)
      dpart[((size_t)mc*NN + nb + ni*16 + r16)*AHD + h] = dn[ni];
  }
}

__global__ __launch_bounds__(256) void attnred_k(const float* __restrict__ opart, const float* __restrict__ dpart,
                                                 float* omean){
  int r0 = blockIdx.x*(NN/256), c = threadIdx.x;
  int head = c >> 6;
  float s = 0.f;
  for (int r = 0; r < NN/256; r++){
    int n = r0 + r;
    float dsum = 0.f, osum = 0.f;
    #pragma unroll
    for (int mc = 0; mc < MCH; mc++){
      dsum += dpart[((size_t)mc*NN + n)*AHD + head];
      osum += opart[((size_t)mc*NN + n)*C + c];
    }
    s += osum / (dsum + 1e-16f);
  }
  atomicAdd(&omean[c], s*(1.f/4096.f));
}

__global__ __launch_bounds__(256) void attnproj_k(const float* __restrict__ omean, const float* __restrict__ opw,
                                                  const float* __restrict__ opb, float* attnp){
  __shared__ float sh[256];
  int j = threadIdx.x;
  sh[j] = omean[j];
  __syncthreads();
  float acc = opb[j];
  for (int k = 0; k < 256; k++) acc += sh[k]*opw[j*256 + k];
  attnp[j] = acc;
}

__global__ __launch_bounds__(512) void fus1_k(const float* __restrict__ meanp, const float* __restrict__ maxp,
                                              const float* __restrict__ attnp, const float* __restrict__ fw1,
                                              const float* __restrict__ fb1, float* g1){
  __shared__ float comb[768];
  for (int i = threadIdx.x; i < 768; i += 512)
    comb[i] = (i < 256) ? meanp[i] : (i < 512 ? maxp[i-256] : attnp[i-512]);
  __syncthreads();
  int j = threadIdx.x;
  float acc = fb1[j];
  for (int k = 0; k < 768; k++) acc += comb[k]*fw1[k*512 + j];
  g1[j] = fmaxf(acc, 0.f);
}

__global__ __launch_bounds__(256) void fus2_k(const float* __restrict__ g1, const float* __restrict__ fw2,
                                              const float* __restrict__ fb2, float* __restrict__ out){
  __shared__ float g[512];
  g[threadIdx.x] = g1[threadIdx.x];
  g[threadIdx.x + 256] = g1[threadIdx.x + 256];
  __syncthreads();
  int j = threadIdx.x;
  float acc = fb2[j];
  for (int k = 0; k < 512; k++) acc += g[k]*fw2[k*256 + j];
  out[j] = fmaxf(acc, 0.f);
}

extern "C" void kernel_launch(void* const* d_in, const int* in_sizes, int n_in,
                              void* d_out, int out_size, void* d_ws, size_t ws_size,
                              hipStream_t stream){
  const float* x     = (const float*)d_in[0];
  const int*   srcv  = (const int*)d_in[1];
  const int*   dstv  = (const int*)d_in[2];
  const float* eattr = (const float*)d_in[3];
  const int*   etyp  = (const int*)d_in[4];
  const float* W0    = (const float*)d_in[5];
  const float* W12   = (const float*)d_in[6];
  const float* attS  = (const float*)d_in[7];
  const float* attD  = (const float*)d_in[8];
  const float* attE  = (const float*)d_in[9];
  const float* linE  = (const float*)d_in[10];
  const float* bias  = (const float*)d_in[11];
  const float* etw   = (const float*)d_in[12];
  const float* ipw   = (const float*)d_in[13];
  const float* ipb   = (const float*)d_in[14];
  const float* opw   = (const float*)d_in[15];
  const float* opb   = (const float*)d_in[16];
  const float* fw1   = (const float*)d_in[17];
  const float* fb1   = (const float*)d_in[18];
  const float* fw2   = (const float*)d_in[19];
  const float* fb2   = (const float*)d_in[20];
  float* out = (float*)d_out;

  if (ws_size < (size_t)WS_WORDS*4) return;

  int*       ip   = (int*)d_ws;
  float*     fp   = (float*)d_ws;
  _Float16*  ip16 = (_Float16*)(fp + F_WT);
  _Float16*  wpT  = (_Float16*)(fp + U_W12P);

  zero_k<<<(NN*T + 255)/256, 256, 0, stream>>>(fp + F_MEANP, NZERO, ip + W_CURSOR, NN*T);
  initmax_k<<<1, 256, 0, stream>>>(fp + F_MAXP);

  hist_k<<<EE/256, 256, 0, stream>>>(dstv, etyp, ip + W_CURSOR);
  scan_k<<<1, 1024, 0, stream>>>(ip + W_CURSOR, ip + W_OFF, ip + W_CURSOR);
  scatter_k<<<EE/256, 256, 0, stream>>>(dstv, etyp, ip + W_CURSOR, ip + W_SORTED);

  // weight packing prepass
  pack12T_k<<<dim3(256, T*2), 256, 0, stream>>>(W12, wpT);
  packT16_k<<<768, 256, 0, stream>>>(ipw, ip16);

  // all-layer prepass: we, se, sloop
  we2_k<<<dim3(T, LL), 256, 0, stream>>>(linE, attE, fp + F_WE);
  se_k<<<dim3(EE/256, LL), 256, 0, stream>>>(eattr, etyp, fp + F_WE, fp + F_SE);
  sloop_k<<<dim3((NN*T)/256, LL), 256, 0, stream>>>(ip + W_OFF, ip + W_SORTED, fp + F_SE, fp + F_SLOOP);

  for (int l = 0; l < 3; l++){
    if (l == 0)
      gemm_k<<<dim3(NN/8, T), 256, 0, stream>>>(x, DIN, W0, (long)DIN*C, attS, attD, 0,
                                                fp + F_XL, fp + F_SSRC, fp + F_SDST);
    else
      gemm16m_k<<<dim3(NN/64, T), 256, 0, stream>>>(fp + F_H, wpT, attS, attD, l,
                                                    fp + F_XL, fp + F_SSRC, fp + F_SDST);
    agg_k<<<(NN*T)/4, 256, 0, stream>>>(fp + F_XL, fp + F_SSRC, fp + F_SDST,
                                        fp + F_SE + (size_t)l*EE,
                                        fp + F_SLOOP + (size_t)l*(NN*T),
                                        ip + W_OFF, ip + W_SORTED, srcv,
                                        bias, fp + F_H, l);
  }

  hacc_k<<<NN, 256, 0, stream>>>(fp + F_H, etw, fp + F_HACC);
  colstats_k<<<256, 256, 0, stream>>>(fp + F_HACC, fp + F_MEANP, fp + F_MAXP);

  qkv16m_k<<<dim3(NN/64, 3), 256, 0, stream>>>(fp + F_HACC, ip16, ipb, fp + F_QKV);
  attn_k<<<dim3(NN/256, AHD, MCH), 256, 0, stream>>>(fp + F_QKV, fp + F_OPART, fp + F_DPART);
  attnred_k<<<256, 256, 0, stream>>>(fp + F_OPART, fp + F_DPART, fp + F_OMEAN);
  attnproj_k<<<1, 256, 0, stream>>>(fp + F_OMEAN, opw, opb, fp + F_ATTNP);

  fus1_k<<<1, 512, 0, stream>>>(fp + F_MEANP, fp + F_MAXP, fp + F_ATTNP, fw1, fb1, fp + F_G1);
  fus2_k<<<1, 256, 0, stream>>>(fp + F_G1, fw2, fb2, out);
}

// Round 16
// 382.869 us; speedup vs baseline: 2.6326x; 1.0194x over previous
//
#include <hip/hip_runtime.h>
#include <math.h>

#define T 4
#define LL 3
#define C 256
#define DIN 20
#define NN 4096
#define EE 65536
#define AHD 4
#define MCH 8     // attention m-chunks (blockIdx.z); grid 16x4x8=512 blocks = 2/CU
#define QKS 72    // padded LDS row stride in halfs (64+8): +4 banks/row -> 2-way (free)
#define AST 264   // GEMM A-tile LDS row stride in halfs (256+8): 2-way (free)

// ---- workspace layout (4-byte word offsets) ----
#define W_OFF    0                    // int[N*T+1]
#define W_CURSOR 16640                // int[N*T]  (also hist counts)
#define W_SORTED 33024                // int[E]
#define F_XL     98560                // float[T][N][C]
#define F_H      (F_XL + T*NN*C)      // float[T][N][C]
#define F_OPART  F_XL                 // alias: float[MCH][N][C] == exactly F_XL+F_H extent (dead at attn time)
#define F_SSRC   (F_H + T*NN*C)       // float[T][N]
#define F_SDST   (F_SSRC + T*NN)      // float[T][N]
#define F_SE     (F_SDST + T*NN)      // float[LL][E]
#define F_SLOOP  (F_SE + LL*EE)       // float[LL][N*T] indexed l*NT + n*T+t
#define F_WE     (F_SLOOP + LL*T*NN)  // float[T*LL][10] (padded 128)
#define F_HACC   (F_WE + 128)         // float[N][C]
#define F_WT     (F_HACC + NN*C)      // f16[768][256] in_proj_w (region reserved 768*256 words)
#define F_QKV    (F_WT + 768*256)     // float[N][768]
#define F_DPART  (F_QKV + NN*768)     // float[MCH][N][AH]
#define F_MEANP  (F_DPART + MCH*NN*AHD) // float[C]
#define F_MAXP   (F_MEANP + C)        // float[C]
#define F_OMEAN  (F_MAXP + C)         // float[C]
#define F_ATTNP  (F_OMEAN + C)        // float[C]  (unused after tail fusion; kept for layout stability)
#define F_G1     (F_ATTNP + C)        // float[512] (unused after tail fusion)
#define U_W12P   (F_G1 + 512)         // f16[T*2][256 n][256 k] transposed W12
#define WS_WORDS (U_W12P + 262144)

static __device__ __forceinline__ float lrelu(float x){ return x > 0.f ? x : 0.2f*x; }
static __device__ __forceinline__ float eluf(float x){ return x > 0.f ? x : __expf(x) - 1.f; }

typedef _Float16 half2_t __attribute__((ext_vector_type(2)));
typedef _Float16 v8h __attribute__((ext_vector_type(8)));
typedef float v4f __attribute__((ext_vector_type(4)));

static __device__ __forceinline__ unsigned pk2(float x, float y){
  half2_t h; h.x = (_Float16)x; h.y = (_Float16)y;
  return __builtin_bit_cast(unsigned, h);
}

static __device__ inline void atomicMaxF(float* addr, float val){
  int* ai = (int*)addr;
  int old = __float_as_int(*addr);
  while (__int_as_float(old) < val){
    int assumed = old;
    old = atomicCAS(ai, assumed, __float_as_int(val));
    if (old == assumed) break;
  }
}

// R16: fused init -- meanp=0, maxp=-1e30, omean=0, cursor=0 in one launch
__global__ __launch_bounds__(256) void zero2_k(float* base /*F_MEANP*/, int* iz, int ni){
  int i = blockIdx.x*256 + threadIdx.x;
  if (i < 256) base[i] = 0.f;            // meanp
  else if (i < 512) base[i] = -1e30f;    // maxp
  else if (i < 768) base[i] = 0.f;       // omean
  if (i < ni) iz[i] = 0;
}

__global__ __launch_bounds__(256) void hist_k(const int* __restrict__ dst, const int* __restrict__ ety, int* cnt){
  int e = blockIdx.x*256 + threadIdx.x;
  if (e < EE) atomicAdd(&cnt[dst[e]*T + ety[e]], 1);
}

__global__ __launch_bounds__(1024) void scan_k(int* cnt, int* off, int* cursor){
  __shared__ int part[1024];
  int tid = threadIdx.x;
  int base = tid*16;
  int loc[16]; int s = 0;
  for (int i = 0; i < 16; i++){ loc[i] = cnt[base+i]; s += loc[i]; }
  part[tid] = s; __syncthreads();
  int v = s;
  for (int offn = 1; offn < 1024; offn <<= 1){
    int add = (tid >= offn) ? part[tid-offn] : 0;
    __syncthreads();
    v += add; part[tid] = v;
    __syncthreads();
  }
  int excl = v - s;
  for (int i = 0; i < 16; i++){ off[base+i] = excl; cursor[base+i] = excl; excl += loc[i]; }
  if (tid == 1023) off[NN*T] = excl;
}

__global__ __launch_bounds__(256) void scatter_k(const int* __restrict__ dst, const int* __restrict__ ety,
                                                 int* cursor, int* sorted){
  int e = blockIdx.x*256 + threadIdx.x;
  if (e < EE){
    int p = atomicAdd(&cursor[dst[e]*T + ety[e]], 1);
    sorted[p] = e;
  }
}

// R16: fused weight packing. by<8: W12 [b][k][n] -> f16 [b][n][k];
// by>=8: in_proj_w [768][256] -> f16 straight copy.
__global__ __launch_bounds__(256) void pack_k(const float* __restrict__ w12, _Float16* __restrict__ wpT,
                                              const float* __restrict__ ipw, _Float16* __restrict__ ip16){
  int by = blockIdx.y, bx = blockIdx.x, tid = threadIdx.x;
  if (by < 8){
    wpT[((size_t)by*256 + bx)*256 + tid] = (_Float16)w12[((size_t)by*256 + tid)*256 + bx];
  } else {
    int j = (by - 8)*256 + bx;
    ip16[(size_t)j*256 + tid] = (_Float16)ipw[(size_t)j*256 + tid];
  }
}

// we[t][l][k] = sum_c lin_edge_w[t,l,k,c] * att_edge[t,l,0,c]  -- all (t,l) in one launch
__global__ __launch_bounds__(256) void we2_k(const float* __restrict__ linE, const float* __restrict__ attE,
                                             float* we){
  int t = blockIdx.x, l = blockIdx.y, c = threadIdx.x;
  __shared__ float part[10*C];
  float ae = attE[(t*LL + l)*C + c];
  const float* lw = linE + (size_t)((t*LL + l)*10)*C;
  for (int k = 0; k < 10; k++) part[k*C + c] = lw[k*C + c]*ae;
  __syncthreads();
  if (c < 10){
    float s = 0.f;
    for (int i = 0; i < C; i++) s += part[c*C + i];
    we[(t*LL + l)*10 + c] = s;
  }
}

// layer 0 only (K=20, cheap): fp32 path, fused ssd reduction
__global__ __launch_bounds__(256) void gemm_k(const float* __restrict__ hin, int K,
                                              const float* __restrict__ Wb, long wtstr,
                                              const float* __restrict__ attS, const float* __restrict__ attD,
                                              int l, float* __restrict__ xlo,
                                              float* __restrict__ ssrc, float* __restrict__ sdst){
  int t = blockIdx.y;
  const float* h = hin;
  const float* W = Wb + (size_t)t*wtstr;
  int n0 = blockIdx.x*8;
  __shared__ float sh[8*256];
  __shared__ float red[64];
  for (int j = 0; j < 8; j++)
    for (int k = threadIdx.x; k < K; k += 256)
      sh[j*K + k] = h[(n0+j)*K + k];
  __syncthreads();
  float acc[8] = {0,0,0,0,0,0,0,0};
  int c = threadIdx.x;
  for (int k = 0; k < K; k += 4){
    float w0 = W[(k+0)*C + c], w1 = W[(k+1)*C + c], w2 = W[(k+2)*C + c], w3 = W[(k+3)*C + c];
    #pragma unroll
    for (int j = 0; j < 8; j++){
      float4 h4 = *(const float4*)&sh[j*K + k];
      acc[j] += w0*h4.x + w1*h4.y + w2*h4.z + w3*h4.w;
    }
  }
  #pragma unroll
  for (int j = 0; j < 8; j++) xlo[(t*NN + n0 + j)*C + c] = acc[j];
  float aS = attS[(t*LL + l)*C + c], aD = attD[(t*LL + l)*C + c];
  int lane = c & 63, w = c >> 6;
  #pragma unroll
  for (int j = 0; j < 8; j++){
    float v1 = acc[j]*aS, v2 = acc[j]*aD;
    #pragma unroll
    for (int off = 32; off > 0; off >>= 1){ v1 += __shfl_down(v1, off); v2 += __shfl_down(v2, off); }
    if (lane == 0){ red[j*8 + w] = v1; red[j*8 + 4 + w] = v2; }
  }
  __syncthreads();
  if (c < 16){
    int j = c >> 1, which = c & 1;
    const float* r = red + j*8 + which*4;
    float s = r[0] + r[1] + r[2] + r[3];
    (which ? sdst : ssrc)[t*NN + n0 + j] = s;
  }
}

// R15: layers 1,2 as MFMA GEMM (4 waves x 64x64 tiles, fused ssd epilogue)
__global__ __launch_bounds__(256, 2) void gemm16m_k(const float* __restrict__ hin,
                                                    const _Float16* __restrict__ wpT,
                                                    const float* __restrict__ attS, const float* __restrict__ attD,
                                                    int l, float* __restrict__ xlo,
                                                    float* __restrict__ ssrc, float* __restrict__ sdst){
  __shared__ __align__(16) _Float16 As[64*AST];
  __shared__ float redS[4*64], redD[4*64];
  int t = blockIdx.y;
  int mb = blockIdx.x*64;
  int tid = threadIdx.x;
  int w = tid >> 6, lane = tid & 63;
  int r16 = lane & 15, q = lane >> 4;
  const float* h = hin + ((size_t)t*NN + mb)*C;
  {
    int sr = tid >> 2, sc = (tid & 3)*64;
    const float* hr = h + (size_t)sr*C + sc;
    #pragma unroll
    for (int i = 0; i < 8; i++){
      float4 a = *(const float4*)(hr + 8*i);
      float4 b = *(const float4*)(hr + 8*i + 4);
      v8h hv = {(_Float16)a.x,(_Float16)a.y,(_Float16)a.z,(_Float16)a.w,
                (_Float16)b.x,(_Float16)b.y,(_Float16)b.z,(_Float16)b.w};
      *(v8h*)(As + (size_t)sr*AST + sc + 8*i) = hv;
    }
  }
  __syncthreads();
  int cb = w*64;
  const _Float16* WB = wpT + ((size_t)((t*2 + (l-1))*256 + cb))*256;
  v4f o[4][4];
  #pragma unroll
  for (int i = 0; i < 4; i++)
    #pragma unroll
    for (int j = 0; j < 4; j++) o[i][j] = (v4f){0.f,0.f,0.f,0.f};
  #pragma unroll
  for (int kk = 0; kk < 8; kk++){
    v8h a[4], b[4];
    #pragma unroll
    for (int mi = 0; mi < 4; mi++) a[mi] = *(v8h*)(As + (size_t)(mi*16 + r16)*AST + kk*32 + q*8);
    #pragma unroll
    for (int ni = 0; ni < 4; ni++) b[ni] = *(const v8h*)(WB + (size_t)(ni*16 + r16)*256 + kk*32 + q*8);
    #pragma unroll
    for (int mi = 0; mi < 4; mi++)
      #pragma unroll
      for (int ni = 0; ni < 4; ni++)
        o[mi][ni] = __builtin_amdgcn_mfma_f32_16x16x32_f16(a[mi], b[ni], o[mi][ni], 0, 0, 0);
  }
  int tl = t*LL + l;
  float aS[4], aD[4];
  #pragma unroll
  for (int ni = 0; ni < 4; ni++){
    aS[ni] = attS[tl*C + cb + ni*16 + r16];
    aD[ni] = attD[tl*C + cb + ni*16 + r16];
  }
  #pragma unroll
  for (int mi = 0; mi < 4; mi++)
    #pragma unroll
    for (int rr = 0; rr < 4; rr++){
      int row = mb + mi*16 + q*4 + rr;
      float v1 = 0.f, v2 = 0.f;
      #pragma unroll
      for (int ni = 0; ni < 4; ni++){
        float ov = o[mi][ni][rr];
        xlo[((size_t)t*NN + row)*C + cb + ni*16 + r16] = ov;
        v1 += ov*aS[ni]; v2 += ov*aD[ni];
      }
      v1 += __shfl_xor(v1, 1); v2 += __shfl_xor(v2, 1);
      v1 += __shfl_xor(v1, 2); v2 += __shfl_xor(v2, 2);
      v1 += __shfl_xor(v1, 4); v2 += __shfl_xor(v2, 4);
      v1 += __shfl_xor(v1, 8); v2 += __shfl_xor(v2, 8);
      if (r16 == 0){
        redS[w*64 + mi*16 + q*4 + rr] = v1;
        redD[w*64 + mi*16 + q*4 + rr] = v2;
      }
    }
  __syncthreads();
  if (tid < 64)
    ssrc[t*NN + mb + tid] = redS[tid] + redS[64+tid] + redS[128+tid] + redS[192+tid];
  else if (tid < 128){
    int i = tid - 64;
    sdst[t*NN + mb + i] = redD[i] + redD[64+i] + redD[128+i] + redD[192+i];
  }
}

// R15: qkv as MFMA GEMM
__global__ __launch_bounds__(256, 2) void qkv16m_k(const float* __restrict__ hacc,
                                                   const _Float16* __restrict__ ip16,
                                                   const float* __restrict__ ipb, float* __restrict__ qkv){
  __shared__ __align__(16) _Float16 As[64*AST];
  int p = blockIdx.y;
  int mb = blockIdx.x*64;
  int tid = threadIdx.x;
  int w = tid >> 6, lane = tid & 63;
  int r16 = lane & 15, q = lane >> 4;
  {
    int sr = tid >> 2, sc = (tid & 3)*64;
    const float* hr = hacc + ((size_t)(mb + sr))*C + sc;
    #pragma unroll
    for (int i = 0; i < 8; i++){
      float4 a = *(const float4*)(hr + 8*i);
      float4 b = *(const float4*)(hr + 8*i + 4);
      v8h hv = {(_Float16)a.x,(_Float16)a.y,(_Float16)a.z,(_Float16)a.w,
                (_Float16)b.x,(_Float16)b.y,(_Float16)b.z,(_Float16)b.w};
      *(v8h*)(As + (size_t)sr*AST + sc + 8*i) = hv;
    }
  }
  __syncthreads();
  int cb = p*256 + w*64;
  v4f o[4][4];
  #pragma unroll
  for (int i = 0; i < 4; i++)
    #pragma unroll
    for (int j = 0; j < 4; j++) o[i][j] = (v4f){0.f,0.f,0.f,0.f};
  #pragma unroll
  for (int kk = 0; kk < 8; kk++){
    v8h a[4], b[4];
    #pragma unroll
    for (int mi = 0; mi < 4; mi++) a[mi] = *(v8h*)(As + (size_t)(mi*16 + r16)*AST + kk*32 + q*8);
    #pragma unroll
    for (int ni = 0; ni < 4; ni++) b[ni] = *(const v8h*)(ip16 + (size_t)(cb + ni*16 + r16)*256 + kk*32 + q*8);
    #pragma unroll
    for (int mi = 0; mi < 4; mi++)
      #pragma unroll
      for (int ni = 0; ni < 4; ni++)
        o[mi][ni] = __builtin_amdgcn_mfma_f32_16x16x32_f16(a[mi], b[ni], o[mi][ni], 0, 0, 0);
  }
  float bn[4];
  #pragma unroll
  for (int ni = 0; ni < 4; ni++) bn[ni] = ipb[cb + ni*16 + r16];
  #pragma unroll
  for (int mi = 0; mi < 4; mi++)
    #pragma unroll
    for (int rr = 0; rr < 4; rr++){
      int row = mb + mi*16 + q*4 + rr;
      #pragma unroll
      for (int ni = 0; ni < 4; ni++)
        qkv[(size_t)row*768 + cb + ni*16 + r16] = o[mi][ni][rr] + bn[ni];
    }
}

// all layers at once: se[l][e]
__global__ __launch_bounds__(256) void se_k(const float* __restrict__ eattr, const int* __restrict__ ety,
                                            const float* __restrict__ we, float* se){
  int e = blockIdx.x*256 + threadIdx.x;
  int l = blockIdx.y;
  if (e < EE){
    const float* w = we + (ety[e]*LL + l)*10;
    const float* ea = eattr + e*10;
    float s = 0.f;
    #pragma unroll
    for (int k = 0; k < 10; k++) s += ea[k]*w[k];
    se[(size_t)l*EE + e] = s;
  }
}

// all layers at once: sloop[l][i]
__global__ __launch_bounds__(256) void sloop_k(const int* __restrict__ off, const int* __restrict__ sorted,
                                               const float* __restrict__ se, float* sloop){
  int i = blockIdx.x*256 + threadIdx.x;
  int l = blockIdx.y;
  if (i < NN*T){
    int o0 = off[i], o1 = off[i+1];
    const float* sel = se + (size_t)l*EE;
    float s = 0.f;
    for (int j = o0; j < o1; j++) s += sel[sorted[j]];
    int dg = o1 - o0;
    sloop[(size_t)l*(NN*T) + i] = s / (float)(dg > 0 ? dg : 1);
  }
}

// R14: wave-per-(n,t) aggregation (zero barriers, shuffle softmax, deg<=64)
__global__ __launch_bounds__(256) void agg_k(const float* __restrict__ xl, const float* __restrict__ ssrc,
                                             const float* __restrict__ sdst, const float* __restrict__ se,
                                             const float* __restrict__ sloop, const int* __restrict__ off,
                                             const int* __restrict__ sorted, const int* __restrict__ srcv,
                                             const float* __restrict__ bias, float* __restrict__ hout, int l){
  int gid = blockIdx.x*4 + (threadIdx.x >> 6);   // over N*T, == n*T+t
  int lane = threadIdx.x & 63;
  int n = gid >> 2, t = gid & 3;                 // T==4
  int o0 = off[gid];
  int deg = off[gid+1] - o0;
  if (deg > 64) deg = 64;
  float sd = sdst[t*NN + n];
  float sc = -1e30f; int sj = 0;
  if (lane < deg){
    int e = sorted[o0 + lane];
    sj = srcv[e];
    sc = lrelu(ssrc[t*NN + sj] + sd + se[e]);
  }
  float al = lrelu(ssrc[t*NN + n] + sd + sloop[gid]);
  float mx = fmaxf(sc, al);
  #pragma unroll
  for (int o = 32; o > 0; o >>= 1) mx = fmaxf(mx, __shfl_xor(mx, o));
  float ex = (lane < deg) ? __expf(sc - mx) : 0.f;
  float ale = __expf(al - mx);
  float ssum = ex;
  #pragma unroll
  for (int o = 32; o > 0; o >>= 1) ssum += __shfl_xor(ssum, o);
  float inv = 1.f/(ssum + ale + 1e-16f);
  const float4* xl4 = (const float4*)xl;
  float4 acc = xl4[((size_t)(t*NN + n))*64 + lane];
  acc.x *= ale; acc.y *= ale; acc.z *= ale; acc.w *= ale;
  for (int j = 0; j < deg; j++){
    float p = __shfl(ex, j);
    int s = __shfl(sj, j);
    float4 v = xl4[((size_t)(t*NN + s))*64 + lane];
    acc.x += p*v.x; acc.y += p*v.y; acc.z += p*v.z; acc.w += p*v.w;
  }
  float4 b4 = *(const float4*)&bias[(t*LL + l)*C + lane*4];
  acc.x = eluf(acc.x*inv + b4.x); acc.y = eluf(acc.y*inv + b4.y);
  acc.z = eluf(acc.z*inv + b4.z); acc.w = eluf(acc.w*inv + b4.w);
  ((float4*)hout)[((size_t)(t*NN + n))*64 + lane] = acc;
}

// R16: fused hacc + colstats. 256 blocks x 16 rows; one atomic pair per thread.
__global__ __launch_bounds__(256) void hacccs_k(const float* __restrict__ h, const float* __restrict__ etw,
                                                float* __restrict__ hacc, float* meanp, float* maxp){
  int r0 = blockIdx.x*(NN/256), c = threadIdx.x;
  float e0 = etw[0], e1 = etw[1], e2 = etw[2], e3 = etw[3];
  float m = fmaxf(fmaxf(e0,e1), fmaxf(e2,e3));
  float w0 = __expf(e0-m), w1 = __expf(e1-m), w2 = __expf(e2-m), w3 = __expf(e3-m);
  float inv = 1.f/(w0+w1+w2+w3);
  float sm = 0.f, mx = -1e30f;
  for (int r = 0; r < NN/256; r++){
    int n = r0 + r;
    float s = (w0*h[(0*NN+n)*C+c] + w1*h[(1*NN+n)*C+c] + w2*h[(2*NN+n)*C+c] + w3*h[(3*NN+n)*C+c])*inv;
    hacc[(size_t)n*C + c] = s;
    sm += s; mx = fmaxf(mx, s);
  }
  atomicAdd(&meanp[c], sm*(1.f/4096.f));
  atomicMaxF(&maxp[c], mx);
}

// R12: multi-wave MFMA flash attention (4 waves/block, coop K/V^T stage,
// Q in registers, per-wave P buffer; 2 blocks/CU)
__global__ __launch_bounds__(256, 2) void attn_k(const float* __restrict__ qkv,
                                                 float* __restrict__ opart,
                                                 float* __restrict__ dpart){
  __shared__ __align__(16) _Float16 Ks[64*QKS];    // [m][k]
  __shared__ __align__(16) _Float16 VTs[64*QKS];   // [d][m]
  __shared__ __align__(16) _Float16 Ps[4][64*QKS]; // per-wave [n][m]
  int tid = threadIdx.x;
  int wave = tid >> 6, l = tid & 63;
  int nb = blockIdx.x*256 + wave*64;
  int h = blockIdx.y, mc = blockIdx.z;
  int r16 = l & 15, q = l >> 4;
  _Float16* Pw = Ps[wave];

  v8h qf[4][2];
  #pragma unroll
  for (int ni = 0; ni < 4; ni++){
    const float* qrow = qkv + (size_t)(nb + ni*16 + r16)*768 + h*64;
    #pragma unroll
    for (int kk = 0; kk < 2; kk++){
      float4 a = *(const float4*)(qrow + kk*32 + q*8);
      float4 b = *(const float4*)(qrow + kk*32 + q*8 + 4);
      v8h hv = {(_Float16)(a.x*0.125f), (_Float16)(a.y*0.125f),
                (_Float16)(a.z*0.125f), (_Float16)(a.w*0.125f),
                (_Float16)(b.x*0.125f), (_Float16)(b.y*0.125f),
                (_Float16)(b.z*0.125f), (_Float16)(b.w*0.125f)};
      qf[ni][kk] = hv;
    }
  }

  v4f o[4][4];
  #pragma unroll
  for (int i = 0; i < 4; i++)
    #pragma unroll
    for (int j = 0; j < 4; j++) o[i][j] = (v4f){0.f,0.f,0.f,0.f};
  float dn[4] = {0.f,0.f,0.f,0.f};

  for (int mt = 0; mt < NN/MCH/64; mt++){
    int mb = mc*(NN/MCH) + mt*64;
    __syncthreads();
    {
      int sr = tid >> 2, sc = (tid & 3)*16;
      const float* krow = qkv + (size_t)(mb + sr)*768 + 256 + h*64 + sc;
      float4 a = *(const float4*)(krow + 0);
      float4 b = *(const float4*)(krow + 4);
      float4 cc = *(const float4*)(krow + 8);
      float4 d = *(const float4*)(krow + 12);
      v8h h0 = {(_Float16)a.x, (_Float16)a.y, (_Float16)a.z, (_Float16)a.w,
                (_Float16)b.x, (_Float16)b.y, (_Float16)b.z, (_Float16)b.w};
      v8h h1 = {(_Float16)cc.x, (_Float16)cc.y, (_Float16)cc.z, (_Float16)cc.w,
                (_Float16)d.x, (_Float16)d.y, (_Float16)d.z, (_Float16)d.w};
      *(v8h*)(Ks + (size_t)sr*QKS + sc) = h0;
      *(v8h*)(Ks + (size_t)sr*QKS + sc + 8) = h1;
    }
    {
      int m0 = (tid & 31)*2;
      int db = (tid >> 5)*8;
      const float* v0 = qkv + (size_t)(mb + m0)*768 + 512 + h*64 + db;
      const float* v1 = v0 + 768;
      #pragma unroll
      for (int i = 0; i < 2; i++){
        float4 a = *(const float4*)(v0 + 4*i);
        float4 b = *(const float4*)(v1 + 4*i);
        int d = db + 4*i;
        *(unsigned*)(VTs + (size_t)(d+0)*QKS + m0) = pk2(a.x, b.x);
        *(unsigned*)(VTs + (size_t)(d+1)*QKS + m0) = pk2(a.y, b.y);
        *(unsigned*)(VTs + (size_t)(d+2)*QKS + m0) = pk2(a.z, b.z);
        *(unsigned*)(VTs + (size_t)(d+3)*QKS + m0) = pk2(a.w, b.w);
      }
    }
    __syncthreads();
    v4f c[4][4];
    #pragma unroll
    for (int i = 0; i < 4; i++)
      #pragma unroll
      for (int j = 0; j < 4; j++) c[i][j] = (v4f){0.f,0.f,0.f,0.f};
    #pragma unroll
    for (int kk = 0; kk < 2; kk++){
      v8h a[4];
      #pragma unroll
      for (int mi = 0; mi < 4; mi++) a[mi] = *(v8h*)(Ks + (size_t)(mi*16 + r16)*QKS + kk*32 + q*8);
      #pragma unroll
      for (int mi = 0; mi < 4; mi++)
        #pragma unroll
        for (int ni = 0; ni < 4; ni++)
          c[mi][ni] = __builtin_amdgcn_mfma_f32_16x16x32_f16(a[mi], qf[ni][kk], c[mi][ni], 0, 0, 0);
    }
    #pragma unroll
    for (int mi = 0; mi < 4; mi++)
      #pragma unroll
      for (int ni = 0; ni < 4; ni++){
        float e0 = __expf(c[mi][ni][0]), e1 = __expf(c[mi][ni][1]),
              e2 = __expf(c[mi][ni][2]), e3 = __expf(c[mi][ni][3]);
        dn[ni] += e0 + e1 + e2 + e3;
        *(uint2*)(Pw + (size_t)(ni*16 + r16)*QKS + mi*16 + q*4) = make_uint2(pk2(e0,e1), pk2(e2,e3));
      }
    #pragma unroll
    for (int km = 0; km < 2; km++){
      v8h pa[4], vb[4];
      #pragma unroll
      for (int ni = 0; ni < 4; ni++) pa[ni] = *(v8h*)(Pw + (size_t)(ni*16 + r16)*QKS + km*32 + q*8);
      #pragma unroll
      for (int di = 0; di < 4; di++) vb[di] = *(v8h*)(VTs + (size_t)(di*16 + r16)*QKS + km*32 + q*8);
      #pragma unroll
      for (int ni = 0; ni < 4; ni++)
        #pragma unroll
        for (int di = 0; di < 4; di++)
          o[ni][di] = __builtin_amdgcn_mfma_f32_16x16x32_f16(pa[ni], vb[di], o[ni][di], 0, 0, 0);
    }
  }

  float* ob = opart + ((size_t)mc*NN + nb)*C + h*64;
  #pragma unroll
  for (int ni = 0; ni < 4; ni++)
    #pragma unroll
    for (int di = 0; di < 4; di++)
      #pragma unroll
      for (int r = 0; r < 4; r++)
        ob[(size_t)(ni*16 + q*4 + r)*C + di*16 + r16] = o[ni][di][r];
  #pragma unroll
  for (int ni = 0; ni < 4; ni++){
    dn[ni] += __shfl_xor(dn[ni], 16);
    dn[ni] += __shfl_xor(dn[ni], 32);
  }
  if (q == 0){
    #pragma unroll
    for (int ni = 0; ni < 4; ni++)
      dpart[((size_t)mc*NN + nb + ni*16 + r16)*AHD + h] = dn[ni];
  }
}

__global__ __launch_bounds__(256) void attnred_k(const float* __restrict__ opart, const float* __restrict__ dpart,
                                                 float* omean){
  int r0 = blockIdx.x*(NN/256), c = threadIdx.x;
  int head = c >> 6;
  float s = 0.f;
  for (int r = 0; r < NN/256; r++){
    int n = r0 + r;
    float dsum = 0.f, osum = 0.f;
    #pragma unroll
    for (int mc = 0; mc < MCH; mc++){
      dsum += dpart[((size_t)mc*NN + n)*AHD + head];
      osum += opart[((size_t)mc*NN + n)*C + c];
    }
    s += osum / (dsum + 1e-16f);
  }
  atomicAdd(&omean[c], s*(1.f/4096.f));
}

// R16: fused tail: attnproj -> fus1 -> fus2 in one single-block kernel.
__global__ __launch_bounds__(512) void tail_k(const float* __restrict__ omean,
                                              const float* __restrict__ meanp, const float* __restrict__ maxp,
                                              const float* __restrict__ opw, const float* __restrict__ opb,
                                              const float* __restrict__ fw1, const float* __restrict__ fb1,
                                              const float* __restrict__ fw2, const float* __restrict__ fb2,
                                              float* __restrict__ out){
  __shared__ float sh[256];
  __shared__ float comb[768];
  __shared__ float g[512];
  int j = threadIdx.x;
  if (j < 256) sh[j] = omean[j];
  __syncthreads();
  if (j < 256){
    float acc = opb[j];
    for (int k = 0; k < 256; k++) acc += sh[k]*opw[j*256 + k];
    comb[512 + j] = acc;
    comb[j] = meanp[j];
    comb[256 + j] = maxp[j];
  }
  __syncthreads();
  {
    float acc = fb1[j];
    for (int k = 0; k < 768; k++) acc += comb[k]*fw1[k*512 + j];
    g[j] = fmaxf(acc, 0.f);
  }
  __syncthreads();
  if (j < 256){
    float acc = fb2[j];
    for (int k = 0; k < 512; k++) acc += g[k]*fw2[k*256 + j];
    out[j] = fmaxf(acc, 0.f);
  }
}

extern "C" void kernel_launch(void* const* d_in, const int* in_sizes, int n_in,
                              void* d_out, int out_size, void* d_ws, size_t ws_size,
                              hipStream_t stream){
  const float* x     = (const float*)d_in[0];
  const int*   srcv  = (const int*)d_in[1];
  const int*   dstv  = (const int*)d_in[2];
  const float* eattr = (const float*)d_in[3];
  const int*   etyp  = (const int*)d_in[4];
  const float* W0    = (const float*)d_in[5];
  const float* W12   = (const float*)d_in[6];
  const float* attS  = (const float*)d_in[7];
  const float* attD  = (const float*)d_in[8];
  const float* attE  = (const float*)d_in[9];
  const float* linE  = (const float*)d_in[10];
  const float* bias  = (const float*)d_in[11];
  const float* etw   = (const float*)d_in[12];
  const float* ipw   = (const float*)d_in[13];
  const float* ipb   = (const float*)d_in[14];
  const float* opw   = (const float*)d_in[15];
  const float* opb   = (const float*)d_in[16];
  const float* fw1   = (const float*)d_in[17];
  const float* fb1   = (const float*)d_in[18];
  const float* fw2   = (const float*)d_in[19];
  const float* fb2   = (const float*)d_in[20];
  float* out = (float*)d_out;

  if (ws_size < (size_t)WS_WORDS*4) return;

  int*       ip   = (int*)d_ws;
  float*     fp   = (float*)d_ws;
  _Float16*  ip16 = (_Float16*)(fp + F_WT);
  _Float16*  wpT  = (_Float16*)(fp + U_W12P);

  zero2_k<<<(NN*T + 255)/256, 256, 0, stream>>>(fp + F_MEANP, ip + W_CURSOR, NN*T);

  hist_k<<<EE/256, 256, 0, stream>>>(dstv, etyp, ip + W_CURSOR);
  scan_k<<<1, 1024, 0, stream>>>(ip + W_CURSOR, ip + W_OFF, ip + W_CURSOR);
  scatter_k<<<EE/256, 256, 0, stream>>>(dstv, etyp, ip + W_CURSOR, ip + W_SORTED);

  pack_k<<<dim3(256, 11), 256, 0, stream>>>(W12, wpT, ipw, ip16);

  we2_k<<<dim3(T, LL), 256, 0, stream>>>(linE, attE, fp + F_WE);
  se_k<<<dim3(EE/256, LL), 256, 0, stream>>>(eattr, etyp, fp + F_WE, fp + F_SE);
  sloop_k<<<dim3((NN*T)/256, LL), 256, 0, stream>>>(ip + W_OFF, ip + W_SORTED, fp + F_SE, fp + F_SLOOP);

  for (int l = 0; l < 3; l++){
    if (l == 0)
      gemm_k<<<dim3(NN/8, T), 256, 0, stream>>>(x, DIN, W0, (long)DIN*C, attS, attD, 0,
                                                fp + F_XL, fp + F_SSRC, fp + F_SDST);
    else
      gemm16m_k<<<dim3(NN/64, T), 256, 0, stream>>>(fp + F_H, wpT, attS, attD, l,
                                                    fp + F_XL, fp + F_SSRC, fp + F_SDST);
    agg_k<<<(NN*T)/4, 256, 0, stream>>>(fp + F_XL, fp + F_SSRC, fp + F_SDST,
                                        fp + F_SE + (size_t)l*EE,
                                        fp + F_SLOOP + (size_t)l*(NN*T),
                                        ip + W_OFF, ip + W_SORTED, srcv,
                                        bias, fp + F_H, l);
  }

  hacccs_k<<<256, 256, 0, stream>>>(fp + F_H, etw, fp + F_HACC, fp + F_MEANP, fp + F_MAXP);

  qkv16m_k<<<dim3(NN/64, 3), 256, 0, stream>>>(fp + F_HACC, ip16, ipb, fp + F_QKV);
  attn_k<<<dim3(NN/256, AHD, MCH), 256, 0, stream>>>(fp + F_QKV, fp + F_OPART, fp + F_DPART);
  attnred_k<<<256, 256, 0, stream>>>(fp + F_OPART, fp + F_DPART, fp + F_OMEAN);

  tail_k<<<1, 512, 0, stream>>>(fp + F_OMEAN, fp + F_MEANP, fp + F_MAXP,
                                opw, opb, fw1, fb1, fw2, fb2, out);
}

// Round 17
// 356.262 us; speedup vs baseline: 2.8292x; 1.0747x over previous
//
#include <hip/hip_runtime.h>
#include <math.h>

#define T 4
#define LL 3
#define C 256
#define DIN 20
#define NN 4096
#define EE 65536
#define AHD 4
#define MCH 8     // attention m-chunks (blockIdx.z); grid 16x4x8=512 blocks = 2/CU
#define QKS 72    // padded LDS row stride in halfs (64+8): +4 banks/row -> 2-way (free)
#define AST 264   // GEMM A-tile LDS row stride in halfs (256+8): 2-way (free)

// ---- workspace layout (4-byte word offsets) ----
#define W_OFF    0                    // int[N*T+1]
#define W_CURSOR 16640                // int[N*T]  (also hist counts)
#define W_SORTED 33024                // int[E]
#define F_XL     98560                // float[T][N][C]
#define F_H      (F_XL + T*NN*C)      // float[T][N][C]
#define F_OPART  F_XL                 // alias: float[MCH][N][C] == exactly F_XL+F_H extent (dead at attn time)
#define F_SSRC   (F_H + T*NN*C)       // float[T][N]
#define F_SDST   (F_SSRC + T*NN)      // float[T][N]
#define F_SE     (F_SDST + T*NN)      // float[LL][E]
#define F_SLOOP  (F_SE + LL*EE)       // float[LL][N*T] indexed l*NT + n*T+t
#define F_WE     (F_SLOOP + LL*T*NN)  // float[T*LL][10] (padded 128)
#define F_HACC   (F_WE + 128)         // float[N][C]
#define F_WT     (F_HACC + NN*C)      // f16[768][256] in_proj_w (region reserved 768*256 words)
#define F_QKV    (F_WT + 768*256)     // float[N][768]
#define F_DPART  (F_QKV + NN*768)     // float[MCH][N][AH]
#define F_MEANP  (F_DPART + MCH*NN*AHD) // float[C]
#define F_MAXP   (F_MEANP + C)        // float[C]
#define F_OMEAN  (F_MAXP + C)         // float[C]
#define F_ATTNP  (F_OMEAN + C)        // float[C]
#define F_G1     (F_ATTNP + C)        // float[512]  (atomic partial target, seeded with fb1)
#define U_W12P   (F_G1 + 512)         // f16[T*2][256 n][256 k] transposed W12
#define WS_WORDS (U_W12P + 262144)

static __device__ __forceinline__ float lrelu(float x){ return x > 0.f ? x : 0.2f*x; }
static __device__ __forceinline__ float eluf(float x){ return x > 0.f ? x : __expf(x) - 1.f; }

typedef _Float16 half2_t __attribute__((ext_vector_type(2)));
typedef _Float16 v8h __attribute__((ext_vector_type(8)));
typedef float v4f __attribute__((ext_vector_type(4)));

static __device__ __forceinline__ unsigned pk2(float x, float y){
  half2_t h; h.x = (_Float16)x; h.y = (_Float16)y;
  return __builtin_bit_cast(unsigned, h);
}

static __device__ inline void atomicMaxF(float* addr, float val){
  int* ai = (int*)addr;
  int old = __float_as_int(*addr);
  while (__int_as_float(old) < val){
    int assumed = old;
    old = atomicCAS(ai, assumed, __float_as_int(val));
    if (old == assumed) break;
  }
}

// fused init -- meanp=0, maxp=-1e30, omean=0, cursor=0
__global__ __launch_bounds__(256) void zero2_k(float* base /*F_MEANP*/, int* iz, int ni){
  int i = blockIdx.x*256 + threadIdx.x;
  if (i < 256) base[i] = 0.f;            // meanp
  else if (i < 512) base[i] = -1e30f;    // maxp
  else if (i < 768) base[i] = 0.f;       // omean
  if (i < ni) iz[i] = 0;
}

__global__ __launch_bounds__(256) void hist_k(const int* __restrict__ dst, const int* __restrict__ ety, int* cnt){
  int e = blockIdx.x*256 + threadIdx.x;
  if (e < EE) atomicAdd(&cnt[dst[e]*T + ety[e]], 1);
}

__global__ __launch_bounds__(1024) void scan_k(int* cnt, int* off, int* cursor){
  __shared__ int part[1024];
  int tid = threadIdx.x;
  int base = tid*16;
  int loc[16]; int s = 0;
  for (int i = 0; i < 16; i++){ loc[i] = cnt[base+i]; s += loc[i]; }
  part[tid] = s; __syncthreads();
  int v = s;
  for (int offn = 1; offn < 1024; offn <<= 1){
    int add = (tid >= offn) ? part[tid-offn] : 0;
    __syncthreads();
    v += add; part[tid] = v;
    __syncthreads();
  }
  int excl = v - s;
  for (int i = 0; i < 16; i++){ off[base+i] = excl; cursor[base+i] = excl; excl += loc[i]; }
  if (tid == 1023) off[NN*T] = excl;
}

__global__ __launch_bounds__(256) void scatter_k(const int* __restrict__ dst, const int* __restrict__ ety,
                                                 int* cursor, int* sorted){
  int e = blockIdx.x*256 + threadIdx.x;
  if (e < EE){
    int p = atomicAdd(&cursor[dst[e]*T + ety[e]], 1);
    sorted[p] = e;
  }
}

// fused weight packing. by<8: W12 [b][k][n] -> f16 [b][n][k]; by>=8: in_proj_w f16 copy.
__global__ __launch_bounds__(256) void pack_k(const float* __restrict__ w12, _Float16* __restrict__ wpT,
                                              const float* __restrict__ ipw, _Float16* __restrict__ ip16){
  int by = blockIdx.y, bx = blockIdx.x, tid = threadIdx.x;
  if (by < 8){
    wpT[((size_t)by*256 + bx)*256 + tid] = (_Float16)w12[((size_t)by*256 + tid)*256 + bx];
  } else {
    int j = (by - 8)*256 + bx;
    ip16[(size_t)j*256 + tid] = (_Float16)ipw[(size_t)j*256 + tid];
  }
}

// we[t][l][k] = sum_c lin_edge_w[t,l,k,c] * att_edge[t,l,0,c]
__global__ __launch_bounds__(256) void we2_k(const float* __restrict__ linE, const float* __restrict__ attE,
                                             float* we){
  int t = blockIdx.x, l = blockIdx.y, c = threadIdx.x;
  __shared__ float part[10*C];
  float ae = attE[(t*LL + l)*C + c];
  const float* lw = linE + (size_t)((t*LL + l)*10)*C;
  for (int k = 0; k < 10; k++) part[k*C + c] = lw[k*C + c]*ae;
  __syncthreads();
  if (c < 10){
    float s = 0.f;
    for (int i = 0; i < C; i++) s += part[c*C + i];
    we[(t*LL + l)*10 + c] = s;
  }
}

// layer 0 only (K=20, cheap): fp32 path, fused ssd reduction
__global__ __launch_bounds__(256) void gemm_k(const float* __restrict__ hin, int K,
                                              const float* __restrict__ Wb, long wtstr,
                                              const float* __restrict__ attS, const float* __restrict__ attD,
                                              int l, float* __restrict__ xlo,
                                              float* __restrict__ ssrc, float* __restrict__ sdst){
  int t = blockIdx.y;
  const float* h = hin;
  const float* W = Wb + (size_t)t*wtstr;
  int n0 = blockIdx.x*8;
  __shared__ float sh[8*256];
  __shared__ float red[64];
  for (int j = 0; j < 8; j++)
    for (int k = threadIdx.x; k < K; k += 256)
      sh[j*K + k] = h[(n0+j)*K + k];
  __syncthreads();
  float acc[8] = {0,0,0,0,0,0,0,0};
  int c = threadIdx.x;
  for (int k = 0; k < K; k += 4){
    float w0 = W[(k+0)*C + c], w1 = W[(k+1)*C + c], w2 = W[(k+2)*C + c], w3 = W[(k+3)*C + c];
    #pragma unroll
    for (int j = 0; j < 8; j++){
      float4 h4 = *(const float4*)&sh[j*K + k];
      acc[j] += w0*h4.x + w1*h4.y + w2*h4.z + w3*h4.w;
    }
  }
  #pragma unroll
  for (int j = 0; j < 8; j++) xlo[(t*NN + n0 + j)*C + c] = acc[j];
  float aS = attS[(t*LL + l)*C + c], aD = attD[(t*LL + l)*C + c];
  int lane = c & 63, w = c >> 6;
  #pragma unroll
  for (int j = 0; j < 8; j++){
    float v1 = acc[j]*aS, v2 = acc[j]*aD;
    #pragma unroll
    for (int off = 32; off > 0; off >>= 1){ v1 += __shfl_down(v1, off); v2 += __shfl_down(v2, off); }
    if (lane == 0){ red[j*8 + w] = v1; red[j*8 + 4 + w] = v2; }
  }
  __syncthreads();
  if (c < 16){
    int j = c >> 1, which = c & 1;
    const float* r = red + j*8 + which*4;
    float s = r[0] + r[1] + r[2] + r[3];
    (which ? sdst : ssrc)[t*NN + n0 + j] = s;
  }
}

// layers 1,2 as MFMA GEMM (4 waves x 64x64 tiles, fused ssd epilogue)
__global__ __launch_bounds__(256, 2) void gemm16m_k(const float* __restrict__ hin,
                                                    const _Float16* __restrict__ wpT,
                                                    const float* __restrict__ attS, const float* __restrict__ attD,
                                                    int l, float* __restrict__ xlo,
                                                    float* __restrict__ ssrc, float* __restrict__ sdst){
  __shared__ __align__(16) _Float16 As[64*AST];
  __shared__ float redS[4*64], redD[4*64];
  int t = blockIdx.y;
  int mb = blockIdx.x*64;
  int tid = threadIdx.x;
  int w = tid >> 6, lane = tid & 63;
  int r16 = lane & 15, q = lane >> 4;
  const float* h = hin + ((size_t)t*NN + mb)*C;
  {
    int sr = tid >> 2, sc = (tid & 3)*64;
    const float* hr = h + (size_t)sr*C + sc;
    #pragma unroll
    for (int i = 0; i < 8; i++){
      float4 a = *(const float4*)(hr + 8*i);
      float4 b = *(const float4*)(hr + 8*i + 4);
      v8h hv = {(_Float16)a.x,(_Float16)a.y,(_Float16)a.z,(_Float16)a.w,
                (_Float16)b.x,(_Float16)b.y,(_Float16)b.z,(_Float16)b.w};
      *(v8h*)(As + (size_t)sr*AST + sc + 8*i) = hv;
    }
  }
  __syncthreads();
  int cb = w*64;
  const _Float16* WB = wpT + ((size_t)((t*2 + (l-1))*256 + cb))*256;
  v4f o[4][4];
  #pragma unroll
  for (int i = 0; i < 4; i++)
    #pragma unroll
    for (int j = 0; j < 4; j++) o[i][j] = (v4f){0.f,0.f,0.f,0.f};
  #pragma unroll
  for (int kk = 0; kk < 8; kk++){
    v8h a[4], b[4];
    #pragma unroll
    for (int mi = 0; mi < 4; mi++) a[mi] = *(v8h*)(As + (size_t)(mi*16 + r16)*AST + kk*32 + q*8);
    #pragma unroll
    for (int ni = 0; ni < 4; ni++) b[ni] = *(const v8h*)(WB + (size_t)(ni*16 + r16)*256 + kk*32 + q*8);
    #pragma unroll
    for (int mi = 0; mi < 4; mi++)
      #pragma unroll
      for (int ni = 0; ni < 4; ni++)
        o[mi][ni] = __builtin_amdgcn_mfma_f32_16x16x32_f16(a[mi], b[ni], o[mi][ni], 0, 0, 0);
  }
  int tl = t*LL + l;
  float aS[4], aD[4];
  #pragma unroll
  for (int ni = 0; ni < 4; ni++){
    aS[ni] = attS[tl*C + cb + ni*16 + r16];
    aD[ni] = attD[tl*C + cb + ni*16 + r16];
  }
  #pragma unroll
  for (int mi = 0; mi < 4; mi++)
    #pragma unroll
    for (int rr = 0; rr < 4; rr++){
      int row = mb + mi*16 + q*4 + rr;
      float v1 = 0.f, v2 = 0.f;
      #pragma unroll
      for (int ni = 0; ni < 4; ni++){
        float ov = o[mi][ni][rr];
        xlo[((size_t)t*NN + row)*C + cb + ni*16 + r16] = ov;
        v1 += ov*aS[ni]; v2 += ov*aD[ni];
      }
      v1 += __shfl_xor(v1, 1); v2 += __shfl_xor(v2, 1);
      v1 += __shfl_xor(v1, 2); v2 += __shfl_xor(v2, 2);
      v1 += __shfl_xor(v1, 4); v2 += __shfl_xor(v2, 4);
      v1 += __shfl_xor(v1, 8); v2 += __shfl_xor(v2, 8);
      if (r16 == 0){
        redS[w*64 + mi*16 + q*4 + rr] = v1;
        redD[w*64 + mi*16 + q*4 + rr] = v2;
      }
    }
  __syncthreads();
  if (tid < 64)
    ssrc[t*NN + mb + tid] = redS[tid] + redS[64+tid] + redS[128+tid] + redS[192+tid];
  else if (tid < 128){
    int i = tid - 64;
    sdst[t*NN + mb + i] = redD[i] + redD[64+i] + redD[128+i] + redD[192+i];
  }
}

// qkv as MFMA GEMM
__global__ __launch_bounds__(256, 2) void qkv16m_k(const float* __restrict__ hacc,
                                                   const _Float16* __restrict__ ip16,
                                                   const float* __restrict__ ipb, float* __restrict__ qkv){
  __shared__ __align__(16) _Float16 As[64*AST];
  int p = blockIdx.y;
  int mb = blockIdx.x*64;
  int tid = threadIdx.x;
  int w = tid >> 6, lane = tid & 63;
  int r16 = lane & 15, q = lane >> 4;
  {
    int sr = tid >> 2, sc = (tid & 3)*64;
    const float* hr = hacc + ((size_t)(mb + sr))*C + sc;
    #pragma unroll
    for (int i = 0; i < 8; i++){
      float4 a = *(const float4*)(hr + 8*i);
      float4 b = *(const float4*)(hr + 8*i + 4);
      v8h hv = {(_Float16)a.x,(_Float16)a.y,(_Float16)a.z,(_Float16)a.w,
                (_Float16)b.x,(_Float16)b.y,(_Float16)b.z,(_Float16)b.w};
      *(v8h*)(As + (size_t)sr*AST + sc + 8*i) = hv;
    }
  }
  __syncthreads();
  int cb = p*256 + w*64;
  v4f o[4][4];
  #pragma unroll
  for (int i = 0; i < 4; i++)
    #pragma unroll
    for (int j = 0; j < 4; j++) o[i][j] = (v4f){0.f,0.f,0.f,0.f};
  #pragma unroll
  for (int kk = 0; kk < 8; kk++){
    v8h a[4], b[4];
    #pragma unroll
    for (int mi = 0; mi < 4; mi++) a[mi] = *(v8h*)(As + (size_t)(mi*16 + r16)*AST + kk*32 + q*8);
    #pragma unroll
    for (int ni = 0; ni < 4; ni++) b[ni] = *(const v8h*)(ip16 + (size_t)(cb + ni*16 + r16)*256 + kk*32 + q*8);
    #pragma unroll
    for (int mi = 0; mi < 4; mi++)
      #pragma unroll
      for (int ni = 0; ni < 4; ni++)
        o[mi][ni] = __builtin_amdgcn_mfma_f32_16x16x32_f16(a[mi], b[ni], o[mi][ni], 0, 0, 0);
  }
  float bn[4];
  #pragma unroll
  for (int ni = 0; ni < 4; ni++) bn[ni] = ipb[cb + ni*16 + r16];
  #pragma unroll
  for (int mi = 0; mi < 4; mi++)
    #pragma unroll
    for (int rr = 0; rr < 4; rr++){
      int row = mb + mi*16 + q*4 + rr;
      #pragma unroll
      for (int ni = 0; ni < 4; ni++)
        qkv[(size_t)row*768 + cb + ni*16 + r16] = o[mi][ni][rr] + bn[ni];
    }
}

// all layers at once: se[l][e]
__global__ __launch_bounds__(256) void se_k(const float* __restrict__ eattr, const int* __restrict__ ety,
                                            const float* __restrict__ we, float* se){
  int e = blockIdx.x*256 + threadIdx.x;
  int l = blockIdx.y;
  if (e < EE){
    const float* w = we + (ety[e]*LL + l)*10;
    const float* ea = eattr + e*10;
    float s = 0.f;
    #pragma unroll
    for (int k = 0; k < 10; k++) s += ea[k]*w[k];
    se[(size_t)l*EE + e] = s;
  }
}

// all layers at once: sloop[l][i]
__global__ __launch_bounds__(256) void sloop_k(const int* __restrict__ off, const int* __restrict__ sorted,
                                               const float* __restrict__ se, float* sloop){
  int i = blockIdx.x*256 + threadIdx.x;
  int l = blockIdx.y;
  if (i < NN*T){
    int o0 = off[i], o1 = off[i+1];
    const float* sel = se + (size_t)l*EE;
    float s = 0.f;
    for (int j = o0; j < o1; j++) s += sel[sorted[j]];
    int dg = o1 - o0;
    sloop[(size_t)l*(NN*T) + i] = s / (float)(dg > 0 ? dg : 1);
  }
}

// wave-per-(n,t) aggregation (zero barriers, shuffle softmax, deg<=64)
__global__ __launch_bounds__(256) void agg_k(const float* __restrict__ xl, const float* __restrict__ ssrc,
                                             const float* __restrict__ sdst, const float* __restrict__ se,
                                             const float* __restrict__ sloop, const int* __restrict__ off,
                                             const int* __restrict__ sorted, const int* __restrict__ srcv,
                                             const float* __restrict__ bias, float* __restrict__ hout, int l){
  int gid = blockIdx.x*4 + (threadIdx.x >> 6);   // over N*T, == n*T+t
  int lane = threadIdx.x & 63;
  int n = gid >> 2, t = gid & 3;                 // T==4
  int o0 = off[gid];
  int deg = off[gid+1] - o0;
  if (deg > 64) deg = 64;
  float sd = sdst[t*NN + n];
  float sc = -1e30f; int sj = 0;
  if (lane < deg){
    int e = sorted[o0 + lane];
    sj = srcv[e];
    sc = lrelu(ssrc[t*NN + sj] + sd + se[e]);
  }
  float al = lrelu(ssrc[t*NN + n] + sd + sloop[gid]);
  float mx = fmaxf(sc, al);
  #pragma unroll
  for (int o = 32; o > 0; o >>= 1) mx = fmaxf(mx, __shfl_xor(mx, o));
  float ex = (lane < deg) ? __expf(sc - mx) : 0.f;
  float ale = __expf(al - mx);
  float ssum = ex;
  #pragma unroll
  for (int o = 32; o > 0; o >>= 1) ssum += __shfl_xor(ssum, o);
  float inv = 1.f/(ssum + ale + 1e-16f);
  const float4* xl4 = (const float4*)xl;
  float4 acc = xl4[((size_t)(t*NN + n))*64 + lane];
  acc.x *= ale; acc.y *= ale; acc.z *= ale; acc.w *= ale;
  for (int j = 0; j < deg; j++){
    float p = __shfl(ex, j);
    int s = __shfl(sj, j);
    float4 v = xl4[((size_t)(t*NN + s))*64 + lane];
    acc.x += p*v.x; acc.y += p*v.y; acc.z += p*v.z; acc.w += p*v.w;
  }
  float4 b4 = *(const float4*)&bias[(t*LL + l)*C + lane*4];
  acc.x = eluf(acc.x*inv + b4.x); acc.y = eluf(acc.y*inv + b4.y);
  acc.z = eluf(acc.z*inv + b4.z); acc.w = eluf(acc.w*inv + b4.w);
  ((float4*)hout)[((size_t)(t*NN + n))*64 + lane] = acc;
}

// fused hacc + colstats
__global__ __launch_bounds__(256) void hacccs_k(const float* __restrict__ h, const float* __restrict__ etw,
                                                float* __restrict__ hacc, float* meanp, float* maxp){
  int r0 = blockIdx.x*(NN/256), c = threadIdx.x;
  float e0 = etw[0], e1 = etw[1], e2 = etw[2], e3 = etw[3];
  float m = fmaxf(fmaxf(e0,e1), fmaxf(e2,e3));
  float w0 = __expf(e0-m), w1 = __expf(e1-m), w2 = __expf(e2-m), w3 = __expf(e3-m);
  float inv = 1.f/(w0+w1+w2+w3);
  float sm = 0.f, mx = -1e30f;
  for (int r = 0; r < NN/256; r++){
    int n = r0 + r;
    float s = (w0*h[(0*NN+n)*C+c] + w1*h[(1*NN+n)*C+c] + w2*h[(2*NN+n)*C+c] + w3*h[(3*NN+n)*C+c])*inv;
    hacc[(size_t)n*C + c] = s;
    sm += s; mx = fmaxf(mx, s);
  }
  atomicAdd(&meanp[c], sm*(1.f/4096.f));
  atomicMaxF(&maxp[c], mx);
}

// multi-wave MFMA flash attention (4 waves/block, coop K/V^T stage,
// Q in registers, per-wave P buffer; 2 blocks/CU)
__global__ __launch_bounds__(256, 2) void attn_k(const float* __restrict__ qkv,
                                                 float* __restrict__ opart,
                                                 float* __restrict__ dpart){
  __shared__ __align__(16) _Float16 Ks[64*QKS];    // [m][k]
  __shared__ __align__(16) _Float16 VTs[64*QKS];   // [d][m]
  __shared__ __align__(16) _Float16 Ps[4][64*QKS]; // per-wave [n][m]
  int tid = threadIdx.x;
  int wave = tid >> 6, l = tid & 63;
  int nb = blockIdx.x*256 + wave*64;
  int h = blockIdx.y, mc = blockIdx.z;
  int r16 = l & 15, q = l >> 4;
  _Float16* Pw = Ps[wave];

  v8h qf[4][2];
  #pragma unroll
  for (int ni = 0; ni < 4; ni++){
    const float* qrow = qkv + (size_t)(nb + ni*16 + r16)*768 + h*64;
    #pragma unroll
    for (int kk = 0; kk < 2; kk++){
      float4 a = *(const float4*)(qrow + kk*32 + q*8);
      float4 b = *(const float4*)(qrow + kk*32 + q*8 + 4);
      v8h hv = {(_Float16)(a.x*0.125f), (_Float16)(a.y*0.125f),
                (_Float16)(a.z*0.125f), (_Float16)(a.w*0.125f),
                (_Float16)(b.x*0.125f), (_Float16)(b.y*0.125f),
                (_Float16)(b.z*0.125f), (_Float16)(b.w*0.125f)};
      qf[ni][kk] = hv;
    }
  }

  v4f o[4][4];
  #pragma unroll
  for (int i = 0; i < 4; i++)
    #pragma unroll
    for (int j = 0; j < 4; j++) o[i][j] = (v4f){0.f,0.f,0.f,0.f};
  float dn[4] = {0.f,0.f,0.f,0.f};

  for (int mt = 0; mt < NN/MCH/64; mt++){
    int mb = mc*(NN/MCH) + mt*64;
    __syncthreads();
    {
      int sr = tid >> 2, sc = (tid & 3)*16;
      const float* krow = qkv + (size_t)(mb + sr)*768 + 256 + h*64 + sc;
      float4 a = *(const float4*)(krow + 0);
      float4 b = *(const float4*)(krow + 4);
      float4 cc = *(const float4*)(krow + 8);
      float4 d = *(const float4*)(krow + 12);
      v8h h0 = {(_Float16)a.x, (_Float16)a.y, (_Float16)a.z, (_Float16)a.w,
                (_Float16)b.x, (_Float16)b.y, (_Float16)b.z, (_Float16)b.w};
      v8h h1 = {(_Float16)cc.x, (_Float16)cc.y, (_Float16)cc.z, (_Float16)cc.w,
                (_Float16)d.x, (_Float16)d.y, (_Float16)d.z, (_Float16)d.w};
      *(v8h*)(Ks + (size_t)sr*QKS + sc) = h0;
      *(v8h*)(Ks + (size_t)sr*QKS + sc + 8) = h1;
    }
    {
      int m0 = (tid & 31)*2;
      int db = (tid >> 5)*8;
      const float* v0 = qkv + (size_t)(mb + m0)*768 + 512 + h*64 + db;
      const float* v1 = v0 + 768;
      #pragma unroll
      for (int i = 0; i < 2; i++){
        float4 a = *(const float4*)(v0 + 4*i);
        float4 b = *(const float4*)(v1 + 4*i);
        int d = db + 4*i;
        *(unsigned*)(VTs + (size_t)(d+0)*QKS + m0) = pk2(a.x, b.x);
        *(unsigned*)(VTs + (size_t)(d+1)*QKS + m0) = pk2(a.y, b.y);
        *(unsigned*)(VTs + (size_t)(d+2)*QKS + m0) = pk2(a.z, b.z);
        *(unsigned*)(VTs + (size_t)(d+3)*QKS + m0) = pk2(a.w, b.w);
      }
    }
    __syncthreads();
    v4f c[4][4];
    #pragma unroll
    for (int i = 0; i < 4; i++)
      #pragma unroll
      for (int j = 0; j < 4; j++) c[i][j] = (v4f){0.f,0.f,0.f,0.f};
    #pragma unroll
    for (int kk = 0; kk < 2; kk++){
      v8h a[4];
      #pragma unroll
      for (int mi = 0; mi < 4; mi++) a[mi] = *(v8h*)(Ks + (size_t)(mi*16 + r16)*QKS + kk*32 + q*8);
      #pragma unroll
      for (int mi = 0; mi < 4; mi++)
        #pragma unroll
        for (int ni = 0; ni < 4; ni++)
          c[mi][ni] = __builtin_amdgcn_mfma_f32_16x16x32_f16(a[mi], qf[ni][kk], c[mi][ni], 0, 0, 0);
    }
    #pragma unroll
    for (int mi = 0; mi < 4; mi++)
      #pragma unroll
      for (int ni = 0; ni < 4; ni++){
        float e0 = __expf(c[mi][ni][0]), e1 = __expf(c[mi][ni][1]),
              e2 = __expf(c[mi][ni][2]), e3 = __expf(c[mi][ni][3]);
        dn[ni] += e0 + e1 + e2 + e3;
        *(uint2*)(Pw + (size_t)(ni*16 + r16)*QKS + mi*16 + q*4) = make_uint2(pk2(e0,e1), pk2(e2,e3));
      }
    #pragma unroll
    for (int km = 0; km < 2; km++){
      v8h pa[4], vb[4];
      #pragma unroll
      for (int ni = 0; ni < 4; ni++) pa[ni] = *(v8h*)(Pw + (size_t)(ni*16 + r16)*QKS + km*32 + q*8);
      #pragma unroll
      for (int di = 0; di < 4; di++) vb[di] = *(v8h*)(VTs + (size_t)(di*16 + r16)*QKS + km*32 + q*8);
      #pragma unroll
      for (int ni = 0; ni < 4; ni++)
        #pragma unroll
        for (int di = 0; di < 4; di++)
          o[ni][di] = __builtin_amdgcn_mfma_f32_16x16x32_f16(pa[ni], vb[di], o[ni][di], 0, 0, 0);
    }
  }

  float* ob = opart + ((size_t)mc*NN + nb)*C + h*64;
  #pragma unroll
  for (int ni = 0; ni < 4; ni++)
    #pragma unroll
    for (int di = 0; di < 4; di++)
      #pragma unroll
      for (int r = 0; r < 4; r++)
        ob[(size_t)(ni*16 + q*4 + r)*C + di*16 + r16] = o[ni][di][r];
  #pragma unroll
  for (int ni = 0; ni < 4; ni++){
    dn[ni] += __shfl_xor(dn[ni], 16);
    dn[ni] += __shfl_xor(dn[ni], 32);
  }
  if (q == 0){
    #pragma unroll
    for (int ni = 0; ni < 4; ni++)
      dpart[((size_t)mc*NN + nb + ni*16 + r16)*AHD + h] = dn[ni];
  }
}

__global__ __launch_bounds__(256) void attnred_k(const float* __restrict__ opart, const float* __restrict__ dpart,
                                                 float* omean){
  int r0 = blockIdx.x*(NN/256), c = threadIdx.x;
  int head = c >> 6;
  float s = 0.f;
  for (int r = 0; r < NN/256; r++){
    int n = r0 + r;
    float dsum = 0.f, osum = 0.f;
    #pragma unroll
    for (int mc = 0; mc < MCH; mc++){
      dsum += dpart[((size_t)mc*NN + n)*AHD + head];
      osum += opart[((size_t)mc*NN + n)*C + c];
    }
    s += osum / (dsum + 1e-16f);
  }
  atomicAdd(&omean[c], s*(1.f/4096.f));
}

// R17a: attnp over 16 blocks x 16 cols (16-lane shuffle dots); seeds g1 = fb1.
// (R16 post-mortem: single-block tail read 2.2MB cold weights at ~20 GB/s
// -> 55-62us latency-bound. Same fix as R13: spread reads over blocks.)
__global__ __launch_bounds__(256) void taila_k(const float* __restrict__ omean, const float* __restrict__ opw,
                                               const float* __restrict__ opb, const float* __restrict__ fb1,
                                               float* attnp, float* g1){
  __shared__ float sh[256];
  int tid = threadIdx.x;
  sh[tid] = omean[tid];
  __syncthreads();
  int jj = tid >> 4, kk = tid & 15;
  int j = blockIdx.x*16 + jj;
  float acc = 0.f;
  #pragma unroll
  for (int i = 0; i < 16; i++){
    int k = kk*16 + i;
    acc += sh[k]*opw[(size_t)j*256 + k];
  }
  acc += __shfl_xor(acc, 1); acc += __shfl_xor(acc, 2);
  acc += __shfl_xor(acc, 4); acc += __shfl_xor(acc, 8);
  if (kk == 0) attnp[j] = acc + opb[j];
  if (blockIdx.x < 2) g1[blockIdx.x*256 + tid] = fb1[blockIdx.x*256 + tid];
}

// R17b: fus1 k-split partials: 16 blocks x 48 k-rows, coalesced fw1 reads,
// atomicAdd onto g1 (seeded with fb1 by taila).
__global__ __launch_bounds__(512) void tailb_k(const float* __restrict__ meanp, const float* __restrict__ maxp,
                                               const float* __restrict__ attnp, const float* __restrict__ fw1,
                                               float* g1){
  __shared__ float comb[48];
  int b = blockIdx.x, tid = threadIdx.x;
  if (tid < 48){
    int k = b*48 + tid;
    comb[tid] = (k < 256) ? meanp[k] : (k < 512 ? maxp[k-256] : attnp[k-512]);
  }
  __syncthreads();
  float acc = 0.f;
  #pragma unroll 4
  for (int i = 0; i < 48; i++)
    acc += comb[i]*fw1[((size_t)(b*48 + i))*512 + tid];
  atomicAdd(&g1[tid], acc);
}

// R17c: fus2: 8 blocks x 32 cols; relu(g1) applied on load, final relu on store.
__global__ __launch_bounds__(256) void tailc_k(const float* __restrict__ g1, const float* __restrict__ fw2,
                                               const float* __restrict__ fb2, float* __restrict__ out){
  __shared__ float g[512];
  __shared__ float red[256];
  int tid = threadIdx.x;
  g[tid] = fmaxf(g1[tid], 0.f);
  g[tid + 256] = fmaxf(g1[tid + 256], 0.f);
  __syncthreads();
  int j = blockIdx.x*32 + (tid & 31);
  int kp = tid >> 5;                     // 8 k-parts x 64
  float acc = 0.f;
  #pragma unroll 4
  for (int i = 0; i < 64; i++){
    int k = kp*64 + i;
    acc += g[k]*fw2[(size_t)k*256 + j];
  }
  red[tid] = acc;
  __syncthreads();
  if (tid < 32){
    float s = 0.f;
    #pragma unroll
    for (int p = 0; p < 8; p++) s += red[p*32 + tid];
    out[j] = fmaxf(s + fb2[j], 0.f);
  }
}

extern "C" void kernel_launch(void* const* d_in, const int* in_sizes, int n_in,
                              void* d_out, int out_size, void* d_ws, size_t ws_size,
                              hipStream_t stream){
  const float* x     = (const float*)d_in[0];
  const int*   srcv  = (const int*)d_in[1];
  const int*   dstv  = (const int*)d_in[2];
  const float* eattr = (const float*)d_in[3];
  const int*   etyp  = (const int*)d_in[4];
  const float* W0    = (const float*)d_in[5];
  const float* W12   = (const float*)d_in[6];
  const float* attS  = (const float*)d_in[7];
  const float* attD  = (const float*)d_in[8];
  const float* attE  = (const float*)d_in[9];
  const float* linE  = (const float*)d_in[10];
  const float* bias  = (const float*)d_in[11];
  const float* etw   = (const float*)d_in[12];
  const float* ipw   = (const float*)d_in[13];
  const float* ipb   = (const float*)d_in[14];
  const float* opw   = (const float*)d_in[15];
  const float* opb   = (const float*)d_in[16];
  const float* fw1   = (const float*)d_in[17];
  const float* fb1   = (const float*)d_in[18];
  const float* fw2   = (const float*)d_in[19];
  const float* fb2   = (const float*)d_in[20];
  float* out = (float*)d_out;

  if (ws_size < (size_t)WS_WORDS*4) return;

  int*       ip   = (int*)d_ws;
  float*     fp   = (float*)d_ws;
  _Float16*  ip16 = (_Float16*)(fp + F_WT);
  _Float16*  wpT  = (_Float16*)(fp + U_W12P);

  zero2_k<<<(NN*T + 255)/256, 256, 0, stream>>>(fp + F_MEANP, ip + W_CURSOR, NN*T);

  hist_k<<<EE/256, 256, 0, stream>>>(dstv, etyp, ip + W_CURSOR);
  scan_k<<<1, 1024, 0, stream>>>(ip + W_CURSOR, ip + W_OFF, ip + W_CURSOR);
  scatter_k<<<EE/256, 256, 0, stream>>>(dstv, etyp, ip + W_CURSOR, ip + W_SORTED);

  pack_k<<<dim3(256, 11), 256, 0, stream>>>(W12, wpT, ipw, ip16);

  we2_k<<<dim3(T, LL), 256, 0, stream>>>(linE, attE, fp + F_WE);
  se_k<<<dim3(EE/256, LL), 256, 0, stream>>>(eattr, etyp, fp + F_WE, fp + F_SE);
  sloop_k<<<dim3((NN*T)/256, LL), 256, 0, stream>>>(ip + W_OFF, ip + W_SORTED, fp + F_SE, fp + F_SLOOP);

  for (int l = 0; l < 3; l++){
    if (l == 0)
      gemm_k<<<dim3(NN/8, T), 256, 0, stream>>>(x, DIN, W0, (long)DIN*C, attS, attD, 0,
                                                fp + F_XL, fp + F_SSRC, fp + F_SDST);
    else
      gemm16m_k<<<dim3(NN/64, T), 256, 0, stream>>>(fp + F_H, wpT, attS, attD, l,
                                                    fp + F_XL, fp + F_SSRC, fp + F_SDST);
    agg_k<<<(NN*T)/4, 256, 0, stream>>>(fp + F_XL, fp + F_SSRC, fp + F_SDST,
                                        fp + F_SE + (size_t)l*EE,
                                        fp + F_SLOOP + (size_t)l*(NN*T),
                                        ip + W_OFF, ip + W_SORTED, srcv,
                                        bias, fp + F_H, l);
  }

  hacccs_k<<<256, 256, 0, stream>>>(fp + F_H, etw, fp + F_HACC, fp + F_MEANP, fp + F_MAXP);

  qkv16m_k<<<dim3(NN/64, 3), 256, 0, stream>>>(fp + F_HACC, ip16, ipb, fp + F_QKV);
  attn_k<<<dim3(NN/256, AHD, MCH), 256, 0, stream>>>(fp + F_QKV, fp + F_OPART, fp + F_DPART);
  attnred_k<<<256, 256, 0, stream>>>(fp + F_OPART, fp + F_DPART, fp + F_OMEAN);

  taila_k<<<16, 256, 0, stream>>>(fp + F_OMEAN, opw, opb, fb1, fp + F_ATTNP, fp + F_G1);
  tailb_k<<<16, 512, 0, stream>>>(fp + F_MEANP, fp + F_MAXP, fp + F_ATTNP, fw1, fp + F_G1);
  tailc_k<<<8, 256, 0, stream>>>(fp + F_G1, fw2, fb2, out);
}

// Round 18
// 344.773 us; speedup vs baseline: 2.9235x; 1.0333x over previous
//
#include <hip/hip_runtime.h>
#include <math.h>

#define T 4
#define LL 3
#define C 256
#define DIN 20
#define NN 4096
#define EE 65536
#define AHD 4
#define MCH 8     // attention m-chunks (blockIdx.z); grid 16x4x8=512 blocks = 2/CU
#define QKS 72    // padded LDS row stride in halfs (64+8): +4 banks/row -> 2-way (free)
#define AST 264   // GEMM A-tile LDS row stride in halfs (256+8): 2-way (free)

// ---- workspace layout (4-byte word offsets) ----
#define W_OFF    0                    // int[N*T+1]
#define W_CURSOR 16640                // int[N*T]  (also hist counts)
#define W_SORTED 33024                // int[E]
#define F_XL     98560                // float[T][N][C]
#define F_H      (F_XL + T*NN*C)      // float[T][N][C]
#define F_OPART  F_XL                 // alias: float[MCH][N][C] == exactly F_XL+F_H extent (dead at attn time)
#define F_SSRC   (F_H + T*NN*C)       // float[T][N]
#define F_SDST   (F_SSRC + T*NN)      // float[T][N]
#define F_SE     (F_SDST + T*NN)      // (unused since R18 -- se computed in agg)
#define F_SLOOP  (F_SE + LL*EE)       // (unused since R18)
#define F_WE     (F_SLOOP + LL*T*NN)  // float[T*LL][10] (padded 128)
#define F_HACC   (F_WE + 128)         // float[N][C]
#define F_WT     (F_HACC + NN*C)      // f16[768][256] in_proj_w (region reserved 768*256 words)
#define F_QKV    (F_WT + 768*256)     // float[N][768]
#define F_DPART  (F_QKV + NN*768)     // float[MCH][N][AH]
#define F_MEANP  (F_DPART + MCH*NN*AHD) // float[C]
#define F_MAXP   (F_MEANP + C)        // float[C]
#define F_OMEAN  (F_MAXP + C)         // float[C]
#define F_ATTNP  (F_OMEAN + C)        // float[C]
#define F_G1     (F_ATTNP + C)        // float[512]  (atomic partial target, seeded with fb1)
#define U_W12P   (F_G1 + 512)         // f16[T*2][256 n][256 k] transposed W12
#define WS_WORDS (U_W12P + 262144)

static __device__ __forceinline__ float lrelu(float x){ return x > 0.f ? x : 0.2f*x; }
static __device__ __forceinline__ float eluf(float x){ return x > 0.f ? x : __expf(x) - 1.f; }

typedef _Float16 half2_t __attribute__((ext_vector_type(2)));
typedef _Float16 v8h __attribute__((ext_vector_type(8)));
typedef float v4f __attribute__((ext_vector_type(4)));

static __device__ __forceinline__ unsigned pk2(float x, float y){
  half2_t h; h.x = (_Float16)x; h.y = (_Float16)y;
  return __builtin_bit_cast(unsigned, h);
}

static __device__ inline void atomicMaxF(float* addr, float val){
  int* ai = (int*)addr;
  int old = __float_as_int(*addr);
  while (__int_as_float(old) < val){
    int assumed = old;
    old = atomicCAS(ai, assumed, __float_as_int(val));
    if (old == assumed) break;
  }
}

__global__ __launch_bounds__(256) void hist_k(const int* __restrict__ dst, const int* __restrict__ ety, int* cnt){
  int e = blockIdx.x*256 + threadIdx.x;
  if (e < EE) atomicAdd(&cnt[dst[e]*T + ety[e]], 1);
}

__global__ __launch_bounds__(1024) void scan_k(int* cnt, int* off, int* cursor){
  __shared__ int part[1024];
  int tid = threadIdx.x;
  int base = tid*16;
  int loc[16]; int s = 0;
  for (int i = 0; i < 16; i++){ loc[i] = cnt[base+i]; s += loc[i]; }
  part[tid] = s; __syncthreads();
  int v = s;
  for (int offn = 1; offn < 1024; offn <<= 1){
    int add = (tid >= offn) ? part[tid-offn] : 0;
    __syncthreads();
    v += add; part[tid] = v;
    __syncthreads();
  }
  int excl = v - s;
  for (int i = 0; i < 16; i++){ off[base+i] = excl; cursor[base+i] = excl; excl += loc[i]; }
  if (tid == 1023) off[NN*T] = excl;
}

__global__ __launch_bounds__(256) void scatter_k(const int* __restrict__ dst, const int* __restrict__ ety,
                                                 int* cursor, int* sorted){
  int e = blockIdx.x*256 + threadIdx.x;
  if (e < EE){
    int p = atomicAdd(&cursor[dst[e]*T + ety[e]], 1);
    sorted[p] = e;
  }
}

// R18: mega-pack. by<8: W12 [b][k][n] -> f16 [b][n][k]; by in [8,11): in_proj_w
// f16 copy; by==11: bx<12 = we2 blocks, bx==12 = meanp/maxp/omean init,
// bx in [64,128) = cursor zeroing. (R17 post-mortem: pipeline dispatch-bound;
// folds zero2_k and we2_k into pack's idle grid space -> -2 dispatches.)
__global__ __launch_bounds__(256) void pack_k(const float* __restrict__ w12, _Float16* __restrict__ wpT,
                                              const float* __restrict__ ipw, _Float16* __restrict__ ip16,
                                              const float* __restrict__ linE, const float* __restrict__ attE,
                                              float* we, float* fbase, int* cursor){
  __shared__ float part[10*C];
  int by = blockIdx.y, bx = blockIdx.x, tid = threadIdx.x;
  if (by < 8){
    wpT[((size_t)by*256 + bx)*256 + tid] = (_Float16)w12[((size_t)by*256 + tid)*256 + bx];
  } else if (by < 11){
    int j = (by - 8)*256 + bx;
    ip16[(size_t)j*256 + tid] = (_Float16)ipw[(size_t)j*256 + tid];
  } else {
    if (bx < 12){
      int t = bx / 3, l = bx % 3;
      float ae = attE[(t*LL + l)*C + tid];
      const float* lw = linE + (size_t)((t*LL + l)*10)*C;
      for (int k = 0; k < 10; k++) part[k*C + tid] = lw[k*C + tid]*ae;
      __syncthreads();
      if (tid < 10){
        float s = 0.f;
        for (int i = 0; i < C; i++) s += part[tid*C + i];
        we[(t*LL + l)*10 + tid] = s;
      }
    } else if (bx == 12){
      fbase[tid] = 0.f;            // meanp
      fbase[256 + tid] = -1e30f;   // maxp
      fbase[512 + tid] = 0.f;      // omean
    } else if (bx >= 64 && bx < 128){
      cursor[(bx - 64)*256 + tid] = 0;
    }
  }
}

// layer 0 only (K=20, cheap): fp32 path, fused ssd reduction
__global__ __launch_bounds__(256) void gemm_k(const float* __restrict__ hin, int K,
                                              const float* __restrict__ Wb, long wtstr,
                                              const float* __restrict__ attS, const float* __restrict__ attD,
                                              int l, float* __restrict__ xlo,
                                              float* __restrict__ ssrc, float* __restrict__ sdst){
  int t = blockIdx.y;
  const float* h = hin;
  const float* W = Wb + (size_t)t*wtstr;
  int n0 = blockIdx.x*8;
  __shared__ float sh[8*256];
  __shared__ float red[64];
  for (int j = 0; j < 8; j++)
    for (int k = threadIdx.x; k < K; k += 256)
      sh[j*K + k] = h[(n0+j)*K + k];
  __syncthreads();
  float acc[8] = {0,0,0,0,0,0,0,0};
  int c = threadIdx.x;
  for (int k = 0; k < K; k += 4){
    float w0 = W[(k+0)*C + c], w1 = W[(k+1)*C + c], w2 = W[(k+2)*C + c], w3 = W[(k+3)*C + c];
    #pragma unroll
    for (int j = 0; j < 8; j++){
      float4 h4 = *(const float4*)&sh[j*K + k];
      acc[j] += w0*h4.x + w1*h4.y + w2*h4.z + w3*h4.w;
    }
  }
  #pragma unroll
  for (int j = 0; j < 8; j++) xlo[(t*NN + n0 + j)*C + c] = acc[j];
  float aS = attS[(t*LL + l)*C + c], aD = attD[(t*LL + l)*C + c];
  int lane = c & 63, w = c >> 6;
  #pragma unroll
  for (int j = 0; j < 8; j++){
    float v1 = acc[j]*aS, v2 = acc[j]*aD;
    #pragma unroll
    for (int off = 32; off > 0; off >>= 1){ v1 += __shfl_down(v1, off); v2 += __shfl_down(v2, off); }
    if (lane == 0){ red[j*8 + w] = v1; red[j*8 + 4 + w] = v2; }
  }
  __syncthreads();
  if (c < 16){
    int j = c >> 1, which = c & 1;
    const float* r = red + j*8 + which*4;
    float s = r[0] + r[1] + r[2] + r[3];
    (which ? sdst : ssrc)[t*NN + n0 + j] = s;
  }
}

// layers 1,2 as MFMA GEMM (4 waves x 64x64 tiles, fused ssd epilogue)
__global__ __launch_bounds__(256, 2) void gemm16m_k(const float* __restrict__ hin,
                                                    const _Float16* __restrict__ wpT,
                                                    const float* __restrict__ attS, const float* __restrict__ attD,
                                                    int l, float* __restrict__ xlo,
                                                    float* __restrict__ ssrc, float* __restrict__ sdst){
  __shared__ __align__(16) _Float16 As[64*AST];
  __shared__ float redS[4*64], redD[4*64];
  int t = blockIdx.y;
  int mb = blockIdx.x*64;
  int tid = threadIdx.x;
  int w = tid >> 6, lane = tid & 63;
  int r16 = lane & 15, q = lane >> 4;
  const float* h = hin + ((size_t)t*NN + mb)*C;
  {
    int sr = tid >> 2, sc = (tid & 3)*64;
    const float* hr = h + (size_t)sr*C + sc;
    #pragma unroll
    for (int i = 0; i < 8; i++){
      float4 a = *(const float4*)(hr + 8*i);
      float4 b = *(const float4*)(hr + 8*i + 4);
      v8h hv = {(_Float16)a.x,(_Float16)a.y,(_Float16)a.z,(_Float16)a.w,
                (_Float16)b.x,(_Float16)b.y,(_Float16)b.z,(_Float16)b.w};
      *(v8h*)(As + (size_t)sr*AST + sc + 8*i) = hv;
    }
  }
  __syncthreads();
  int cb = w*64;
  const _Float16* WB = wpT + ((size_t)((t*2 + (l-1))*256 + cb))*256;
  v4f o[4][4];
  #pragma unroll
  for (int i = 0; i < 4; i++)
    #pragma unroll
    for (int j = 0; j < 4; j++) o[i][j] = (v4f){0.f,0.f,0.f,0.f};
  #pragma unroll
  for (int kk = 0; kk < 8; kk++){
    v8h a[4], b[4];
    #pragma unroll
    for (int mi = 0; mi < 4; mi++) a[mi] = *(v8h*)(As + (size_t)(mi*16 + r16)*AST + kk*32 + q*8);
    #pragma unroll
    for (int ni = 0; ni < 4; ni++) b[ni] = *(const v8h*)(WB + (size_t)(ni*16 + r16)*256 + kk*32 + q*8);
    #pragma unroll
    for (int mi = 0; mi < 4; mi++)
      #pragma unroll
      for (int ni = 0; ni < 4; ni++)
        o[mi][ni] = __builtin_amdgcn_mfma_f32_16x16x32_f16(a[mi], b[ni], o[mi][ni], 0, 0, 0);
  }
  int tl = t*LL + l;
  float aS[4], aD[4];
  #pragma unroll
  for (int ni = 0; ni < 4; ni++){
    aS[ni] = attS[tl*C + cb + ni*16 + r16];
    aD[ni] = attD[tl*C + cb + ni*16 + r16];
  }
  #pragma unroll
  for (int mi = 0; mi < 4; mi++)
    #pragma unroll
    for (int rr = 0; rr < 4; rr++){
      int row = mb + mi*16 + q*4 + rr;
      float v1 = 0.f, v2 = 0.f;
      #pragma unroll
      for (int ni = 0; ni < 4; ni++){
        float ov = o[mi][ni][rr];
        xlo[((size_t)t*NN + row)*C + cb + ni*16 + r16] = ov;
        v1 += ov*aS[ni]; v2 += ov*aD[ni];
      }
      v1 += __shfl_xor(v1, 1); v2 += __shfl_xor(v2, 1);
      v1 += __shfl_xor(v1, 2); v2 += __shfl_xor(v2, 2);
      v1 += __shfl_xor(v1, 4); v2 += __shfl_xor(v2, 4);
      v1 += __shfl_xor(v1, 8); v2 += __shfl_xor(v2, 8);
      if (r16 == 0){
        redS[w*64 + mi*16 + q*4 + rr] = v1;
        redD[w*64 + mi*16 + q*4 + rr] = v2;
      }
    }
  __syncthreads();
  if (tid < 64)
    ssrc[t*NN + mb + tid] = redS[tid] + redS[64+tid] + redS[128+tid] + redS[192+tid];
  else if (tid < 128){
    int i = tid - 64;
    sdst[t*NN + mb + i] = redD[i] + redD[64+i] + redD[128+i] + redD[192+i];
  }
}

// qkv as MFMA GEMM
__global__ __launch_bounds__(256, 2) void qkv16m_k(const float* __restrict__ hacc,
                                                   const _Float16* __restrict__ ip16,
                                                   const float* __restrict__ ipb, float* __restrict__ qkv){
  __shared__ __align__(16) _Float16 As[64*AST];
  int p = blockIdx.y;
  int mb = blockIdx.x*64;
  int tid = threadIdx.x;
  int w = tid >> 6, lane = tid & 63;
  int r16 = lane & 15, q = lane >> 4;
  {
    int sr = tid >> 2, sc = (tid & 3)*64;
    const float* hr = hacc + ((size_t)(mb + sr))*C + sc;
    #pragma unroll
    for (int i = 0; i < 8; i++){
      float4 a = *(const float4*)(hr + 8*i);
      float4 b = *(const float4*)(hr + 8*i + 4);
      v8h hv = {(_Float16)a.x,(_Float16)a.y,(_Float16)a.z,(_Float16)a.w,
                (_Float16)b.x,(_Float16)b.y,(_Float16)b.z,(_Float16)b.w};
      *(v8h*)(As + (size_t)sr*AST + sc + 8*i) = hv;
    }
  }
  __syncthreads();
  int cb = p*256 + w*64;
  v4f o[4][4];
  #pragma unroll
  for (int i = 0; i < 4; i++)
    #pragma unroll
    for (int j = 0; j < 4; j++) o[i][j] = (v4f){0.f,0.f,0.f,0.f};
  #pragma unroll
  for (int kk = 0; kk < 8; kk++){
    v8h a[4], b[4];
    #pragma unroll
    for (int mi = 0; mi < 4; mi++) a[mi] = *(v8h*)(As + (size_t)(mi*16 + r16)*AST + kk*32 + q*8);
    #pragma unroll
    for (int ni = 0; ni < 4; ni++) b[ni] = *(const v8h*)(ip16 + (size_t)(cb + ni*16 + r16)*256 + kk*32 + q*8);
    #pragma unroll
    for (int mi = 0; mi < 4; mi++)
      #pragma unroll
      for (int ni = 0; ni < 4; ni++)
        o[mi][ni] = __builtin_amdgcn_mfma_f32_16x16x32_f16(a[mi], b[ni], o[mi][ni], 0, 0, 0);
  }
  float bn[4];
  #pragma unroll
  for (int ni = 0; ni < 4; ni++) bn[ni] = ipb[cb + ni*16 + r16];
  #pragma unroll
  for (int mi = 0; mi < 4; mi++)
    #pragma unroll
    for (int rr = 0; rr < 4; rr++){
      int row = mb + mi*16 + q*4 + rr;
      #pragma unroll
      for (int ni = 0; ni < 4; ni++)
        qkv[(size_t)row*768 + cb + ni*16 + r16] = o[mi][ni][rr] + bn[ni];
    }
}

// R18: wave-per-(n,t) aggregation with INLINE se/sloop (kills se_k+sloop_k):
// bucket edges all share type t -> we[t][l][0..10) is wave-uniform (s_load);
// per-lane se = dot10(eattr row, we); sloop = wave-mean of se.
__global__ __launch_bounds__(256) void agg_k(const float* __restrict__ xl, const float* __restrict__ ssrc,
                                             const float* __restrict__ sdst, const float* __restrict__ we,
                                             const float* __restrict__ eattr, const int* __restrict__ off,
                                             const int* __restrict__ sorted, const int* __restrict__ srcv,
                                             const float* __restrict__ bias, float* __restrict__ hout, int l){
  int gid = blockIdx.x*4 + (threadIdx.x >> 6);   // over N*T, == n*T+t
  int lane = threadIdx.x & 63;
  int n = gid >> 2, t = gid & 3;                 // T==4
  int o0 = off[gid];
  int deg = off[gid+1] - o0;
  if (deg > 64) deg = 64;
  const float* w = we + (t*LL + l)*10;           // wave-uniform
  float sd = sdst[t*NN + n];
  float se_e = 0.f; int sj = 0;
  if (lane < deg){
    int e = sorted[o0 + lane];
    sj = srcv[e];
    const float* ea = eattr + (size_t)e*10;
    #pragma unroll
    for (int k = 0; k < 10; k++) se_e += ea[k]*w[k];
  }
  // sloop = mean of se over incoming edges (inactive lanes contribute 0)
  float ssum_se = se_e;
  #pragma unroll
  for (int o = 32; o > 0; o >>= 1) ssum_se += __shfl_xor(ssum_se, o);
  float sloop = ssum_se / (float)(deg > 0 ? deg : 1);
  float sc = (lane < deg) ? lrelu(ssrc[t*NN + sj] + sd + se_e) : -1e30f;
  float al = lrelu(ssrc[t*NN + n] + sd + sloop);
  float mx = fmaxf(sc, al);
  #pragma unroll
  for (int o = 32; o > 0; o >>= 1) mx = fmaxf(mx, __shfl_xor(mx, o));
  float ex = (lane < deg) ? __expf(sc - mx) : 0.f;
  float ale = __expf(al - mx);
  float ssum = ex;
  #pragma unroll
  for (int o = 32; o > 0; o >>= 1) ssum += __shfl_xor(ssum, o);
  float inv = 1.f/(ssum + ale + 1e-16f);
  const float4* xl4 = (const float4*)xl;
  float4 acc = xl4[((size_t)(t*NN + n))*64 + lane];
  acc.x *= ale; acc.y *= ale; acc.z *= ale; acc.w *= ale;
  for (int j = 0; j < deg; j++){
    float p = __shfl(ex, j);
    int s = __shfl(sj, j);
    float4 v = xl4[((size_t)(t*NN + s))*64 + lane];
    acc.x += p*v.x; acc.y += p*v.y; acc.z += p*v.z; acc.w += p*v.w;
  }
  float4 b4 = *(const float4*)&bias[(t*LL + l)*C + lane*4];
  acc.x = eluf(acc.x*inv + b4.x); acc.y = eluf(acc.y*inv + b4.y);
  acc.z = eluf(acc.z*inv + b4.z); acc.w = eluf(acc.w*inv + b4.w);
  ((float4*)hout)[((size_t)(t*NN + n))*64 + lane] = acc;
}

// fused hacc + colstats
__global__ __launch_bounds__(256) void hacccs_k(const float* __restrict__ h, const float* __restrict__ etw,
                                                float* __restrict__ hacc, float* meanp, float* maxp){
  int r0 = blockIdx.x*(NN/256), c = threadIdx.x;
  float e0 = etw[0], e1 = etw[1], e2 = etw[2], e3 = etw[3];
  float m = fmaxf(fmaxf(e0,e1), fmaxf(e2,e3));
  float w0 = __expf(e0-m), w1 = __expf(e1-m), w2 = __expf(e2-m), w3 = __expf(e3-m);
  float inv = 1.f/(w0+w1+w2+w3);
  float sm = 0.f, mx = -1e30f;
  for (int r = 0; r < NN/256; r++){
    int n = r0 + r;
    float s = (w0*h[(0*NN+n)*C+c] + w1*h[(1*NN+n)*C+c] + w2*h[(2*NN+n)*C+c] + w3*h[(3*NN+n)*C+c])*inv;
    hacc[(size_t)n*C + c] = s;
    sm += s; mx = fmaxf(mx, s);
  }
  atomicAdd(&meanp[c], sm*(1.f/4096.f));
  atomicMaxF(&maxp[c], mx);
}

// multi-wave MFMA flash attention (4 waves/block, coop K/V^T stage,
// Q in registers, per-wave P buffer; 2 blocks/CU)
__global__ __launch_bounds__(256, 2) void attn_k(const float* __restrict__ qkv,
                                                 float* __restrict__ opart,
                                                 float* __restrict__ dpart){
  __shared__ __align__(16) _Float16 Ks[64*QKS];    // [m][k]
  __shared__ __align__(16) _Float16 VTs[64*QKS];   // [d][m]
  __shared__ __align__(16) _Float16 Ps[4][64*QKS]; // per-wave [n][m]
  int tid = threadIdx.x;
  int wave = tid >> 6, l = tid & 63;
  int nb = blockIdx.x*256 + wave*64;
  int h = blockIdx.y, mc = blockIdx.z;
  int r16 = l & 15, q = l >> 4;
  _Float16* Pw = Ps[wave];

  v8h qf[4][2];
  #pragma unroll
  for (int ni = 0; ni < 4; ni++){
    const float* qrow = qkv + (size_t)(nb + ni*16 + r16)*768 + h*64;
    #pragma unroll
    for (int kk = 0; kk < 2; kk++){
      float4 a = *(const float4*)(qrow + kk*32 + q*8);
      float4 b = *(const float4*)(qrow + kk*32 + q*8 + 4);
      v8h hv = {(_Float16)(a.x*0.125f), (_Float16)(a.y*0.125f),
                (_Float16)(a.z*0.125f), (_Float16)(a.w*0.125f),
                (_Float16)(b.x*0.125f), (_Float16)(b.y*0.125f),
                (_Float16)(b.z*0.125f), (_Float16)(b.w*0.125f)};
      qf[ni][kk] = hv;
    }
  }

  v4f o[4][4];
  #pragma unroll
  for (int i = 0; i < 4; i++)
    #pragma unroll
    for (int j = 0; j < 4; j++) o[i][j] = (v4f){0.f,0.f,0.f,0.f};
  float dn[4] = {0.f,0.f,0.f,0.f};

  for (int mt = 0; mt < NN/MCH/64; mt++){
    int mb = mc*(NN/MCH) + mt*64;
    __syncthreads();
    {
      int sr = tid >> 2, sc = (tid & 3)*16;
      const float* krow = qkv + (size_t)(mb + sr)*768 + 256 + h*64 + sc;
      float4 a = *(const float4*)(krow + 0);
      float4 b = *(const float4*)(krow + 4);
      float4 cc = *(const float4*)(krow + 8);
      float4 d = *(const float4*)(krow + 12);
      v8h h0 = {(_Float16)a.x, (_Float16)a.y, (_Float16)a.z, (_Float16)a.w,
                (_Float16)b.x, (_Float16)b.y, (_Float16)b.z, (_Float16)b.w};
      v8h h1 = {(_Float16)cc.x, (_Float16)cc.y, (_Float16)cc.z, (_Float16)cc.w,
                (_Float16)d.x, (_Float16)d.y, (_Float16)d.z, (_Float16)d.w};
      *(v8h*)(Ks + (size_t)sr*QKS + sc) = h0;
      *(v8h*)(Ks + (size_t)sr*QKS + sc + 8) = h1;
    }
    {
      int m0 = (tid & 31)*2;
      int db = (tid >> 5)*8;
      const float* v0 = qkv + (size_t)(mb + m0)*768 + 512 + h*64 + db;
      const float* v1 = v0 + 768;
      #pragma unroll
      for (int i = 0; i < 2; i++){
        float4 a = *(const float4*)(v0 + 4*i);
        float4 b = *(const float4*)(v1 + 4*i);
        int d = db + 4*i;
        *(unsigned*)(VTs + (size_t)(d+0)*QKS + m0) = pk2(a.x, b.x);
        *(unsigned*)(VTs + (size_t)(d+1)*QKS + m0) = pk2(a.y, b.y);
        *(unsigned*)(VTs + (size_t)(d+2)*QKS + m0) = pk2(a.z, b.z);
        *(unsigned*)(VTs + (size_t)(d+3)*QKS + m0) = pk2(a.w, b.w);
      }
    }
    __syncthreads();
    v4f c[4][4];
    #pragma unroll
    for (int i = 0; i < 4; i++)
      #pragma unroll
      for (int j = 0; j < 4; j++) c[i][j] = (v4f){0.f,0.f,0.f,0.f};
    #pragma unroll
    for (int kk = 0; kk < 2; kk++){
      v8h a[4];
      #pragma unroll
      for (int mi = 0; mi < 4; mi++) a[mi] = *(v8h*)(Ks + (size_t)(mi*16 + r16)*QKS + kk*32 + q*8);
      #pragma unroll
      for (int mi = 0; mi < 4; mi++)
        #pragma unroll
        for (int ni = 0; ni < 4; ni++)
          c[mi][ni] = __builtin_amdgcn_mfma_f32_16x16x32_f16(a[mi], qf[ni][kk], c[mi][ni], 0, 0, 0);
    }
    #pragma unroll
    for (int mi = 0; mi < 4; mi++)
      #pragma unroll
      for (int ni = 0; ni < 4; ni++){
        float e0 = __expf(c[mi][ni][0]), e1 = __expf(c[mi][ni][1]),
              e2 = __expf(c[mi][ni][2]), e3 = __expf(c[mi][ni][3]);
        dn[ni] += e0 + e1 + e2 + e3;
        *(uint2*)(Pw + (size_t)(ni*16 + r16)*QKS + mi*16 + q*4) = make_uint2(pk2(e0,e1), pk2(e2,e3));
      }
    #pragma unroll
    for (int km = 0; km < 2; km++){
      v8h pa[4], vb[4];
      #pragma unroll
      for (int ni = 0; ni < 4; ni++) pa[ni] = *(v8h*)(Pw + (size_t)(ni*16 + r16)*QKS + km*32 + q*8);
      #pragma unroll
      for (int di = 0; di < 4; di++) vb[di] = *(v8h*)(VTs + (size_t)(di*16 + r16)*QKS + km*32 + q*8);
      #pragma unroll
      for (int ni = 0; ni < 4; ni++)
        #pragma unroll
        for (int di = 0; di < 4; di++)
          o[ni][di] = __builtin_amdgcn_mfma_f32_16x16x32_f16(pa[ni], vb[di], o[ni][di], 0, 0, 0);
    }
  }

  float* ob = opart + ((size_t)mc*NN + nb)*C + h*64;
  #pragma unroll
  for (int ni = 0; ni < 4; ni++)
    #pragma unroll
    for (int di = 0; di < 4; di++)
      #pragma unroll
      for (int r = 0; r < 4; r++)
        ob[(size_t)(ni*16 + q*4 + r)*C + di*16 + r16] = o[ni][di][r];
  #pragma unroll
  for (int ni = 0; ni < 4; ni++){
    dn[ni] += __shfl_xor(dn[ni], 16);
    dn[ni] += __shfl_xor(dn[ni], 32);
  }
  if (q == 0){
    #pragma unroll
    for (int ni = 0; ni < 4; ni++)
      dpart[((size_t)mc*NN + nb + ni*16 + r16)*AHD + h] = dn[ni];
  }
}

__global__ __launch_bounds__(256) void attnred_k(const float* __restrict__ opart, const float* __restrict__ dpart,
                                                 float* omean){
  int r0 = blockIdx.x*(NN/256), c = threadIdx.x;
  int head = c >> 6;
  float s = 0.f;
  for (int r = 0; r < NN/256; r++){
    int n = r0 + r;
    float dsum = 0.f, osum = 0.f;
    #pragma unroll
    for (int mc = 0; mc < MCH; mc++){
      dsum += dpart[((size_t)mc*NN + n)*AHD + head];
      osum += opart[((size_t)mc*NN + n)*C + c];
    }
    s += osum / (dsum + 1e-16f);
  }
  atomicAdd(&omean[c], s*(1.f/4096.f));
}

// attnp over 16 blocks x 16 cols (16-lane shuffle dots); seeds g1 = fb1.
__global__ __launch_bounds__(256) void taila_k(const float* __restrict__ omean, const float* __restrict__ opw,
                                               const float* __restrict__ opb, const float* __restrict__ fb1,
                                               float* attnp, float* g1){
  __shared__ float sh[256];
  int tid = threadIdx.x;
  sh[tid] = omean[tid];
  __syncthreads();
  int jj = tid >> 4, kk = tid & 15;
  int j = blockIdx.x*16 + jj;
  float acc = 0.f;
  #pragma unroll
  for (int i = 0; i < 16; i++){
    int k = kk*16 + i;
    acc += sh[k]*opw[(size_t)j*256 + k];
  }
  acc += __shfl_xor(acc, 1); acc += __shfl_xor(acc, 2);
  acc += __shfl_xor(acc, 4); acc += __shfl_xor(acc, 8);
  if (kk == 0) attnp[j] = acc + opb[j];
  if (blockIdx.x < 2) g1[blockIdx.x*256 + tid] = fb1[blockIdx.x*256 + tid];
}

// fus1 k-split partials: 16 blocks x 48 k-rows, atomicAdd onto g1
__global__ __launch_bounds__(512) void tailb_k(const float* __restrict__ meanp, const float* __restrict__ maxp,
                                               const float* __restrict__ attnp, const float* __restrict__ fw1,
                                               float* g1){
  __shared__ float comb[48];
  int b = blockIdx.x, tid = threadIdx.x;
  if (tid < 48){
    int k = b*48 + tid;
    comb[tid] = (k < 256) ? meanp[k] : (k < 512 ? maxp[k-256] : attnp[k-512]);
  }
  __syncthreads();
  float acc = 0.f;
  #pragma unroll 4
  for (int i = 0; i < 48; i++)
    acc += comb[i]*fw1[((size_t)(b*48 + i))*512 + tid];
  atomicAdd(&g1[tid], acc);
}

// fus2: 8 blocks x 32 cols; relu(g1) on load, final relu on store.
__global__ __launch_bounds__(256) void tailc_k(const float* __restrict__ g1, const float* __restrict__ fw2,
                                               const float* __restrict__ fb2, float* __restrict__ out){
  __shared__ float g[512];
  __shared__ float red[256];
  int tid = threadIdx.x;
  g[tid] = fmaxf(g1[tid], 0.f);
  g[tid + 256] = fmaxf(g1[tid + 256], 0.f);
  __syncthreads();
  int j = blockIdx.x*32 + (tid & 31);
  int kp = tid >> 5;                     // 8 k-parts x 64
  float acc = 0.f;
  #pragma unroll 4
  for (int i = 0; i < 64; i++){
    int k = kp*64 + i;
    acc += g[k]*fw2[(size_t)k*256 + j];
  }
  red[tid] = acc;
  __syncthreads();
  if (tid < 32){
    float s = 0.f;
    #pragma unroll
    for (int p = 0; p < 8; p++) s += red[p*32 + tid];
    out[j] = fmaxf(s + fb2[j], 0.f);
  }
}

extern "C" void kernel_launch(void* const* d_in, const int* in_sizes, int n_in,
                              void* d_out, int out_size, void* d_ws, size_t ws_size,
                              hipStream_t stream){
  const float* x     = (const float*)d_in[0];
  const int*   srcv  = (const int*)d_in[1];
  const int*   dstv  = (const int*)d_in[2];
  const float* eattr = (const float*)d_in[3];
  const int*   etyp  = (const int*)d_in[4];
  const float* W0    = (const float*)d_in[5];
  const float* W12   = (const float*)d_in[6];
  const float* attS  = (const float*)d_in[7];
  const float* attD  = (const float*)d_in[8];
  const float* attE  = (const float*)d_in[9];
  const float* linE  = (const float*)d_in[10];
  const float* bias  = (const float*)d_in[11];
  const float* etw   = (const float*)d_in[12];
  const float* ipw   = (const float*)d_in[13];
  const float* ipb   = (const float*)d_in[14];
  const float* opw   = (const float*)d_in[15];
  const float* opb   = (const float*)d_in[16];
  const float* fw1   = (const float*)d_in[17];
  const float* fb1   = (const float*)d_in[18];
  const float* fw2   = (const float*)d_in[19];
  const float* fb2   = (const float*)d_in[20];
  float* out = (float*)d_out;

  if (ws_size < (size_t)WS_WORDS*4) return;

  int*       ip   = (int*)d_ws;
  float*     fp   = (float*)d_ws;
  _Float16*  ip16 = (_Float16*)(fp + F_WT);
  _Float16*  wpT  = (_Float16*)(fp + U_W12P);

  // mega-pack: weights, we, float inits, cursor zero (must precede hist)
  pack_k<<<dim3(256, 12), 256, 0, stream>>>(W12, wpT, ipw, ip16, linE, attE,
                                            fp + F_WE, fp + F_MEANP, ip + W_CURSOR);

  hist_k<<<EE/256, 256, 0, stream>>>(dstv, etyp, ip + W_CURSOR);
  scan_k<<<1, 1024, 0, stream>>>(ip + W_CURSOR, ip + W_OFF, ip + W_CURSOR);
  scatter_k<<<EE/256, 256, 0, stream>>>(dstv, etyp, ip + W_CURSOR, ip + W_SORTED);

  for (int l = 0; l < 3; l++){
    if (l == 0)
      gemm_k<<<dim3(NN/8, T), 256, 0, stream>>>(x, DIN, W0, (long)DIN*C, attS, attD, 0,
                                                fp + F_XL, fp + F_SSRC, fp + F_SDST);
    else
      gemm16m_k<<<dim3(NN/64, T), 256, 0, stream>>>(fp + F_H, wpT, attS, attD, l,
                                                    fp + F_XL, fp + F_SSRC, fp + F_SDST);
    agg_k<<<(NN*T)/4, 256, 0, stream>>>(fp + F_XL, fp + F_SSRC, fp + F_SDST,
                                        fp + F_WE, eattr,
                                        ip + W_OFF, ip + W_SORTED, srcv,
                                        bias, fp + F_H, l);
  }

  hacccs_k<<<256, 256, 0, stream>>>(fp + F_H, etw, fp + F_HACC, fp + F_MEANP, fp + F_MAXP);

  qkv16m_k<<<dim3(NN/64, 3), 256, 0, stream>>>(fp + F_HACC, ip16, ipb, fp + F_QKV);
  attn_k<<<dim3(NN/256, AHD, MCH), 256, 0, stream>>>(fp + F_QKV, fp + F_OPART, fp + F_DPART);
  attnred_k<<<256, 256, 0, stream>>>(fp + F_OPART, fp + F_DPART, fp + F_OMEAN);

  taila_k<<<16, 256, 0, stream>>>(fp + F_OMEAN, opw, opb, fb1, fp + F_ATTNP, fp + F_G1);
  tailb_k<<<16, 512, 0, stream>>>(fp + F_MEANP, fp + F_MAXP, fp + F_ATTNP, fw1, fp + F_G1);
  tailc_k<<<8, 256, 0, stream>>>(fp + F_G1, fw2, fb2, out);
}